// Round 9
// baseline (1075.073 us; speedup 1.0000x reference)
//
#include <hip/hip_runtime.h>
#include <math.h>

#define NN 50000
#define EE 800000
#define HH 128
#define FF 64
#define GG 8
#define PB 500      // pool phase-1 blocks (covers 100 rows each)
#define SB 1600     // scatter blocks: 200 per dst-group, 8 groups

using short8 = __attribute__((ext_vector_type(8))) short;
using f32x4  = __attribute__((ext_vector_type(4))) float;
using f32x2  = __attribute__((ext_vector_type(2))) float;

__device__ __forceinline__ float sigm(float x){ return 1.0f/(1.0f+expf(-x)); }
__device__ __forceinline__ unsigned short f2bf(float f){
    union { float f; unsigned u; } v; v.f = f;
    unsigned r = v.u + 0x7fff + ((v.u >> 16) & 1);
    return (unsigned short)(r >> 16);
}
__device__ __forceinline__ float bf2f(unsigned short h){
    union { unsigned u; float f; } v; v.u = ((unsigned)h) << 16;
    return v.f;
}

// ---------- fp8 helpers (HW cvt on gfx950; self-consistent either format) ----------
#if __has_builtin(__builtin_amdgcn_cvt_pk_fp8_f32) && __has_builtin(__builtin_amdgcn_cvt_pk_f32_fp8)
#define FP8_HW 1
#else
#define FP8_HW 0
#endif

__device__ __forceinline__ unsigned fp8enc1_sw(float f){
    union { float fl; unsigned u; } x; x.fl = f;
    unsigned s = (x.u >> 31) << 7;
    float a = fabsf(f);
    if (!(a > 0.f)) return s;
    if (a >= 448.f) return s | 0x7E;
    if (a < 0.015625f) {
        int q = (int)(a * 512.f + 0.5f);
        if (q > 7) return s | (1u << 3);
        return s | (unsigned)q;
    }
    unsigned u = x.u + (1u << 19);          // round at 3-bit mantissa
    int e32 = (int)((u >> 23) & 255) - 127;
    if (e32 < -6) { int q=(int)(a*512.f+0.5f); if(q>7)q=7; return s|(unsigned)q; }
    if (e32 > 8) return s | 0x7E;
    unsigned m = (u >> 20) & 7;
    return s | ((unsigned)(e32 + 7) << 3) | m;
}
__device__ __forceinline__ float fp8dec1_sw(unsigned v){
    unsigned s = v >> 7, e = (v >> 3) & 15, m = v & 7;
    float f;
    if (e == 0) f = (float)m * 0.001953125f;
    else { union { unsigned u; float fl; } x; x.u = ((e + 120u) << 23) | (m << 20); f = x.fl; }
    return s ? -f : f;
}
__device__ __forceinline__ unsigned char e2fp8(float a){
#if FP8_HW
    return (unsigned char)(__builtin_amdgcn_cvt_pk_fp8_f32(a, a, 0, false) & 0xFF);
#else
    return (unsigned char)fp8enc1_sw(a);
#endif
}
__device__ __forceinline__ float2 d2fp8(unsigned short u){
#if FP8_HW
    f32x2 r = __builtin_amdgcn_cvt_pk_f32_fp8((int)(unsigned)u, false);
    return make_float2(r[0], r[1]);
#else
    return make_float2(fp8dec1_sw(u & 0xFF), fp8dec1_sw((u >> 8) & 0xFF));
#endif
}

// ---------- setup (block 0) + graph bounds (block 1) ----------
__global__ void k_setup(const float* __restrict__ meth,
                        const float* __restrict__ histones,
                        const float* __restrict__ logd,
                        float* __restrict__ scal,
                        const int* __restrict__ batch, int* __restrict__ st)
{
    if (blockIdx.x == 1) {
        int g = threadIdx.x;
        if (g > GG) return;
        int lo = 0, hi = NN;
        while (lo < hi) { int mid = (lo + hi) >> 1; if (batch[mid] < g) lo = mid + 1; else hi = mid; }
        st[g] = lo;
        return;
    }
    int l = threadIdx.x;
    float s = sigm(meth[l]) + sigm(meth[l + 64]);
#pragma unroll
    for (int o = 32; o >= 1; o >>= 1) s += __shfl_xor(s, o, 64);
    if (l == 0) {
        float msil = s * (1.0f / 128.0f);
        float h0 = sigm(histones[0]), h1 = sigm(histones[1]);
        float h2 = sigm(histones[2]), h3 = sigm(histones[3]);
        float act = (h0 + h2) * 0.5f, rep = (h1 + h3) * 0.5f;
        float chrom = fminf(fmaxf(act - rep + 0.5f, 0.0f), 1.0f);
        scal[0] = chrom * (1.0f - msil);
        float d = expf(logd[0]);
        scal[1] = fminf(fmaxf(d, 0.1f), 3.0f);   // dt
    }
}

// ---------- single merged weight pack: all 7 matrices -> one contiguous bf16 buffer ----------
__global__ void k_packall(const float* __restrict__ in_w, const float* __restrict__ gcn_w,
                          const float* __restrict__ gate_w, const float* __restrict__ out_w,
                          unsigned short* __restrict__ outp)
{
    int i = blockIdx.x * 256 + threadIdx.x;
    if (i >= 8192 + 6 * 16384) return;
    const float* src; int base, li;
    if (i < 8192) { src = in_w + i; base = 0; li = i; }
    else {
        int j = i - 8192;
        int m = j >> 14, r = j & 16383;
        base = 8192 + (m << 14); li = r;
        if (m < 3)      src = gcn_w  + m * 16384 + r;
        else if (m < 5) src = gate_w + (m - 3) * 16384 + r;
        else            src = out_w + r;
    }
    int k = li >> 7, n = li & 127;
    int c = k >> 5, kl = k & 31, q = kl >> 3, j2 = kl & 7;
    int b = n >> 4, ln = n & 15;
    int lane = q * 16 + ln;
    outp[base + ((c * 8 + b) * 64 + lane) * 8 + j2] = f2bf(*src);
}

// ---------- x fp32 -> bf16 ----------
__global__ void k_cvtx(const float* __restrict__ x, unsigned short* __restrict__ xb)
{
    size_t i = (size_t)blockIdx.x * 256 + threadIdx.x;
    if (i >= (size_t)NN * 16) return;
    float4 v = ((const float4*)x)[i];
    ushort4 o;
    o.x = f2bf(v.x); o.y = f2bf(v.y); o.z = f2bf(v.z); o.w = f2bf(v.w);
    ((ushort4*)xb)[i] = o;
}

// ---------- CSR build ----------
__global__ void k_hist(const int* __restrict__ ei, int* __restrict__ hist)
{
    int e = blockIdx.x * 256 + threadIdx.x;
    if (e < EE) atomicAdd(&hist[ei[EE + e]], 1);
}

__global__ void k_dinv(const int* __restrict__ hist, float* __restrict__ dinv)
{
    int n = blockIdx.x * 256 + threadIdx.x;
    if (n < NN) {
        int d = hist[n];
        dinv[n] = d > 0 ? rsqrtf((float)d) : 0.0f;
    }
}

__global__ void k_scan_a(const int* __restrict__ hist, int* __restrict__ aux)
{
    __shared__ int sh[256];
    int b = blockIdx.x, t = threadIdx.x;
    int base = b * 1024 + t * 4;
    int s = 0;
#pragma unroll
    for (int j = 0; j < 4; ++j) { int i = base + j; if (i < NN) s += hist[i]; }
    sh[t] = s; __syncthreads();
    for (int o = 128; o >= 1; o >>= 1) { if (t < o) sh[t] += sh[t + o]; __syncthreads(); }
    if (t == 0) aux[b] = sh[0];
}

__global__ void k_scan_b(int* __restrict__ aux, int nb)
{
    if (blockIdx.x == 0 && threadIdx.x == 0) {
        int run = 0;
        for (int i = 0; i < nb; ++i) { int v = aux[i]; aux[i] = run; run += v; }
    }
}

// writes BOTH row_ptr and cursor (folds the old cursor memcpy away)
__global__ void k_scan_c(const int* __restrict__ hist, const int* __restrict__ aux,
                         int* __restrict__ row_ptr, int* __restrict__ cursor)
{
    __shared__ int sh[256];
    int b = blockIdx.x, t = threadIdx.x;
    int base = b * 1024 + t * 4;
    int v[4]; int s = 0;
#pragma unroll
    for (int j = 0; j < 4; ++j) { int i = base + j; v[j] = (i < NN) ? hist[i] : 0; s += v[j]; }
    sh[t] = s; __syncthreads();
    for (int o = 1; o < 256; o <<= 1) {
        int x = 0; if (t >= o) x = sh[t - o];
        __syncthreads(); sh[t] += x; __syncthreads();
    }
    int run = aux[b] + sh[t] - s;
#pragma unroll
    for (int j = 0; j < 4; ++j) {
        int i = base + j;
        if (i < NN) { row_ptr[i] = run; cursor[i] = run; }
        run += v[j];
    }
    if (b == 0 && t == 0) { row_ptr[NN] = EE; cursor[NN] = EE; }
}

// ---------- XCD-aligned dst-partitioned scatter, 4-byte records, nt streams ----------
// Verified rounds 5-8: 42 µs (FETCH 25 MB from 8x dst-read replication — L3
// does NOT absorb it; WRITE 31 MB; nt hints don't prevent L2 allocation).
__global__ __launch_bounds__(256) void k_scatter(const int* __restrict__ ei,
                          int* __restrict__ cursor, unsigned* __restrict__ ew)
{
    if (blockIdx.x == 0 && threadIdx.x < 128)    // tail pads for spgemm prefetch
        ew[EE + threadIdx.x] = 0u;
    const int grp = blockIdx.x & 7;
    const int blk = blockIdx.x >> 3;             // 0..SB/8-1
    const int CH  = EE / (SB / 8);               // 4000
    const int e0 = blk * CH, e1 = e0 + CH;
    const int glo = grp * (NN / 8), ghi = glo + (NN / 8);
    for (int e = e0 + threadIdx.x; e < e1; e += 256) {
        int d = __builtin_nontemporal_load(ei + EE + e);
        if (d >= glo && d < ghi) {
            int s = __builtin_nontemporal_load(ei + e);
            int p = atomicAdd(&cursor[d], 1);
            ew[p] = (unsigned)s | ((unsigned)(d & 15) << 16);
        }
    }
}

// ---------- MFMA dense (LDS-staged W): out = [relu(]LN(A@W+b)[)*sc] (+scaled fp8 shadow) ----------
// fp8 shadow = dinv[row] * value (spgemm gather sources are pre-scaled)
template<int KC, int MODE>
__global__ __launch_bounds__(256) void k_dense_mfma(
    const unsigned short* __restrict__ A, const unsigned short* __restrict__ Wp,
    const float* __restrict__ bias, const float* __restrict__ lng,
    const float* __restrict__ lnb, const float* __restrict__ scal,
    const float* __restrict__ dinv,
    unsigned short* __restrict__ out, unsigned char* __restrict__ out8)
{
    __shared__ unsigned short Ws[KC * 4096];
    const int t = threadIdx.x;
    {
        const float4* src = (const float4*)Wp;
        float4* dst = (float4*)Ws;
#pragma unroll
        for (int i = 0; i < KC * 2; ++i) dst[t + i * 256] = src[t + i * 256];
    }
    __syncthreads();
    const int wave = t >> 6, lane = t & 63;
    const int quad = lane >> 4, ln = lane & 15;
    const int r0 = blockIdx.x * 64 + wave * 16;
    const int K = KC * 32;
    const int arow = r0 + ln;
    const bool av = arow < NN;

    f32x4 acc[8] = {};
#pragma unroll
    for (int c = 0; c < KC; ++c) {
        short8 a = {};
        if (av) a = *(const short8*)(A + (size_t)arow * K + c * 32 + quad * 8);
#pragma unroll
        for (int b = 0; b < 8; ++b) {
            short8 bb = *(const short8*)&Ws[((c * 8 + b) * 64 + lane) * 8];
            acc[b] = __builtin_amdgcn_mfma_f32_16x16x32_bf16(a, bb, acc[b], 0, 0, 0);
        }
    }

    float b_s[8], g_s[8], e_s[8];
#pragma unroll
    for (int b = 0; b < 8; ++b) {
        int col = b * 16 + ln;
        b_s[b] = bias[col]; g_s[b] = lng[col]; e_s[b] = lnb[col];
    }
    float sc = (MODE == 1) ? scal[0] : 0.0f;
#pragma unroll
    for (int i = 0; i < 4; ++i) {
        int row = r0 + quad * 4 + i;
        float v[8]; float s = 0.f, q = 0.f;
#pragma unroll
        for (int b = 0; b < 8; ++b) { float x = acc[b][i] + b_s[b]; v[b] = x; s += x; q += x * x; }
#pragma unroll
        for (int o = 1; o < 16; o <<= 1) { s += __shfl_xor(s, o, 64); q += __shfl_xor(q, o, 64); }
        float m  = s * (1.0f / 128.0f);
        float vr = q * (1.0f / 128.0f) - m * m;
        float rs = rsqrtf(vr + 1e-5f);
        if (row < NN) {
            float dv = out8 ? dinv[row] : 0.f;
#pragma unroll
            for (int b = 0; b < 8; ++b) {
                float o2 = (v[b] - m) * rs * g_s[b] + e_s[b];
                if (MODE == 1) o2 = fmaxf(o2, 0.f) * sc;
                out[(size_t)row * 128 + b * 16 + ln] = f2bf(o2);
                if (out8) out8[(size_t)row * 128 + b * 16 + ln] = e2fp8(o2 * dv);
            }
        }
    }
}

// ---------- fused SpMM + GEMM + LN [+ gate [+ RK4 stage]] ----------
// EPI=0: plain LN -> out/out8 (layer 0).
// EPI=1: + gate vs curg -> out/out8 (layer 1; MUST write fresh buffers —
//        writing cur8 in-place would race other blocks' edge-phase gathers).
// EPI=2..5: + gate vs curg + RK4 stage S=EPI-1 -> tvS, y(out), y8(out8).
// ROUND-8/9 RATIONALE: gates are latency-bound, not BW-bound (bf16-tv
// restructure was time-neutral) — so the ~25-30 µs/dispatch is launch/drain
// floor; the only recovery is fusing them here. Gate-hnew goes through the
// same bf16 round-trip (via LDS) the old t2 buffer had -> numerics identical.
// Gate MFMA reads B from L2 like the existing MFMA phase (no per-MFMA
// barrier; occupancy covers latency — NOT the R6 failure mode).
// Edge phase: PIPELINE DEPTH 1 (R5: 2-deep regressed). No LDS atomics in hot
// loop (R1-2: halves throughput). No min-waves launch_bounds (spills).
template<int EPI>
__global__ __launch_bounds__(128) void k_spgemm(
    const int* __restrict__ rp, const unsigned* __restrict__ ew,
    const unsigned char* __restrict__ X8, const unsigned short* __restrict__ Wp,
    const float* __restrict__ bias, const float* __restrict__ lng,
    const float* __restrict__ lnb, const float* __restrict__ dinv,
    const unsigned short* __restrict__ Gw, const float* __restrict__ gb,
    const unsigned short* __restrict__ curg,
    const unsigned short* __restrict__ fin, const unsigned short* __restrict__ h0,
    unsigned short* __restrict__ tv1, unsigned short* __restrict__ tv2,
    unsigned short* __restrict__ tv3,
    const float* __restrict__ scal, const float* __restrict__ rwp,
    unsigned short* __restrict__ out, unsigned char* __restrict__ out8)
{
    __shared__ float accf[2][16 * 132];       // per-half buffers (16.9 KB)
    const int t = threadIdx.x, wave = t >> 6, lane = t & 63;
    const int quad = lane >> 4, ln = lane & 15;
    const int half = lane >> 5, li = lane & 31;
    const int n0 = blockIdx.x * 16;           // NN%16==0 -> all rows valid
    const int nf = n0 + wave * 8;

    // zero own rows in both half-buffers (own-wave rows only)
    {
        float* z0 = &accf[0][wave * 8 * 132];
        float* z1 = &accf[1][wave * 8 * 132];
        for (int i = lane; i < 8 * 132; i += 64) { z0[i] = 0.f; z1[i] = 0.f; }
    }

    {
        const int nl = min(nf + 8, NN);
        const int ebeg = __builtin_amdgcn_readfirstlane(rp[nf]);
        const int eend = __builtin_amdgcn_readfirstlane(rp[nl]);
        if (ebeg < eend) {
            float4 racc = make_float4(0.f, 0.f, 0.f, 0.f);
            int curd = (int)((ew[min(ebeg + half, eend - 1)] >> 16) & 15u);
            const unsigned char* Xl = X8 + li * 4;
            unsigned rec[8], recN[8], g[8];
#pragma unroll
            for (int j = 0; j < 8; ++j) rec[j]  = ew[ebeg + 2 * j + half];        // pad-safe
#pragma unroll
            for (int j = 0; j < 8; ++j) recN[j] = ew[ebeg + 16 + 2 * j + half];   // pad-safe
#pragma unroll
            for (int j = 0; j < 8; ++j) {
                int src = (int)(rec[j] & 0xFFFFu);
                g[j] = *(const unsigned*)(Xl + (size_t)src * 128);
            }
            for (int e = ebeg; e < eend; e += 16) {
                // issue next round's gathers + round-after-next records
                unsigned gN[8], recNN[8];
#pragma unroll
                for (int j = 0; j < 8; ++j) {
                    int src = (int)(recN[j] & 0xFFFFu);
                    gN[j] = *(const unsigned*)(Xl + (size_t)src * 128);
                }
#pragma unroll
                for (int j = 0; j < 8; ++j) recNN[j] = ew[e + 32 + 2 * j + half]; // pad-safe
                // consume current round (waits only on g)
                int lim = eend - e;
                int mj = lim > half ? ((lim - half + 1) >> 1) : 0; if (mj > 8) mj = 8;
#pragma unroll
                for (int j = 0; j < 8; ++j) {
                    if (j >= mj) break;                  // half-uniform (tail only)
                    int dl = (int)((rec[j] >> 16) & 15u);
                    if (dl != curd) {                    // half-uniform, 1 store
                        *(float4*)&accf[half][curd * 132 + li * 4] = racc;
                        racc = make_float4(0.f, 0.f, 0.f, 0.f);
                        curd = dl;
                    }
                    float2 p0 = d2fp8((unsigned short)(g[j] & 0xFFFFu));
                    float2 p1 = d2fp8((unsigned short)(g[j] >> 16));
                    racc.x += p0.x;
                    racc.y += p0.y;
                    racc.z += p1.x;
                    racc.w += p1.y;
                }
#pragma unroll
                for (int j = 0; j < 8; ++j) { rec[j] = recN[j]; recN[j] = recNN[j]; g[j] = gN[j]; }
            }
            *(float4*)&accf[half][curd * 132 + li * 4] = racc;   // final flush
        }
    }
    __syncthreads();

    // MFMA phase (redundant across the 2 waves): A = accf[0]+accf[1], B from L2
    f32x4 acc[8] = {};
    {
        const float* ar0 = &accf[0][(size_t)ln * 132];
        const float* ar1 = &accf[1][(size_t)ln * 132];
#pragma unroll
        for (int c = 0; c < 4; ++c) {
            float4 a0 = *(const float4*)(ar0 + c * 32 + quad * 8);
            float4 a1 = *(const float4*)(ar0 + c * 32 + quad * 8 + 4);
            float4 b0 = *(const float4*)(ar1 + c * 32 + quad * 8);
            float4 b1 = *(const float4*)(ar1 + c * 32 + quad * 8 + 4);
            short8 af;
            af[0] = (short)f2bf(a0.x + b0.x); af[1] = (short)f2bf(a0.y + b0.y);
            af[2] = (short)f2bf(a0.z + b0.z); af[3] = (short)f2bf(a0.w + b0.w);
            af[4] = (short)f2bf(a1.x + b1.x); af[5] = (short)f2bf(a1.y + b1.y);
            af[6] = (short)f2bf(a1.z + b1.z); af[7] = (short)f2bf(a1.w + b1.w);
#pragma unroll
            for (int b = 0; b < 8; ++b) {
                short8 bb = *(const short8*)(Wp + ((size_t)(c * 8 + b) * 64 + lane) * 8);
                acc[b] = __builtin_amdgcn_mfma_f32_16x16x32_bf16(af, bb, acc[b], 0, 0, 0);
            }
        }
    }

    float b_s[8], g_s[8], e_s[8];
#pragma unroll
    for (int b = 0; b < 8; ++b) {
        int col = b * 16 + ln;
        b_s[b] = bias[col]; g_s[b] = lng[col]; e_s[b] = lnb[col];
    }

    if (EPI == 0) {
#pragma unroll
        for (int i = 0; i < 4; ++i) {
            int row = n0 + quad * 4 + i;
            float dv = dinv[row];
            float v[8]; float s = 0.f, q = 0.f;
#pragma unroll
            for (int b = 0; b < 8; ++b) { float x = acc[b][i] * dv + b_s[b]; v[b] = x; s += x; q += x * x; }
#pragma unroll
            for (int o = 1; o < 16; o <<= 1) { s += __shfl_xor(s, o, 64); q += __shfl_xor(q, o, 64); }
            float m  = s * (1.0f / 128.0f);
            float vr = q * (1.0f / 128.0f) - m * m;
            float rs = rsqrtf(vr + 1e-5f);
            if ((quad >> 1) == wave) {   // each wave stores its half
#pragma unroll
                for (int b = 0; b < 8; ++b) {
                    float o2 = (v[b] - m) * rs * g_s[b] + e_s[b];
                    out[(size_t)row * 128 + b * 16 + ln] = f2bf(o2);
                    if (out8) out8[(size_t)row * 128 + b * 16 + ln] = e2fp8(o2 * dv);
                }
            }
        }
    } else {
        // ---- fused gate epilogue ----
        // 1) LN -> bf16 hnew into LDS (reuse accf; barrier: MFMA-phase reads done)
        __syncthreads();
        unsigned short* hsh = (unsigned short*)&accf[0][0];   // [16][132] shorts (4.2 KB)
#pragma unroll
        for (int i = 0; i < 4; ++i) {
            int rt = quad * 4 + i;
            int row = n0 + rt;
            float dv = dinv[row];
            float v[8]; float s = 0.f, q = 0.f;
#pragma unroll
            for (int b = 0; b < 8; ++b) { float x = acc[b][i] * dv + b_s[b]; v[b] = x; s += x; q += x * x; }
#pragma unroll
            for (int o = 1; o < 16; o <<= 1) { s += __shfl_xor(s, o, 64); q += __shfl_xor(q, o, 64); }
            float m  = s * (1.0f / 128.0f);
            float vr = q * (1.0f / 128.0f) - m * m;
            float rs = rsqrtf(vr + 1e-5f);
            if ((quad >> 1) == wave) {   // own-half rows only (avoid LDS write race)
#pragma unroll
                for (int b = 0; b < 8; ++b)
                    hsh[rt * 132 + b * 16 + ln] = f2bf((v[b] - m) * rs * g_s[b] + e_s[b]);
            }
        }
        __syncthreads();

        // 2) gate MFMA: gacc = cur@gw0 + hnew@gw1  (B from L2, A from global/LDS)
        //    D row r depends only on A row r -> cross-wave cur write overlap benign.
        f32x4 gacc[8] = {};
#pragma unroll
        for (int c = 0; c < 4; ++c) {
            short8 ac = *(const short8*)(curg + (size_t)(n0 + ln) * 128 + c * 32 + quad * 8);
            short8 ah = *(const short8*)&hsh[ln * 132 + c * 32 + quad * 8];
#pragma unroll
            for (int b = 0; b < 8; ++b) {
                short8 w0 = *(const short8*)(Gw + ((size_t)(c * 8 + b) * 64 + lane) * 8);
                short8 w1 = *(const short8*)(Gw + 16384 + ((size_t)(c * 8 + b) * 64 + lane) * 8);
                gacc[b] = __builtin_amdgcn_mfma_f32_16x16x32_bf16(ac, w0, gacc[b], 0, 0, 0);
                gacc[b] = __builtin_amdgcn_mfma_f32_16x16x32_bf16(ah, w1, gacc[b], 0, 0, 0);
            }
        }

        float gb_s[8];
#pragma unroll
        for (int b = 0; b < 8; ++b) gb_s[b] = gb[b * 16 + ln];
        float dt = 0.f, rw = 0.f;
        if (EPI >= 2) { dt = scal[1]; rw = rwp[0]; }
        const float cn  = (EPI == 4) ? dt : 0.5f * dt;   // S==3 -> dt
        const float w16 = dt * (1.f / 6.f), w13 = dt * (1.f / 3.f);

#pragma unroll
        for (int i = 0; i < 4; ++i) {
            int rt = quad * 4 + i;
            int row = n0 + rt;
            if ((quad >> 1) == wave) {
                float dv = dinv[row];
#pragma unroll
                for (int b = 0; b < 8; ++b) {
                    size_t idx = (size_t)row * 128 + b * 16 + ln;
                    float hn = bf2f(hsh[rt * 132 + b * 16 + ln]);
                    float g  = sigm(gacc[b][i] + gb_s[b]);
                    float cu = bf2f(curg[idx]);
                    float r  = g * hn + (1.f - g) * cu;
                    if (EPI == 1) {
                        out[idx]  = f2bf(r);
                        out8[idx] = e2fp8(r * dv);
                    } else {
                        float tv = tanhf(r) + rw * bf2f(fin[idx]);
                        float yv;
                        if (EPI == 5) {      // S=4: final combine, skip tv/y8 stores
                            yv = bf2f(h0[idx]) + w16 * (bf2f(tv1[idx]) + tv)
                                               + w13 * (bf2f(tv2[idx]) + bf2f(tv3[idx]));
                        } else {
                            if (EPI == 2) tv1[idx] = f2bf(tv);
                            if (EPI == 3) tv2[idx] = f2bf(tv);
                            if (EPI == 4) tv3[idx] = f2bf(tv);
                            yv = bf2f(h0[idx]) + cn * tv;
                        }
                        out[idx] = f2bf(yv);
                        if (EPI != 5) out8[idx] = e2fp8(yv * dv);
                    }
                }
            }
        }
    }
}

// ---------- pooling, two-phase (pool1 writes all 8 groups -> no memset needed) ----------
__global__ __launch_bounds__(128) void k_pool1(
    const unsigned short* __restrict__ h, const int* __restrict__ batch,
    float* __restrict__ partial)
{
    int c = threadIdx.x, b = blockIdx.x;
    int r0 = b * (NN / PB), r1 = r0 + (NN / PB);
    float acc = 0.f;
    int gfirst = batch[r0], g = gfirst;
#pragma unroll 4
    for (int r = r0; r < r1; ++r) {
        int gg = batch[r];
        if (gg != g) {
            partial[(size_t)b * 1024 + g * 128 + c] = acc;
            for (int z = g + 1; z < gg; ++z) partial[(size_t)b * 1024 + z * 128 + c] = 0.f;
            acc = 0.f; g = gg;
        }
        acc += bf2f(h[(size_t)r * 128 + c]);
    }
    partial[(size_t)b * 1024 + g * 128 + c] = acc;
    for (int z = 0; z < gfirst; ++z)  partial[(size_t)b * 1024 + z * 128 + c] = 0.f;
    for (int z = g + 1; z < GG; ++z)  partial[(size_t)b * 1024 + z * 128 + c] = 0.f;
}

__global__ __launch_bounds__(256) void k_pool2(
    const float* __restrict__ partial, const int* __restrict__ st,
    float* __restrict__ out)
{
    __shared__ float sh[8][32];
    int cb = blockIdx.x & 3, g = blockIdx.x >> 2;
    int cl = threadIdx.x & 31, sl = threadIdx.x >> 5;
    int c = cb * 32 + cl;
    float s = 0.f;
    for (int b = sl; b < PB; b += 8) s += partial[(size_t)b * 1024 + g * 128 + c];
    sh[sl][cl] = s; __syncthreads();
    if (sl == 0) {
        float tt = 0.f;
#pragma unroll
        for (int i = 0; i < 8; ++i) tt += sh[i][cl];
        int cnt = st[g + 1] - st[g];
        out[g * 128 + c] = tt / (float)(cnt > 0 ? cnt : 1);
    }
}

// ---------- host ----------
static inline size_t al(size_t x) { return (x + 255) & ~(size_t)255; }

extern "C" void kernel_launch(void* const* d_in, const int* in_sizes, int n_in,
                              void* d_out, int out_size, void* d_ws, size_t ws_size,
                              hipStream_t stream)
{
    const float* x       = (const float*)d_in[0];
    const int*   ei      = (const int*)d_in[1];
    const int*   batch   = (const int*)d_in[2];
    const float* in_w    = (const float*)d_in[3];
    const float* in_b    = (const float*)d_in[4];
    const float* in_lng  = (const float*)d_in[5];
    const float* in_lnb  = (const float*)d_in[6];
    const float* meth    = (const float*)d_in[7];
    const float* histn   = (const float*)d_in[8];
    const float* logd    = (const float*)d_in[9];
    const float* gcn_w   = (const float*)d_in[10];
    const float* gcn_b   = (const float*)d_in[11];
    const float* ln_g    = (const float*)d_in[12];
    const float* ln_b    = (const float*)d_in[13];
    const float* gate_w  = (const float*)d_in[14];
    const float* gate_b  = (const float*)d_in[15];
    const float* rw      = (const float*)d_in[16];
    const float* out_w   = (const float*)d_in[17];
    const float* out_b   = (const float*)d_in[18];
    const float* out_lng = (const float*)d_in[19];
    const float* out_lnb = (const float*)d_in[20];
    float* out = (float*)d_out;

    char* w = (char*)d_ws;
    size_t off = 0;
    float* scal   = (float*)(w + off); off += al(16 * 4);
    int*   hist   = (int*)(w + off);   off += al((size_t)NN * 4);
    int*   rp     = (int*)(w + off);   off += al((size_t)(NN + 1) * 4);
    int*   cursor = (int*)(w + off);   off += al((size_t)(NN + 1) * 4);
    int*   aux    = (int*)(w + off);   off += al(64 * 4);
    int*   st     = (int*)(w + off);   off += al(16 * 4);
    float* dinv   = (float*)(w + off); off += al((size_t)NN * 4);
    unsigned* ew  = (unsigned*)(w + off); off += al((size_t)(EE + 128) * 4);
    float* partial= (float*)(w + off); off += al((size_t)PB * 1024 * 4);
    // packed bf16 weights: [in | gcn0 | gcn1 | gcn2 | gate0 | gate1 | out] contiguous
    unsigned short* wpak = (unsigned short*)(w + off); off += al((size_t)(8192 + 6 * 16384) * 2);
    unsigned short* inwp  = wpak;
    unsigned short* gcnwp = wpak + 8192;
    unsigned short* gwp   = wpak + 8192 + 3 * 16384;
    unsigned short* owp   = wpak + 8192 + 5 * 16384;
    // bf16 activations
    size_t B16 = al((size_t)NN * 128 * 2);
    unsigned short* xb  = (unsigned short*)(w + off); off += al((size_t)NN * 64 * 2);
    unsigned short* h0  = (unsigned short*)(w + off); off += B16;
    unsigned short* y   = (unsigned short*)(w + off); off += B16;
    unsigned short* cur = (unsigned short*)(w + off); off += B16;
    unsigned short* t2  = (unsigned short*)(w + off); off += B16;
    // bf16 RK4 slope buffers
    unsigned short* tv1 = (unsigned short*)(w + off); off += B16;
    unsigned short* tv2 = (unsigned short*)(w + off); off += B16;
    unsigned short* tv3 = (unsigned short*)(w + off); off += B16;
    // fp8 gather shadows (pre-scaled by dinv[node])
    size_t B8 = al((size_t)NN * 128);
    unsigned char* h08  = (unsigned char*)(w + off); off += B8;
    unsigned char* y8   = (unsigned char*)(w + off); off += B8;
    unsigned char* cur8 = (unsigned char*)(w + off); off += B8;
    unsigned char* t28  = (unsigned char*)(w + off); off += B8;
    if (off > ws_size) return;

    hipMemsetAsync(hist, 0, (size_t)NN * 4, stream);

    // setup+bounds, merged pack, x conversion (independent)
    k_setup<<<2, 64, 0, stream>>>(meth, histn, logd, scal, batch, st);
    k_packall<<<(8192 + 6 * 16384 + 255) / 256, 256, 0, stream>>>(in_w, gcn_w, gate_w, out_w, wpak);
    k_cvtx<<<3125, 256, 0, stream>>>(x, xb);

    // CSR build (scan_c also initializes cursor — no memcpy)
    k_hist<<<(EE + 255) / 256, 256, 0, stream>>>(ei, hist);
    k_dinv<<<(NN + 255) / 256, 256, 0, stream>>>(hist, dinv);
    k_scan_a<<<49, 256, 0, stream>>>(hist, aux);
    k_scan_b<<<1, 1, 0, stream>>>(aux, 49);
    k_scan_c<<<49, 256, 0, stream>>>(hist, aux, rp, cursor);
    k_scatter<<<SB, 256, 0, stream>>>(ei, cursor, ew);

    const int DG = (NN + 63) / 64;     // 782 blocks (dense)
    const int SG = (NN + 15) / 16;     // 3125 blocks (spgemm)
    k_dense_mfma<2, 1><<<DG, 256, 0, stream>>>(xb, inwp, in_b, in_lng, in_lnb, scal, dinv, h0, h08);

    for (int s = 1; s <= 4; ++s) {
        const unsigned short* fin = (s == 1) ? h0 : y;
        const unsigned char*  fin8 = (s == 1) ? h08 : y8;
        // layer 0: plain
        k_spgemm<0><<<SG, 128, 0, stream>>>(rp, ew, fin8, gcnwp, gcn_b, ln_g, ln_b, dinv,
                                            (const unsigned short*)0, (const float*)0,
                                            (const unsigned short*)0, (const unsigned short*)0,
                                            (const unsigned short*)0, (unsigned short*)0,
                                            (unsigned short*)0, (unsigned short*)0,
                                            (const float*)0, (const float*)0, cur, cur8);
        // layer 1: fused gate vs cur -> t2/t28 (fresh buffers: no gather race)
        k_spgemm<1><<<SG, 128, 0, stream>>>(rp, ew, cur8,
                                            gcnwp + (size_t)1 * 128 * 128, gcn_b + 128,
                                            ln_g + 128, ln_b + 128, dinv,
                                            gwp, gate_b, cur,
                                            (const unsigned short*)0, (const unsigned short*)0,
                                            (unsigned short*)0, (unsigned short*)0, (unsigned short*)0,
                                            (const float*)0, (const float*)0, t2, t28);
        // layer 2: fused gate vs t2 + RK4 stage s -> y/y8 (+tv_s)
        if (s == 1)
            k_spgemm<2><<<SG, 128, 0, stream>>>(rp, ew, t28,
                gcnwp + (size_t)2 * 128 * 128, gcn_b + 256, ln_g + 256, ln_b + 256, dinv,
                gwp, gate_b, t2, fin, h0, tv1, tv2, tv3, scal, rw, y, y8);
        else if (s == 2)
            k_spgemm<3><<<SG, 128, 0, stream>>>(rp, ew, t28,
                gcnwp + (size_t)2 * 128 * 128, gcn_b + 256, ln_g + 256, ln_b + 256, dinv,
                gwp, gate_b, t2, fin, h0, tv1, tv2, tv3, scal, rw, y, y8);
        else if (s == 3)
            k_spgemm<4><<<SG, 128, 0, stream>>>(rp, ew, t28,
                gcnwp + (size_t)2 * 128 * 128, gcn_b + 256, ln_g + 256, ln_b + 256, dinv,
                gwp, gate_b, t2, fin, h0, tv1, tv2, tv3, scal, rw, y, y8);
        else
            k_spgemm<5><<<SG, 128, 0, stream>>>(rp, ew, t28,
                gcnwp + (size_t)2 * 128 * 128, gcn_b + 256, ln_g + 256, ln_b + 256, dinv,
                gwp, gate_b, t2, fin, h0, tv1, tv2, tv3, scal, rw, y, y8);
    }

    // output projection + pool
    k_dense_mfma<4, 0><<<DG, 256, 0, stream>>>(y, owp, out_b, out_lng, out_lnb, scal, dinv, t2, (unsigned char*)0);
    k_pool1<<<PB, 128, 0, stream>>>(t2, batch, partial);
    k_pool2<<<GG * 4, 256, 0, stream>>>(partial, st, out);
}

// Round 10
// 914.091 us; speedup vs baseline: 1.1761x; 1.1761x over previous
//
#include <hip/hip_runtime.h>
#include <math.h>

#define NN 50000
#define EE 800000
#define HH 128
#define FF 64
#define GG 8
#define PB 500      // pool phase-1 blocks (covers 100 rows each)
#define SB 1600     // scatter blocks: 200 per dst-group, 8 groups

using short8 = __attribute__((ext_vector_type(8))) short;
using f32x4  = __attribute__((ext_vector_type(4))) float;
using f32x2  = __attribute__((ext_vector_type(2))) float;

__device__ __forceinline__ float sigm(float x){ return 1.0f/(1.0f+expf(-x)); }
__device__ __forceinline__ unsigned short f2bf(float f){
    union { float f; unsigned u; } v; v.f = f;
    unsigned r = v.u + 0x7fff + ((v.u >> 16) & 1);
    return (unsigned short)(r >> 16);
}
__device__ __forceinline__ float bf2f(unsigned short h){
    union { unsigned u; float f; } v; v.u = ((unsigned)h) << 16;
    return v.f;
}

// ---------- fp8 helpers (HW cvt on gfx950; self-consistent either format) ----------
#if __has_builtin(__builtin_amdgcn_cvt_pk_fp8_f32) && __has_builtin(__builtin_amdgcn_cvt_pk_f32_fp8)
#define FP8_HW 1
#else
#define FP8_HW 0
#endif

__device__ __forceinline__ unsigned fp8enc1_sw(float f){
    union { float fl; unsigned u; } x; x.fl = f;
    unsigned s = (x.u >> 31) << 7;
    float a = fabsf(f);
    if (!(a > 0.f)) return s;
    if (a >= 448.f) return s | 0x7E;
    if (a < 0.015625f) {
        int q = (int)(a * 512.f + 0.5f);
        if (q > 7) return s | (1u << 3);
        return s | (unsigned)q;
    }
    unsigned u = x.u + (1u << 19);          // round at 3-bit mantissa
    int e32 = (int)((u >> 23) & 255) - 127;
    if (e32 < -6) { int q=(int)(a*512.f+0.5f); if(q>7)q=7; return s|(unsigned)q; }
    if (e32 > 8) return s | 0x7E;
    unsigned m = (u >> 20) & 7;
    return s | ((unsigned)(e32 + 7) << 3) | m;
}
__device__ __forceinline__ float fp8dec1_sw(unsigned v){
    unsigned s = v >> 7, e = (v >> 3) & 15, m = v & 7;
    float f;
    if (e == 0) f = (float)m * 0.001953125f;
    else { union { unsigned u; float fl; } x; x.u = ((e + 120u) << 23) | (m << 20); f = x.fl; }
    return s ? -f : f;
}
__device__ __forceinline__ unsigned char e2fp8(float a){
#if FP8_HW
    return (unsigned char)(__builtin_amdgcn_cvt_pk_fp8_f32(a, a, 0, false) & 0xFF);
#else
    return (unsigned char)fp8enc1_sw(a);
#endif
}
__device__ __forceinline__ float2 d2fp8(unsigned short u){
#if FP8_HW
    f32x2 r = __builtin_amdgcn_cvt_pk_f32_fp8((int)(unsigned)u, false);
    return make_float2(r[0], r[1]);
#else
    return make_float2(fp8dec1_sw(u & 0xFF), fp8dec1_sw((u >> 8) & 0xFF));
#endif
}

// ---------- setup (block 0) + graph bounds (block 1) ----------
__global__ void k_setup(const float* __restrict__ meth,
                        const float* __restrict__ histones,
                        const float* __restrict__ logd,
                        float* __restrict__ scal,
                        const int* __restrict__ batch, int* __restrict__ st)
{
    if (blockIdx.x == 1) {
        int g = threadIdx.x;
        if (g > GG) return;
        int lo = 0, hi = NN;
        while (lo < hi) { int mid = (lo + hi) >> 1; if (batch[mid] < g) lo = mid + 1; else hi = mid; }
        st[g] = lo;
        return;
    }
    int l = threadIdx.x;
    float s = sigm(meth[l]) + sigm(meth[l + 64]);
#pragma unroll
    for (int o = 32; o >= 1; o >>= 1) s += __shfl_xor(s, o, 64);
    if (l == 0) {
        float msil = s * (1.0f / 128.0f);
        float h0 = sigm(histones[0]), h1 = sigm(histones[1]);
        float h2 = sigm(histones[2]), h3 = sigm(histones[3]);
        float act = (h0 + h2) * 0.5f, rep = (h1 + h3) * 0.5f;
        float chrom = fminf(fmaxf(act - rep + 0.5f, 0.0f), 1.0f);
        scal[0] = chrom * (1.0f - msil);
        float d = expf(logd[0]);
        scal[1] = fminf(fmaxf(d, 0.1f), 3.0f);   // dt
    }
}

// ---------- single merged weight pack: all 7 matrices -> one contiguous bf16 buffer ----------
__global__ void k_packall(const float* __restrict__ in_w, const float* __restrict__ gcn_w,
                          const float* __restrict__ gate_w, const float* __restrict__ out_w,
                          unsigned short* __restrict__ outp)
{
    int i = blockIdx.x * 256 + threadIdx.x;
    if (i >= 8192 + 6 * 16384) return;
    const float* src; int base, li;
    if (i < 8192) { src = in_w + i; base = 0; li = i; }
    else {
        int j = i - 8192;
        int m = j >> 14, r = j & 16383;
        base = 8192 + (m << 14); li = r;
        if (m < 3)      src = gcn_w  + m * 16384 + r;
        else if (m < 5) src = gate_w + (m - 3) * 16384 + r;
        else            src = out_w + r;
    }
    int k = li >> 7, n = li & 127;
    int c = k >> 5, kl = k & 31, q = kl >> 3, j2 = kl & 7;
    int b = n >> 4, ln = n & 15;
    int lane = q * 16 + ln;
    outp[base + ((c * 8 + b) * 64 + lane) * 8 + j2] = f2bf(*src);
}

// ---------- CSR build ----------
__global__ void k_hist(const int* __restrict__ ei, int* __restrict__ hist)
{
    int e = blockIdx.x * 256 + threadIdx.x;
    if (e < EE) atomicAdd(&hist[ei[EE + e]], 1);
}

__global__ void k_dinv(const int* __restrict__ hist, float* __restrict__ dinv)
{
    int n = blockIdx.x * 256 + threadIdx.x;
    if (n < NN) {
        int d = hist[n];
        dinv[n] = d > 0 ? rsqrtf((float)d) : 0.0f;
    }
}

__global__ void k_scan_a(const int* __restrict__ hist, int* __restrict__ aux)
{
    __shared__ int sh[256];
    int b = blockIdx.x, t = threadIdx.x;
    int base = b * 1024 + t * 4;
    int s = 0;
#pragma unroll
    for (int j = 0; j < 4; ++j) { int i = base + j; if (i < NN) s += hist[i]; }
    sh[t] = s; __syncthreads();
    for (int o = 128; o >= 1; o >>= 1) { if (t < o) sh[t] += sh[t + o]; __syncthreads(); }
    if (t == 0) aux[b] = sh[0];
}

__global__ void k_scan_b(int* __restrict__ aux, int nb)
{
    if (blockIdx.x == 0 && threadIdx.x == 0) {
        int run = 0;
        for (int i = 0; i < nb; ++i) { int v = aux[i]; aux[i] = run; run += v; }
    }
}

// writes BOTH row_ptr and cursor (folds the old cursor memcpy away)
__global__ void k_scan_c(const int* __restrict__ hist, const int* __restrict__ aux,
                         int* __restrict__ row_ptr, int* __restrict__ cursor)
{
    __shared__ int sh[256];
    int b = blockIdx.x, t = threadIdx.x;
    int base = b * 1024 + t * 4;
    int v[4]; int s = 0;
#pragma unroll
    for (int j = 0; j < 4; ++j) { int i = base + j; v[j] = (i < NN) ? hist[i] : 0; s += v[j]; }
    sh[t] = s; __syncthreads();
    for (int o = 1; o < 256; o <<= 1) {
        int x = 0; if (t >= o) x = sh[t - o];
        __syncthreads(); sh[t] += x; __syncthreads();
    }
    int run = aux[b] + sh[t] - s;
#pragma unroll
    for (int j = 0; j < 4; ++j) {
        int i = base + j;
        if (i < NN) { row_ptr[i] = run; cursor[i] = run; }
        run += v[j];
    }
    if (b == 0 && t == 0) { row_ptr[NN] = EE; cursor[NN] = EE; }
}

// ---------- XCD-aligned dst-partitioned scatter, 4-byte records, nt streams ----------
// Verified rounds 5-8: 42 µs (FETCH 25 MB from 8x dst-read replication — L3
// does NOT absorb it; WRITE 31 MB; nt hints don't prevent L2 allocation).
__global__ __launch_bounds__(256) void k_scatter(const int* __restrict__ ei,
                          int* __restrict__ cursor, unsigned* __restrict__ ew)
{
    if (blockIdx.x == 0 && threadIdx.x < 128)    // tail pads for spgemm prefetch
        ew[EE + threadIdx.x] = 0u;
    const int grp = blockIdx.x & 7;
    const int blk = blockIdx.x >> 3;             // 0..SB/8-1
    const int CH  = EE / (SB / 8);               // 4000
    const int e0 = blk * CH, e1 = e0 + CH;
    const int glo = grp * (NN / 8), ghi = glo + (NN / 8);
    for (int e = e0 + threadIdx.x; e < e1; e += 256) {
        int d = __builtin_nontemporal_load(ei + EE + e);
        if (d >= glo && d < ghi) {
            int s = __builtin_nontemporal_load(ei + e);
            int p = atomicAdd(&cursor[d], 1);
            ew[p] = (unsigned)s | ((unsigned)(d & 15) << 16);
        }
    }
}

// ---------- MFMA dense (LDS-staged W): out = [relu(]LN(A@W+b)[)*sc] (+scaled fp8 shadow) ----------
// F32A=1: A is fp32 (raw input x), converted to bf16 in registers — this
// fuses the old k_cvtx pass away (round 10: saves a 3125-block launch and
// ~13 MB of xb round-trip traffic; numerics identical, same f2bf rounding).
// fp8 shadow = dinv[row] * value (spgemm gather sources are pre-scaled)
template<int KC, int MODE, int F32A>
__global__ __launch_bounds__(256) void k_dense_mfma(
    const void* __restrict__ A, const unsigned short* __restrict__ Wp,
    const float* __restrict__ bias, const float* __restrict__ lng,
    const float* __restrict__ lnb, const float* __restrict__ scal,
    const float* __restrict__ dinv,
    unsigned short* __restrict__ out, unsigned char* __restrict__ out8)
{
    __shared__ unsigned short Ws[KC * 4096];
    const int t = threadIdx.x;
    {
        const float4* src = (const float4*)Wp;
        float4* dst = (float4*)Ws;
#pragma unroll
        for (int i = 0; i < KC * 2; ++i) dst[t + i * 256] = src[t + i * 256];
    }
    __syncthreads();
    const int wave = t >> 6, lane = t & 63;
    const int quad = lane >> 4, ln = lane & 15;
    const int r0 = blockIdx.x * 64 + wave * 16;
    const int K = KC * 32;
    const int arow = r0 + ln;
    const bool av = arow < NN;

    f32x4 acc[8] = {};
#pragma unroll
    for (int c = 0; c < KC; ++c) {
        short8 a = {};
        if (av) {
            if (F32A) {
                const float* Af = (const float*)A + (size_t)arow * K + c * 32 + quad * 8;
                float4 f0 = *(const float4*)(Af);
                float4 f1 = *(const float4*)(Af + 4);
                a[0] = (short)f2bf(f0.x); a[1] = (short)f2bf(f0.y);
                a[2] = (short)f2bf(f0.z); a[3] = (short)f2bf(f0.w);
                a[4] = (short)f2bf(f1.x); a[5] = (short)f2bf(f1.y);
                a[6] = (short)f2bf(f1.z); a[7] = (short)f2bf(f1.w);
            } else {
                a = *(const short8*)((const unsigned short*)A + (size_t)arow * K + c * 32 + quad * 8);
            }
        }
#pragma unroll
        for (int b = 0; b < 8; ++b) {
            short8 bb = *(const short8*)&Ws[((c * 8 + b) * 64 + lane) * 8];
            acc[b] = __builtin_amdgcn_mfma_f32_16x16x32_bf16(a, bb, acc[b], 0, 0, 0);
        }
    }

    float b_s[8], g_s[8], e_s[8];
#pragma unroll
    for (int b = 0; b < 8; ++b) {
        int col = b * 16 + ln;
        b_s[b] = bias[col]; g_s[b] = lng[col]; e_s[b] = lnb[col];
    }
    float sc = (MODE == 1) ? scal[0] : 0.0f;
#pragma unroll
    for (int i = 0; i < 4; ++i) {
        int row = r0 + quad * 4 + i;
        float v[8]; float s = 0.f, q = 0.f;
#pragma unroll
        for (int b = 0; b < 8; ++b) { float x = acc[b][i] + b_s[b]; v[b] = x; s += x; q += x * x; }
#pragma unroll
        for (int o = 1; o < 16; o <<= 1) { s += __shfl_xor(s, o, 64); q += __shfl_xor(q, o, 64); }
        float m  = s * (1.0f / 128.0f);
        float vr = q * (1.0f / 128.0f) - m * m;
        float rs = rsqrtf(vr + 1e-5f);
        if (row < NN) {
            float dv = out8 ? dinv[row] : 0.f;
#pragma unroll
            for (int b = 0; b < 8; ++b) {
                float o2 = (v[b] - m) * rs * g_s[b] + e_s[b];
                if (MODE == 1) o2 = fmaxf(o2, 0.f) * sc;
                out[(size_t)row * 128 + b * 16 + ln] = f2bf(o2);
                if (out8) out8[(size_t)row * 128 + b * 16 + ln] = e2fp8(o2 * dv);
            }
        }
    }
}

// ---------- fused SpMM + GEMM + LN (fp8 gather; 2 half-wave edge tracks) ----------
// Wave owns 8 CSR-contiguous nodes. Half h = lane>>5 processes edges e+2j+h;
// lane covers 4 fp8 cols. Plain-store flushes into per-half buffers.
// PIPELINE DEPTH IS 1 (R5: 2-deep prefetch regressed ~2 µs/dispatch).
// LESSONS: no LDS atomics in hot loop (R1-2: halves throughput); no min-waves
// launch_bounds (spills); occupancy NOT LDS-capped; and do NOT fuse
// register-hungry epilogues in here (R9: gate epilogue -> VGPR 60->88,
// occupancy 30->18%, dur 67->113 µs — the gather phase's occupancy is this
// kernel's most fragile resource).
__global__ __launch_bounds__(128) void k_spgemm(
    const int* __restrict__ rp, const unsigned* __restrict__ ew,
    const unsigned char* __restrict__ X8, const unsigned short* __restrict__ Wp,
    const float* __restrict__ bias, const float* __restrict__ lng,
    const float* __restrict__ lnb, const float* __restrict__ dinv,
    unsigned short* __restrict__ out, unsigned char* __restrict__ out8)
{
    __shared__ float accf[2][16 * 132];       // per-half buffers (16.9 KB)
    const int t = threadIdx.x, wave = t >> 6, lane = t & 63;
    const int quad = lane >> 4, ln = lane & 15;
    const int half = lane >> 5, li = lane & 31;
    const int n0 = blockIdx.x * 16;
    const int nf = n0 + wave * 8;

    // zero own rows in both half-buffers (own-wave rows only)
    {
        float* z0 = &accf[0][wave * 8 * 132];
        float* z1 = &accf[1][wave * 8 * 132];
        for (int i = lane; i < 8 * 132; i += 64) { z0[i] = 0.f; z1[i] = 0.f; }
    }

    if (nf < NN) {
        const int nl = min(nf + 8, NN);
        const int ebeg = __builtin_amdgcn_readfirstlane(rp[nf]);
        const int eend = __builtin_amdgcn_readfirstlane(rp[nl]);
        if (ebeg < eend) {
            float4 racc = make_float4(0.f, 0.f, 0.f, 0.f);
            int curd = (int)((ew[min(ebeg + half, eend - 1)] >> 16) & 15u);
            const unsigned char* Xl = X8 + li * 4;
            unsigned rec[8], recN[8], g[8];
#pragma unroll
            for (int j = 0; j < 8; ++j) rec[j]  = ew[ebeg + 2 * j + half];        // pad-safe
#pragma unroll
            for (int j = 0; j < 8; ++j) recN[j] = ew[ebeg + 16 + 2 * j + half];   // pad-safe
#pragma unroll
            for (int j = 0; j < 8; ++j) {
                int src = (int)(rec[j] & 0xFFFFu);
                g[j] = *(const unsigned*)(Xl + (size_t)src * 128);
            }
            for (int e = ebeg; e < eend; e += 16) {
                // issue next round's gathers + round-after-next records
                unsigned gN[8], recNN[8];
#pragma unroll
                for (int j = 0; j < 8; ++j) {
                    int src = (int)(recN[j] & 0xFFFFu);
                    gN[j] = *(const unsigned*)(Xl + (size_t)src * 128);
                }
#pragma unroll
                for (int j = 0; j < 8; ++j) recNN[j] = ew[e + 32 + 2 * j + half]; // pad-safe
                // consume current round (waits only on g)
                int lim = eend - e;
                int mj = lim > half ? ((lim - half + 1) >> 1) : 0; if (mj > 8) mj = 8;
#pragma unroll
                for (int j = 0; j < 8; ++j) {
                    if (j >= mj) break;                  // half-uniform (tail only)
                    int dl = (int)((rec[j] >> 16) & 15u);
                    if (dl != curd) {                    // half-uniform, 1 store
                        *(float4*)&accf[half][curd * 132 + li * 4] = racc;
                        racc = make_float4(0.f, 0.f, 0.f, 0.f);
                        curd = dl;
                    }
                    float2 p0 = d2fp8((unsigned short)(g[j] & 0xFFFFu));
                    float2 p1 = d2fp8((unsigned short)(g[j] >> 16));
                    racc.x += p0.x;
                    racc.y += p0.y;
                    racc.z += p1.x;
                    racc.w += p1.y;
                }
#pragma unroll
                for (int j = 0; j < 8; ++j) { rec[j] = recN[j]; recN[j] = recNN[j]; g[j] = gN[j]; }
            }
            *(float4*)&accf[half][curd * 132 + li * 4] = racc;   // final flush
        }
    }
    __syncthreads();

    // MFMA phase (redundant across the 2 waves): A = accf[0]+accf[1], B from L2
    f32x4 acc[8] = {};
    const float* ar0 = &accf[0][(size_t)ln * 132];
    const float* ar1 = &accf[1][(size_t)ln * 132];
#pragma unroll
    for (int c = 0; c < 4; ++c) {
        float4 a0 = *(const float4*)(ar0 + c * 32 + quad * 8);
        float4 a1 = *(const float4*)(ar0 + c * 32 + quad * 8 + 4);
        float4 b0 = *(const float4*)(ar1 + c * 32 + quad * 8);
        float4 b1 = *(const float4*)(ar1 + c * 32 + quad * 8 + 4);
        short8 af;
        af[0] = (short)f2bf(a0.x + b0.x); af[1] = (short)f2bf(a0.y + b0.y);
        af[2] = (short)f2bf(a0.z + b0.z); af[3] = (short)f2bf(a0.w + b0.w);
        af[4] = (short)f2bf(a1.x + b1.x); af[5] = (short)f2bf(a1.y + b1.y);
        af[6] = (short)f2bf(a1.z + b1.z); af[7] = (short)f2bf(a1.w + b1.w);
#pragma unroll
        for (int b = 0; b < 8; ++b) {
            short8 bb = *(const short8*)(Wp + ((size_t)(c * 8 + b) * 64 + lane) * 8);
            acc[b] = __builtin_amdgcn_mfma_f32_16x16x32_bf16(af, bb, acc[b], 0, 0, 0);
        }
    }

    float b_s[8], g_s[8], e_s[8];
#pragma unroll
    for (int b = 0; b < 8; ++b) {
        int col = b * 16 + ln;
        b_s[b] = bias[col]; g_s[b] = lng[col]; e_s[b] = lnb[col];
    }
#pragma unroll
    for (int i = 0; i < 4; ++i) {
        int row = n0 + quad * 4 + i;
        float dv = (row < NN) ? dinv[row] : 0.f;   // dinv[dst] factor of enorm
        float v[8]; float s = 0.f, q = 0.f;
#pragma unroll
        for (int b = 0; b < 8; ++b) { float x = acc[b][i] * dv + b_s[b]; v[b] = x; s += x; q += x * x; }
#pragma unroll
        for (int o = 1; o < 16; o <<= 1) { s += __shfl_xor(s, o, 64); q += __shfl_xor(q, o, 64); }
        float m  = s * (1.0f / 128.0f);
        float vr = q * (1.0f / 128.0f) - m * m;
        float rs = rsqrtf(vr + 1e-5f);
        if (((quad >> 1) == wave) && row < NN) {   // each wave stores its half
#pragma unroll
            for (int b = 0; b < 8; ++b) {
                float o2 = (v[b] - m) * rs * g_s[b] + e_s[b];
                out[(size_t)row * 128 + b * 16 + ln] = f2bf(o2);
                if (out8) out8[(size_t)row * 128 + b * 16 + ln] = e2fp8(o2 * dv);
            }
        }
    }
}

// ---------- MFMA gate (LDS-staged W), writes bf16 + scaled fp8 shadow ----------
// ROUND-6 LESSON: keep the LDS staging. Reading W per-MFMA from L2 puts a
// vmcnt wait in front of every MFMA and serializes the accumulator chain on
// ~200-cyc L2 latency 64x/wave: +14.5 µs per gate dispatch (870->961 µs).
__global__ __launch_bounds__(256) void k_gate_mfma(
    unsigned short* __restrict__ cur, const unsigned short* __restrict__ hnew,
    const unsigned short* __restrict__ Wp, const float* __restrict__ gb,
    const float* __restrict__ dinv, unsigned char* __restrict__ cur8)
{
    __shared__ unsigned short Ws[16384];
    const int t = threadIdx.x;
    const int wave = t >> 6, lane = t & 63;
    const int quad = lane >> 4, ln = lane & 15;
    const int r0 = blockIdx.x * 64 + wave * 16;
    const int arow = r0 + ln;
    const bool av = arow < NN;

    f32x4 acc[8] = {};
#pragma unroll
    for (int s = 0; s < 2; ++s) {
        __syncthreads();
        {
            const float4* src = (const float4*)(Wp + (size_t)s * 16384);
            float4* dst = (float4*)Ws;
#pragma unroll
            for (int i = 0; i < 8; ++i) dst[t + i * 256] = src[t + i * 256];
        }
        __syncthreads();
        const unsigned short* A = s ? hnew : cur;
#pragma unroll
        for (int c = 0; c < 4; ++c) {
            short8 a = {};
            if (av) a = *(const short8*)(A + (size_t)arow * 128 + c * 32 + quad * 8);
#pragma unroll
            for (int b = 0; b < 8; ++b) {
                short8 bb = *(const short8*)&Ws[((c * 8 + b) * 64 + lane) * 8];
                acc[b] = __builtin_amdgcn_mfma_f32_16x16x32_bf16(a, bb, acc[b], 0, 0, 0);
            }
        }
    }

    float gb_s[8];
#pragma unroll
    for (int b = 0; b < 8; ++b) gb_s[b] = gb[b * 16 + ln];
#pragma unroll
    for (int i = 0; i < 4; ++i) {
        int row = r0 + quad * 4 + i;
        if (row < NN) {
            float dv = dinv[row];
#pragma unroll
            for (int b = 0; b < 8; ++b) {
                size_t idx = (size_t)row * 128 + b * 16 + ln;
                float g  = sigm(acc[b][i] + gb_s[b]);
                float cu = bf2f(cur[idx]);
                float hn = bf2f(hnew[idx]);
                float r  = g * hn + (1.f - g) * cu;
                cur[idx]  = f2bf(r);
                cur8[idx] = e2fp8(r * dv);
            }
        }
    }
}

// ---------- fused MFMA gate + RK4 stage combine (LDS-staged W) ----------
// bf16 tv_s buffers instead of fp32 acc (R8: traffic-neutral in time but
// keeps the smaller footprint); S=4 skips tv/y8 stores.
template<int S>
__global__ __launch_bounds__(256) void k_gate_fused(
    const unsigned short* __restrict__ cur, const unsigned short* __restrict__ hnew,
    const unsigned short* __restrict__ Wp, const float* __restrict__ gb,
    const unsigned short* __restrict__ fin, const unsigned short* __restrict__ h0,
    unsigned short* __restrict__ tv1, unsigned short* __restrict__ tv2,
    unsigned short* __restrict__ tv3,
    unsigned short* __restrict__ ybuf, unsigned char* __restrict__ y8,
    const float* __restrict__ scal, const float* __restrict__ rwp,
    const float* __restrict__ dinv)
{
    __shared__ unsigned short Ws[16384];
    const int t = threadIdx.x;
    const int wave = t >> 6, lane = t & 63;
    const int quad = lane >> 4, ln = lane & 15;
    const int r0 = blockIdx.x * 64 + wave * 16;
    const int arow = r0 + ln;
    const bool av = arow < NN;

    f32x4 am[8] = {};
#pragma unroll
    for (int s = 0; s < 2; ++s) {
        __syncthreads();
        {
            const float4* src = (const float4*)(Wp + (size_t)s * 16384);
            float4* dst = (float4*)Ws;
#pragma unroll
            for (int i = 0; i < 8; ++i) dst[t + i * 256] = src[t + i * 256];
        }
        __syncthreads();
        const unsigned short* A = s ? hnew : cur;
#pragma unroll
        for (int c = 0; c < 4; ++c) {
            short8 a = {};
            if (av) a = *(const short8*)(A + (size_t)arow * 128 + c * 32 + quad * 8);
#pragma unroll
            for (int b = 0; b < 8; ++b) {
                short8 bb = *(const short8*)&Ws[((c * 8 + b) * 64 + lane) * 8];
                am[b] = __builtin_amdgcn_mfma_f32_16x16x32_bf16(a, bb, am[b], 0, 0, 0);
            }
        }
    }

    float gb_s[8];
#pragma unroll
    for (int b = 0; b < 8; ++b) gb_s[b] = gb[b * 16 + ln];
    const float dt = scal[1], rw = rwp[0];
    const float cn = (S == 3) ? dt : 0.5f * dt;
    const float w16 = dt * (1.f / 6.f), w13 = dt * (1.f / 3.f);
#pragma unroll
    for (int i = 0; i < 4; ++i) {
        int row = r0 + quad * 4 + i;
        if (row < NN) {
            float dv = dinv[row];
#pragma unroll
            for (int b = 0; b < 8; ++b) {
                size_t idx = (size_t)row * 128 + b * 16 + ln;
                float g  = sigm(am[b][i] + gb_s[b]);
                float cu = bf2f(cur[idx]);
                float hn = bf2f(hnew[idx]);
                float r  = g * hn + (1.f - g) * cu;
                float tv = tanhf(r) + rw * bf2f(fin[idx]);
                float yv;
                if (S == 4) {
                    float t1 = bf2f(tv1[idx]);
                    float t2 = bf2f(tv2[idx]);
                    float t3 = bf2f(tv3[idx]);
                    yv = bf2f(h0[idx]) + w16 * (t1 + tv) + w13 * (t2 + t3);
                } else {
                    if (S == 1) tv1[idx] = f2bf(tv);
                    if (S == 2) tv2[idx] = f2bf(tv);
                    if (S == 3) tv3[idx] = f2bf(tv);
                    yv = bf2f(h0[idx]) + cn * tv;
                }
                ybuf[idx] = f2bf(yv);
                if (S != 4) y8[idx] = e2fp8(yv * dv);
            }
        }
    }
}

// ---------- pooling, two-phase (pool1 writes all 8 groups -> no memset needed) ----------
__global__ __launch_bounds__(128) void k_pool1(
    const unsigned short* __restrict__ h, const int* __restrict__ batch,
    float* __restrict__ partial)
{
    int c = threadIdx.x, b = blockIdx.x;
    int r0 = b * (NN / PB), r1 = r0 + (NN / PB);
    float acc = 0.f;
    int gfirst = batch[r0], g = gfirst;
#pragma unroll 4
    for (int r = r0; r < r1; ++r) {
        int gg = batch[r];
        if (gg != g) {
            partial[(size_t)b * 1024 + g * 128 + c] = acc;
            for (int z = g + 1; z < gg; ++z) partial[(size_t)b * 1024 + z * 128 + c] = 0.f;
            acc = 0.f; g = gg;
        }
        acc += bf2f(h[(size_t)r * 128 + c]);
    }
    partial[(size_t)b * 1024 + g * 128 + c] = acc;
    for (int z = 0; z < gfirst; ++z)  partial[(size_t)b * 1024 + z * 128 + c] = 0.f;
    for (int z = g + 1; z < GG; ++z)  partial[(size_t)b * 1024 + z * 128 + c] = 0.f;
}

__global__ __launch_bounds__(256) void k_pool2(
    const float* __restrict__ partial, const int* __restrict__ st,
    float* __restrict__ out)
{
    __shared__ float sh[8][32];
    int cb = blockIdx.x & 3, g = blockIdx.x >> 2;
    int cl = threadIdx.x & 31, sl = threadIdx.x >> 5;
    int c = cb * 32 + cl;
    float s = 0.f;
    for (int b = sl; b < PB; b += 8) s += partial[(size_t)b * 1024 + g * 128 + c];
    sh[sl][cl] = s; __syncthreads();
    if (sl == 0) {
        float tt = 0.f;
#pragma unroll
        for (int i = 0; i < 8; ++i) tt += sh[i][cl];
        int cnt = st[g + 1] - st[g];
        out[g * 128 + c] = tt / (float)(cnt > 0 ? cnt : 1);
    }
}

// ---------- host ----------
static inline size_t al(size_t x) { return (x + 255) & ~(size_t)255; }

extern "C" void kernel_launch(void* const* d_in, const int* in_sizes, int n_in,
                              void* d_out, int out_size, void* d_ws, size_t ws_size,
                              hipStream_t stream)
{
    const float* x       = (const float*)d_in[0];
    const int*   ei      = (const int*)d_in[1];
    const int*   batch   = (const int*)d_in[2];
    const float* in_w    = (const float*)d_in[3];
    const float* in_b    = (const float*)d_in[4];
    const float* in_lng  = (const float*)d_in[5];
    const float* in_lnb  = (const float*)d_in[6];
    const float* meth    = (const float*)d_in[7];
    const float* histn   = (const float*)d_in[8];
    const float* logd    = (const float*)d_in[9];
    const float* gcn_w   = (const float*)d_in[10];
    const float* gcn_b   = (const float*)d_in[11];
    const float* ln_g    = (const float*)d_in[12];
    const float* ln_b    = (const float*)d_in[13];
    const float* gate_w  = (const float*)d_in[14];
    const float* gate_b  = (const float*)d_in[15];
    const float* rw      = (const float*)d_in[16];
    const float* out_w   = (const float*)d_in[17];
    const float* out_b   = (const float*)d_in[18];
    const float* out_lng = (const float*)d_in[19];
    const float* out_lnb = (const float*)d_in[20];
    float* out = (float*)d_out;

    char* w = (char*)d_ws;
    size_t off = 0;
    float* scal   = (float*)(w + off); off += al(16 * 4);
    int*   hist   = (int*)(w + off);   off += al((size_t)NN * 4);
    int*   rp     = (int*)(w + off);   off += al((size_t)(NN + 1) * 4);
    int*   cursor = (int*)(w + off);   off += al((size_t)(NN + 1) * 4);
    int*   aux    = (int*)(w + off);   off += al(64 * 4);
    int*   st     = (int*)(w + off);   off += al(16 * 4);
    float* dinv   = (float*)(w + off); off += al((size_t)NN * 4);
    unsigned* ew  = (unsigned*)(w + off); off += al((size_t)(EE + 128) * 4);
    float* partial= (float*)(w + off); off += al((size_t)PB * 1024 * 4);
    // packed bf16 weights: [in | gcn0 | gcn1 | gcn2 | gate0 | gate1 | out] contiguous
    unsigned short* wpak = (unsigned short*)(w + off); off += al((size_t)(8192 + 6 * 16384) * 2);
    unsigned short* inwp  = wpak;
    unsigned short* gcnwp = wpak + 8192;
    unsigned short* gwp   = wpak + 8192 + 3 * 16384;
    unsigned short* owp   = wpak + 8192 + 5 * 16384;
    // bf16 activations
    size_t B16 = al((size_t)NN * 128 * 2);
    unsigned short* h0  = (unsigned short*)(w + off); off += B16;
    unsigned short* y   = (unsigned short*)(w + off); off += B16;
    unsigned short* cur = (unsigned short*)(w + off); off += B16;
    unsigned short* t2  = (unsigned short*)(w + off); off += B16;
    // bf16 RK4 slope buffers
    unsigned short* tv1 = (unsigned short*)(w + off); off += B16;
    unsigned short* tv2 = (unsigned short*)(w + off); off += B16;
    unsigned short* tv3 = (unsigned short*)(w + off); off += B16;
    // fp8 gather shadows (pre-scaled by dinv[node])
    size_t B8 = al((size_t)NN * 128);
    unsigned char* h08  = (unsigned char*)(w + off); off += B8;
    unsigned char* y8   = (unsigned char*)(w + off); off += B8;
    unsigned char* cur8 = (unsigned char*)(w + off); off += B8;
    if (off > ws_size) return;

    hipMemsetAsync(hist, 0, (size_t)NN * 4, stream);

    // setup+bounds, merged pack (independent)
    k_setup<<<2, 64, 0, stream>>>(meth, histn, logd, scal, batch, st);
    k_packall<<<(8192 + 6 * 16384 + 255) / 256, 256, 0, stream>>>(in_w, gcn_w, gate_w, out_w, wpak);

    // CSR build (scan_c also initializes cursor — no memcpy)
    k_hist<<<(EE + 255) / 256, 256, 0, stream>>>(ei, hist);
    k_dinv<<<(NN + 255) / 256, 256, 0, stream>>>(hist, dinv);
    k_scan_a<<<49, 256, 0, stream>>>(hist, aux);
    k_scan_b<<<1, 1, 0, stream>>>(aux, 49);
    k_scan_c<<<49, 256, 0, stream>>>(hist, aux, rp, cursor);
    k_scatter<<<SB, 256, 0, stream>>>(ei, cursor, ew);

    const int DG = (NN + 63) / 64;     // 782 blocks (dense/gate)
    const int SG = (NN + 15) / 16;     // 3125 blocks (spgemm)
    // input projection reads fp32 x directly (fused cvtx)
    k_dense_mfma<2, 1, 1><<<DG, 256, 0, stream>>>(x, inwp, in_b, in_lng, in_lnb, scal, dinv, h0, h08);

    for (int s = 1; s <= 4; ++s) {
        const unsigned short* fin = (s == 1) ? h0 : y;
        const unsigned char*  fin8 = (s == 1) ? h08 : y8;
        // layer 0
        k_spgemm<<<SG, 128, 0, stream>>>(rp, ew, fin8, gcnwp, gcn_b, ln_g, ln_b, dinv, cur, cur8);
        // layer 1 + gate
        k_spgemm<<<SG, 128, 0, stream>>>(rp, ew, cur8,
                                         gcnwp + (size_t)1 * 128 * 128, gcn_b + 128,
                                         ln_g + 128, ln_b + 128, dinv, t2, (unsigned char*)0);
        k_gate_mfma<<<DG, 256, 0, stream>>>(cur, t2, gwp, gate_b, dinv, cur8);
        // layer 2 + gate fused with RK4 stage combine
        k_spgemm<<<SG, 128, 0, stream>>>(rp, ew, cur8,
                                         gcnwp + (size_t)2 * 128 * 128, gcn_b + 256,
                                         ln_g + 256, ln_b + 256, dinv, t2, (unsigned char*)0);
        if (s == 1)      k_gate_fused<1><<<DG, 256, 0, stream>>>(cur, t2, gwp, gate_b, fin, h0, tv1, tv2, tv3, y, y8, scal, rw, dinv);
        else if (s == 2) k_gate_fused<2><<<DG, 256, 0, stream>>>(cur, t2, gwp, gate_b, fin, h0, tv1, tv2, tv3, y, y8, scal, rw, dinv);
        else if (s == 3) k_gate_fused<3><<<DG, 256, 0, stream>>>(cur, t2, gwp, gate_b, fin, h0, tv1, tv2, tv3, y, y8, scal, rw, dinv);
        else             k_gate_fused<4><<<DG, 256, 0, stream>>>(cur, t2, gwp, gate_b, fin, h0, tv1, tv2, tv3, y, y8, scal, rw, dinv);
    }

    // output projection + pool
    k_dense_mfma<4, 0, 0><<<DG, 256, 0, stream>>>(y, owp, out_b, out_lng, out_lnb, scal, dinv, t2, (unsigned char*)0);
    k_pool1<<<PB, 128, 0, stream>>>(t2, batch, partial);
    k_pool2<<<GG * 4, 256, 0, stream>>>(partial, st, out);
}

// Round 11
// 860.171 us; speedup vs baseline: 1.2498x; 1.0627x over previous
//
#include <hip/hip_runtime.h>
#include <math.h>

#define NN 50000
#define EE 800000
#define HH 128
#define FF 64
#define GG 8
#define PBLK 782    // pooled partials: one per dense-output block ((NN+63)/64)
#define SB 1600     // scatter blocks: 200 per dst-group, 8 groups

using short8 = __attribute__((ext_vector_type(8))) short;
using f32x4  = __attribute__((ext_vector_type(4))) float;
using f32x2  = __attribute__((ext_vector_type(2))) float;

__device__ __forceinline__ float sigm(float x){ return 1.0f/(1.0f+expf(-x)); }
__device__ __forceinline__ unsigned short f2bf(float f){
    union { float f; unsigned u; } v; v.f = f;
    unsigned r = v.u + 0x7fff + ((v.u >> 16) & 1);
    return (unsigned short)(r >> 16);
}
__device__ __forceinline__ float bf2f(unsigned short h){
    union { unsigned u; float f; } v; v.u = ((unsigned)h) << 16;
    return v.f;
}

// ---------- fp8 helpers (HW cvt on gfx950; self-consistent either format) ----------
#if __has_builtin(__builtin_amdgcn_cvt_pk_fp8_f32) && __has_builtin(__builtin_amdgcn_cvt_pk_f32_fp8)
#define FP8_HW 1
#else
#define FP8_HW 0
#endif

__device__ __forceinline__ unsigned fp8enc1_sw(float f){
    union { float fl; unsigned u; } x; x.fl = f;
    unsigned s = (x.u >> 31) << 7;
    float a = fabsf(f);
    if (!(a > 0.f)) return s;
    if (a >= 448.f) return s | 0x7E;
    if (a < 0.015625f) {
        int q = (int)(a * 512.f + 0.5f);
        if (q > 7) return s | (1u << 3);
        return s | (unsigned)q;
    }
    unsigned u = x.u + (1u << 19);          // round at 3-bit mantissa
    int e32 = (int)((u >> 23) & 255) - 127;
    if (e32 < -6) { int q=(int)(a*512.f+0.5f); if(q>7)q=7; return s|(unsigned)q; }
    if (e32 > 8) return s | 0x7E;
    unsigned m = (u >> 20) & 7;
    return s | ((unsigned)(e32 + 7) << 3) | m;
}
__device__ __forceinline__ float fp8dec1_sw(unsigned v){
    unsigned s = v >> 7, e = (v >> 3) & 15, m = v & 7;
    float f;
    if (e == 0) f = (float)m * 0.001953125f;
    else { union { unsigned u; float fl; } x; x.u = ((e + 120u) << 23) | (m << 20); f = x.fl; }
    return s ? -f : f;
}
__device__ __forceinline__ unsigned char e2fp8(float a){
#if FP8_HW
    return (unsigned char)(__builtin_amdgcn_cvt_pk_fp8_f32(a, a, 0, false) & 0xFF);
#else
    return (unsigned char)fp8enc1_sw(a);
#endif
}
__device__ __forceinline__ float2 d2fp8(unsigned short u){
#if FP8_HW
    f32x2 r = __builtin_amdgcn_cvt_pk_f32_fp8((int)(unsigned)u, false);
    return make_float2(r[0], r[1]);
#else
    return make_float2(fp8dec1_sw(u & 0xFF), fp8dec1_sw((u >> 8) & 0xFF));
#endif
}

// ---------- setup (block 0) + graph bounds (block 1) ----------
__global__ void k_setup(const float* __restrict__ meth,
                        const float* __restrict__ histones,
                        const float* __restrict__ logd,
                        float* __restrict__ scal,
                        const int* __restrict__ batch, int* __restrict__ st)
{
    if (blockIdx.x == 1) {
        int g = threadIdx.x;
        if (g > GG) return;
        int lo = 0, hi = NN;
        while (lo < hi) { int mid = (lo + hi) >> 1; if (batch[mid] < g) lo = mid + 1; else hi = mid; }
        st[g] = lo;
        return;
    }
    int l = threadIdx.x;
    float s = sigm(meth[l]) + sigm(meth[l + 64]);
#pragma unroll
    for (int o = 32; o >= 1; o >>= 1) s += __shfl_xor(s, o, 64);
    if (l == 0) {
        float msil = s * (1.0f / 128.0f);
        float h0 = sigm(histones[0]), h1 = sigm(histones[1]);
        float h2 = sigm(histones[2]), h3 = sigm(histones[3]);
        float act = (h0 + h2) * 0.5f, rep = (h1 + h3) * 0.5f;
        float chrom = fminf(fmaxf(act - rep + 0.5f, 0.0f), 1.0f);
        scal[0] = chrom * (1.0f - msil);
        float d = expf(logd[0]);
        scal[1] = fminf(fmaxf(d, 0.1f), 3.0f);   // dt
    }
}

// ---------- single merged weight pack: all 7 matrices -> one contiguous bf16 buffer ----------
__global__ void k_packall(const float* __restrict__ in_w, const float* __restrict__ gcn_w,
                          const float* __restrict__ gate_w, const float* __restrict__ out_w,
                          unsigned short* __restrict__ outp)
{
    int i = blockIdx.x * 256 + threadIdx.x;
    if (i >= 8192 + 6 * 16384) return;
    const float* src; int base, li;
    if (i < 8192) { src = in_w + i; base = 0; li = i; }
    else {
        int j = i - 8192;
        int m = j >> 14, r = j & 16383;
        base = 8192 + (m << 14); li = r;
        if (m < 3)      src = gcn_w  + m * 16384 + r;
        else if (m < 5) src = gate_w + (m - 3) * 16384 + r;
        else            src = out_w + r;
    }
    int k = li >> 7, n = li & 127;
    int c = k >> 5, kl = k & 31, q = kl >> 3, j2 = kl & 7;
    int b = n >> 4, ln = n & 15;
    int lane = q * 16 + ln;
    outp[base + ((c * 8 + b) * 64 + lane) * 8 + j2] = f2bf(*src);
}

// ---------- x fp32 -> bf16 ----------
__global__ void k_cvtx(const float* __restrict__ x, unsigned short* __restrict__ xb)
{
    size_t i = (size_t)blockIdx.x * 256 + threadIdx.x;
    if (i >= (size_t)NN * 16) return;
    float4 v = ((const float4*)x)[i];
    ushort4 o;
    o.x = f2bf(v.x); o.y = f2bf(v.y); o.z = f2bf(v.z); o.w = f2bf(v.w);
    ((ushort4*)xb)[i] = o;
}

// ---------- CSR build ----------
__global__ void k_hist(const int* __restrict__ ei, int* __restrict__ hist)
{
    int e = blockIdx.x * 256 + threadIdx.x;
    if (e < EE) atomicAdd(&hist[ei[EE + e]], 1);
}

__global__ void k_dinv(const int* __restrict__ hist, float* __restrict__ dinv)
{
    int n = blockIdx.x * 256 + threadIdx.x;
    if (n < NN) {
        int d = hist[n];
        dinv[n] = d > 0 ? rsqrtf((float)d) : 0.0f;
    }
}

__global__ void k_scan_a(const int* __restrict__ hist, int* __restrict__ aux)
{
    __shared__ int sh[256];
    int b = blockIdx.x, t = threadIdx.x;
    int base = b * 1024 + t * 4;
    int s = 0;
#pragma unroll
    for (int j = 0; j < 4; ++j) { int i = base + j; if (i < NN) s += hist[i]; }
    sh[t] = s; __syncthreads();
    for (int o = 128; o >= 1; o >>= 1) { if (t < o) sh[t] += sh[t + o]; __syncthreads(); }
    if (t == 0) aux[b] = sh[0];
}

__global__ void k_scan_b(int* __restrict__ aux, int nb)
{
    if (blockIdx.x == 0 && threadIdx.x == 0) {
        int run = 0;
        for (int i = 0; i < nb; ++i) { int v = aux[i]; aux[i] = run; run += v; }
    }
}

// writes BOTH row_ptr and cursor (folds the old cursor memcpy away)
__global__ void k_scan_c(const int* __restrict__ hist, const int* __restrict__ aux,
                         int* __restrict__ row_ptr, int* __restrict__ cursor)
{
    __shared__ int sh[256];
    int b = blockIdx.x, t = threadIdx.x;
    int base = b * 1024 + t * 4;
    int v[4]; int s = 0;
#pragma unroll
    for (int j = 0; j < 4; ++j) { int i = base + j; v[j] = (i < NN) ? hist[i] : 0; s += v[j]; }
    sh[t] = s; __syncthreads();
    for (int o = 1; o < 256; o <<= 1) {
        int x = 0; if (t >= o) x = sh[t - o];
        __syncthreads(); sh[t] += x; __syncthreads();
    }
    int run = aux[b] + sh[t] - s;
#pragma unroll
    for (int j = 0; j < 4; ++j) {
        int i = base + j;
        if (i < NN) { row_ptr[i] = run; cursor[i] = run; }
        run += v[j];
    }
    if (b == 0 && t == 0) { row_ptr[NN] = EE; cursor[NN] = EE; }
}

// ---------- XCD-aligned dst-partitioned scatter, 4-byte records, nt streams ----------
// Verified rounds 5-8: 42 µs (FETCH 25 MB from 8x dst-read replication — L3
// does NOT absorb it; WRITE 31 MB; nt hints don't prevent L2 allocation).
__global__ __launch_bounds__(256) void k_scatter(const int* __restrict__ ei,
                          int* __restrict__ cursor, unsigned* __restrict__ ew)
{
    if (blockIdx.x == 0 && threadIdx.x < 128)    // tail pads for spgemm prefetch
        ew[EE + threadIdx.x] = 0u;
    const int grp = blockIdx.x & 7;
    const int blk = blockIdx.x >> 3;             // 0..SB/8-1
    const int CH  = EE / (SB / 8);               // 4000
    const int e0 = blk * CH, e1 = e0 + CH;
    const int glo = grp * (NN / 8), ghi = glo + (NN / 8);
    for (int e = e0 + threadIdx.x; e < e1; e += 256) {
        int d = __builtin_nontemporal_load(ei + EE + e);
        if (d >= glo && d < ghi) {
            int s = __builtin_nontemporal_load(ei + e);
            int p = atomicAdd(&cursor[d], 1);
            ew[p] = (unsigned)s | ((unsigned)(d & 15) << 16);
        }
    }
}

// ---------- MFMA dense (LDS-staged W) ----------
// MODE=1: relu(LN(A@W+b))*sc -> out + scaled fp8 shadow (input projection).
// MODE=2: LN(A@W+b) pooled per-graph into partial[block][8][128] — fuses the
//   old k_pool1 away (round 11: kills the 12.8 MB t2 write + 12.8 MB re-read
//   + a launch). LDS atomics are fine HERE (cold epilogue, not the R2 hot
//   loop); pbuf reuses the Ws staging LDS after a barrier (zero LDS growth).
// NOTE (R10 lesson): keep this kernel's template/signature stable — changing
// it perturbed co-compiled kernels' regalloc (gate_fused 60->64 VGPR, +15 µs
// per dispatch, total 845->914). One added trailing arg set, same 2 params.
template<int KC, int MODE>
__global__ __launch_bounds__(256) void k_dense_mfma(
    const unsigned short* __restrict__ A, const unsigned short* __restrict__ Wp,
    const float* __restrict__ bias, const float* __restrict__ lng,
    const float* __restrict__ lnb, const float* __restrict__ scal,
    const float* __restrict__ dinv,
    unsigned short* __restrict__ out, unsigned char* __restrict__ out8,
    const int* __restrict__ batchp, float* __restrict__ partial)
{
    __shared__ unsigned short Ws[KC * 4096];
    const int t = threadIdx.x;
    {
        const float4* src = (const float4*)Wp;
        float4* dst = (float4*)Ws;
#pragma unroll
        for (int i = 0; i < KC * 2; ++i) dst[t + i * 256] = src[t + i * 256];
    }
    __syncthreads();
    const int wave = t >> 6, lane = t & 63;
    const int quad = lane >> 4, ln = lane & 15;
    const int r0 = blockIdx.x * 64 + wave * 16;
    const int K = KC * 32;
    const int arow = r0 + ln;
    const bool av = arow < NN;

    f32x4 acc[8] = {};
#pragma unroll
    for (int c = 0; c < KC; ++c) {
        short8 a = {};
        if (av) a = *(const short8*)(A + (size_t)arow * K + c * 32 + quad * 8);
#pragma unroll
        for (int b = 0; b < 8; ++b) {
            short8 bb = *(const short8*)&Ws[((c * 8 + b) * 64 + lane) * 8];
            acc[b] = __builtin_amdgcn_mfma_f32_16x16x32_bf16(a, bb, acc[b], 0, 0, 0);
        }
    }

    float* pbuf = (float*)Ws;                 // MODE==2: reuse staging LDS
    if (MODE == 2) {
        __syncthreads();                      // all waves done reading Ws
        for (int i2 = t; i2 < GG * 128; i2 += 256) pbuf[i2] = 0.f;
        __syncthreads();
    }

    float b_s[8], g_s[8], e_s[8];
#pragma unroll
    for (int b = 0; b < 8; ++b) {
        int col = b * 16 + ln;
        b_s[b] = bias[col]; g_s[b] = lng[col]; e_s[b] = lnb[col];
    }
    float sc = (MODE == 1) ? scal[0] : 0.0f;
#pragma unroll
    for (int i = 0; i < 4; ++i) {
        int row = r0 + quad * 4 + i;
        float v[8]; float s = 0.f, q = 0.f;
#pragma unroll
        for (int b = 0; b < 8; ++b) { float x = acc[b][i] + b_s[b]; v[b] = x; s += x; q += x * x; }
#pragma unroll
        for (int o = 1; o < 16; o <<= 1) { s += __shfl_xor(s, o, 64); q += __shfl_xor(q, o, 64); }
        float m  = s * (1.0f / 128.0f);
        float vr = q * (1.0f / 128.0f) - m * m;
        float rs = rsqrtf(vr + 1e-5f);
        if (row < NN) {
            if (MODE == 2) {
                int gg = batchp[row];
#pragma unroll
                for (int b = 0; b < 8; ++b) {
                    float o2 = (v[b] - m) * rs * g_s[b] + e_s[b];
                    atomicAdd(&pbuf[gg * 128 + b * 16 + ln], o2);
                }
            } else {
                float dv = out8 ? dinv[row] : 0.f;
#pragma unroll
                for (int b = 0; b < 8; ++b) {
                    float o2 = (v[b] - m) * rs * g_s[b] + e_s[b];
                    if (MODE == 1) o2 = fmaxf(o2, 0.f) * sc;
                    out[(size_t)row * 128 + b * 16 + ln] = f2bf(o2);
                    if (out8) out8[(size_t)row * 128 + b * 16 + ln] = e2fp8(o2 * dv);
                }
            }
        }
    }

    if (MODE == 2) {
        __syncthreads();
        ((float4*)(partial + (size_t)blockIdx.x * 1024))[t] = ((const float4*)pbuf)[t];
    }
}

// ---------- fused SpMM + GEMM + LN (fp8 gather; 2 half-wave edge tracks) ----------
// Wave owns 8 CSR-contiguous nodes. Half h = lane>>5 processes edges e+2j+h;
// lane covers 4 fp8 cols. Plain-store flushes into per-half buffers.
// PIPELINE DEPTH IS 1 (R5: 2-deep prefetch regressed ~2 µs/dispatch).
// LESSONS: no LDS atomics in hot loop (R1-2: halves throughput); no min-waves
// launch_bounds (spills); occupancy NOT LDS-capped; do NOT fuse
// register-hungry epilogues in here (R9: gate epilogue -> VGPR 60->88,
// occupancy 30->18%, dur 67->113 µs — the gather phase's occupancy is this
// kernel's most fragile resource).
__global__ __launch_bounds__(128) void k_spgemm(
    const int* __restrict__ rp, const unsigned* __restrict__ ew,
    const unsigned char* __restrict__ X8, const unsigned short* __restrict__ Wp,
    const float* __restrict__ bias, const float* __restrict__ lng,
    const float* __restrict__ lnb, const float* __restrict__ dinv,
    unsigned short* __restrict__ out, unsigned char* __restrict__ out8)
{
    __shared__ float accf[2][16 * 132];       // per-half buffers (16.9 KB)
    const int t = threadIdx.x, wave = t >> 6, lane = t & 63;
    const int quad = lane >> 4, ln = lane & 15;
    const int half = lane >> 5, li = lane & 31;
    const int n0 = blockIdx.x * 16;
    const int nf = n0 + wave * 8;

    // zero own rows in both half-buffers (own-wave rows only)
    {
        float* z0 = &accf[0][wave * 8 * 132];
        float* z1 = &accf[1][wave * 8 * 132];
        for (int i = lane; i < 8 * 132; i += 64) { z0[i] = 0.f; z1[i] = 0.f; }
    }

    if (nf < NN) {
        const int nl = min(nf + 8, NN);
        const int ebeg = __builtin_amdgcn_readfirstlane(rp[nf]);
        const int eend = __builtin_amdgcn_readfirstlane(rp[nl]);
        if (ebeg < eend) {
            float4 racc = make_float4(0.f, 0.f, 0.f, 0.f);
            int curd = (int)((ew[min(ebeg + half, eend - 1)] >> 16) & 15u);
            const unsigned char* Xl = X8 + li * 4;
            unsigned rec[8], recN[8], g[8];
#pragma unroll
            for (int j = 0; j < 8; ++j) rec[j]  = ew[ebeg + 2 * j + half];        // pad-safe
#pragma unroll
            for (int j = 0; j < 8; ++j) recN[j] = ew[ebeg + 16 + 2 * j + half];   // pad-safe
#pragma unroll
            for (int j = 0; j < 8; ++j) {
                int src = (int)(rec[j] & 0xFFFFu);
                g[j] = *(const unsigned*)(Xl + (size_t)src * 128);
            }
            for (int e = ebeg; e < eend; e += 16) {
                // issue next round's gathers + round-after-next records
                unsigned gN[8], recNN[8];
#pragma unroll
                for (int j = 0; j < 8; ++j) {
                    int src = (int)(recN[j] & 0xFFFFu);
                    gN[j] = *(const unsigned*)(Xl + (size_t)src * 128);
                }
#pragma unroll
                for (int j = 0; j < 8; ++j) recNN[j] = ew[e + 32 + 2 * j + half]; // pad-safe
                // consume current round (waits only on g)
                int lim = eend - e;
                int mj = lim > half ? ((lim - half + 1) >> 1) : 0; if (mj > 8) mj = 8;
#pragma unroll
                for (int j = 0; j < 8; ++j) {
                    if (j >= mj) break;                  // half-uniform (tail only)
                    int dl = (int)((rec[j] >> 16) & 15u);
                    if (dl != curd) {                    // half-uniform, 1 store
                        *(float4*)&accf[half][curd * 132 + li * 4] = racc;
                        racc = make_float4(0.f, 0.f, 0.f, 0.f);
                        curd = dl;
                    }
                    float2 p0 = d2fp8((unsigned short)(g[j] & 0xFFFFu));
                    float2 p1 = d2fp8((unsigned short)(g[j] >> 16));
                    racc.x += p0.x;
                    racc.y += p0.y;
                    racc.z += p1.x;
                    racc.w += p1.y;
                }
#pragma unroll
                for (int j = 0; j < 8; ++j) { rec[j] = recN[j]; recN[j] = recNN[j]; g[j] = gN[j]; }
            }
            *(float4*)&accf[half][curd * 132 + li * 4] = racc;   // final flush
        }
    }
    __syncthreads();

    // MFMA phase (redundant across the 2 waves): A = accf[0]+accf[1], B from L2
    f32x4 acc[8] = {};
    const float* ar0 = &accf[0][(size_t)ln * 132];
    const float* ar1 = &accf[1][(size_t)ln * 132];
#pragma unroll
    for (int c = 0; c < 4; ++c) {
        float4 a0 = *(const float4*)(ar0 + c * 32 + quad * 8);
        float4 a1 = *(const float4*)(ar0 + c * 32 + quad * 8 + 4);
        float4 b0 = *(const float4*)(ar1 + c * 32 + quad * 8);
        float4 b1 = *(const float4*)(ar1 + c * 32 + quad * 8 + 4);
        short8 af;
        af[0] = (short)f2bf(a0.x + b0.x); af[1] = (short)f2bf(a0.y + b0.y);
        af[2] = (short)f2bf(a0.z + b0.z); af[3] = (short)f2bf(a0.w + b0.w);
        af[4] = (short)f2bf(a1.x + b1.x); af[5] = (short)f2bf(a1.y + b1.y);
        af[6] = (short)f2bf(a1.z + b1.z); af[7] = (short)f2bf(a1.w + b1.w);
#pragma unroll
        for (int b = 0; b < 8; ++b) {
            short8 bb = *(const short8*)(Wp + ((size_t)(c * 8 + b) * 64 + lane) * 8);
            acc[b] = __builtin_amdgcn_mfma_f32_16x16x32_bf16(af, bb, acc[b], 0, 0, 0);
        }
    }

    float b_s[8], g_s[8], e_s[8];
#pragma unroll
    for (int b = 0; b < 8; ++b) {
        int col = b * 16 + ln;
        b_s[b] = bias[col]; g_s[b] = lng[col]; e_s[b] = lnb[col];
    }
#pragma unroll
    for (int i = 0; i < 4; ++i) {
        int row = n0 + quad * 4 + i;
        float dv = (row < NN) ? dinv[row] : 0.f;   // dinv[dst] factor of enorm
        float v[8]; float s = 0.f, q = 0.f;
#pragma unroll
        for (int b = 0; b < 8; ++b) { float x = acc[b][i] * dv + b_s[b]; v[b] = x; s += x; q += x * x; }
#pragma unroll
        for (int o = 1; o < 16; o <<= 1) { s += __shfl_xor(s, o, 64); q += __shfl_xor(q, o, 64); }
        float m  = s * (1.0f / 128.0f);
        float vr = q * (1.0f / 128.0f) - m * m;
        float rs = rsqrtf(vr + 1e-5f);
        if (((quad >> 1) == wave) && row < NN) {   // each wave stores its half
#pragma unroll
            for (int b = 0; b < 8; ++b) {
                float o2 = (v[b] - m) * rs * g_s[b] + e_s[b];
                out[(size_t)row * 128 + b * 16 + ln] = f2bf(o2);
                if (out8) out8[(size_t)row * 128 + b * 16 + ln] = e2fp8(o2 * dv);
            }
        }
    }
}

// ---------- MFMA gate (LDS-staged W), writes bf16 + scaled fp8 shadow ----------
// ROUND-6 LESSON: keep the LDS staging. Reading W per-MFMA from L2 puts a
// vmcnt wait in front of every MFMA and serializes the accumulator chain on
// ~200-cyc L2 latency 64x/wave: +14.5 µs per gate dispatch (870->961 µs).
__global__ __launch_bounds__(256) void k_gate_mfma(
    unsigned short* __restrict__ cur, const unsigned short* __restrict__ hnew,
    const unsigned short* __restrict__ Wp, const float* __restrict__ gb,
    const float* __restrict__ dinv, unsigned char* __restrict__ cur8)
{
    __shared__ unsigned short Ws[16384];
    const int t = threadIdx.x;
    const int wave = t >> 6, lane = t & 63;
    const int quad = lane >> 4, ln = lane & 15;
    const int r0 = blockIdx.x * 64 + wave * 16;
    const int arow = r0 + ln;
    const bool av = arow < NN;

    f32x4 acc[8] = {};
#pragma unroll
    for (int s = 0; s < 2; ++s) {
        __syncthreads();
        {
            const float4* src = (const float4*)(Wp + (size_t)s * 16384);
            float4* dst = (float4*)Ws;
#pragma unroll
            for (int i = 0; i < 8; ++i) dst[t + i * 256] = src[t + i * 256];
        }
        __syncthreads();
        const unsigned short* A = s ? hnew : cur;
#pragma unroll
        for (int c = 0; c < 4; ++c) {
            short8 a = {};
            if (av) a = *(const short8*)(A + (size_t)arow * 128 + c * 32 + quad * 8);
#pragma unroll
            for (int b = 0; b < 8; ++b) {
                short8 bb = *(const short8*)&Ws[((c * 8 + b) * 64 + lane) * 8];
                acc[b] = __builtin_amdgcn_mfma_f32_16x16x32_bf16(a, bb, acc[b], 0, 0, 0);
            }
        }
    }

    float gb_s[8];
#pragma unroll
    for (int b = 0; b < 8; ++b) gb_s[b] = gb[b * 16 + ln];
#pragma unroll
    for (int i = 0; i < 4; ++i) {
        int row = r0 + quad * 4 + i;
        if (row < NN) {
            float dv = dinv[row];
#pragma unroll
            for (int b = 0; b < 8; ++b) {
                size_t idx = (size_t)row * 128 + b * 16 + ln;
                float g  = sigm(acc[b][i] + gb_s[b]);
                float cu = bf2f(cur[idx]);
                float hn = bf2f(hnew[idx]);
                float r  = g * hn + (1.f - g) * cu;
                cur[idx]  = f2bf(r);
                cur8[idx] = e2fp8(r * dv);
            }
        }
    }
}

// ---------- fused MFMA gate + RK4 stage combine (LDS-staged W) ----------
// bf16 tv_s buffers instead of fp32 acc (R8: traffic-neutral in time but
// keeps the smaller footprint); S=4 skips tv/y8 stores.
template<int S>
__global__ __launch_bounds__(256) void k_gate_fused(
    const unsigned short* __restrict__ cur, const unsigned short* __restrict__ hnew,
    const unsigned short* __restrict__ Wp, const float* __restrict__ gb,
    const unsigned short* __restrict__ fin, const unsigned short* __restrict__ h0,
    unsigned short* __restrict__ tv1, unsigned short* __restrict__ tv2,
    unsigned short* __restrict__ tv3,
    unsigned short* __restrict__ ybuf, unsigned char* __restrict__ y8,
    const float* __restrict__ scal, const float* __restrict__ rwp,
    const float* __restrict__ dinv)
{
    __shared__ unsigned short Ws[16384];
    const int t = threadIdx.x;
    const int wave = t >> 6, lane = t & 63;
    const int quad = lane >> 4, ln = lane & 15;
    const int r0 = blockIdx.x * 64 + wave * 16;
    const int arow = r0 + ln;
    const bool av = arow < NN;

    f32x4 am[8] = {};
#pragma unroll
    for (int s = 0; s < 2; ++s) {
        __syncthreads();
        {
            const float4* src = (const float4*)(Wp + (size_t)s * 16384);
            float4* dst = (float4*)Ws;
#pragma unroll
            for (int i = 0; i < 8; ++i) dst[t + i * 256] = src[t + i * 256];
        }
        __syncthreads();
        const unsigned short* A = s ? hnew : cur;
#pragma unroll
        for (int c = 0; c < 4; ++c) {
            short8 a = {};
            if (av) a = *(const short8*)(A + (size_t)arow * 128 + c * 32 + quad * 8);
#pragma unroll
            for (int b = 0; b < 8; ++b) {
                short8 bb = *(const short8*)&Ws[((c * 8 + b) * 64 + lane) * 8];
                am[b] = __builtin_amdgcn_mfma_f32_16x16x32_bf16(a, bb, am[b], 0, 0, 0);
            }
        }
    }

    float gb_s[8];
#pragma unroll
    for (int b = 0; b < 8; ++b) gb_s[b] = gb[b * 16 + ln];
    const float dt = scal[1], rw = rwp[0];
    const float cn = (S == 3) ? dt : 0.5f * dt;
    const float w16 = dt * (1.f / 6.f), w13 = dt * (1.f / 3.f);
#pragma unroll
    for (int i = 0; i < 4; ++i) {
        int row = r0 + quad * 4 + i;
        if (row < NN) {
            float dv = dinv[row];
#pragma unroll
            for (int b = 0; b < 8; ++b) {
                size_t idx = (size_t)row * 128 + b * 16 + ln;
                float g  = sigm(am[b][i] + gb_s[b]);
                float cu = bf2f(cur[idx]);
                float hn = bf2f(hnew[idx]);
                float r  = g * hn + (1.f - g) * cu;
                float tv = tanhf(r) + rw * bf2f(fin[idx]);
                float yv;
                if (S == 4) {
                    float t1 = bf2f(tv1[idx]);
                    float t2 = bf2f(tv2[idx]);
                    float t3 = bf2f(tv3[idx]);
                    yv = bf2f(h0[idx]) + w16 * (t1 + tv) + w13 * (t2 + t3);
                } else {
                    if (S == 1) tv1[idx] = f2bf(tv);
                    if (S == 2) tv2[idx] = f2bf(tv);
                    if (S == 3) tv3[idx] = f2bf(tv);
                    yv = bf2f(h0[idx]) + cn * tv;
                }
                ybuf[idx] = f2bf(yv);
                if (S != 4) y8[idx] = e2fp8(yv * dv);
            }
        }
    }
}

// ---------- pooling phase 2: sum per-block partials (782), divide by counts ----------
__global__ __launch_bounds__(256) void k_pool2(
    const float* __restrict__ partial, const int* __restrict__ st,
    float* __restrict__ out)
{
    __shared__ float sh[8][32];
    int cb = blockIdx.x & 3, g = blockIdx.x >> 2;
    int cl = threadIdx.x & 31, sl = threadIdx.x >> 5;
    int c = cb * 32 + cl;
    float s = 0.f;
    for (int b = sl; b < PBLK; b += 8) s += partial[(size_t)b * 1024 + g * 128 + c];
    sh[sl][cl] = s; __syncthreads();
    if (sl == 0) {
        float tt = 0.f;
#pragma unroll
        for (int i = 0; i < 8; ++i) tt += sh[i][cl];
        int cnt = st[g + 1] - st[g];
        out[g * 128 + c] = tt / (float)(cnt > 0 ? cnt : 1);
    }
}

// ---------- host ----------
static inline size_t al(size_t x) { return (x + 255) & ~(size_t)255; }

extern "C" void kernel_launch(void* const* d_in, const int* in_sizes, int n_in,
                              void* d_out, int out_size, void* d_ws, size_t ws_size,
                              hipStream_t stream)
{
    const float* x       = (const float*)d_in[0];
    const int*   ei      = (const int*)d_in[1];
    const int*   batch   = (const int*)d_in[2];
    const float* in_w    = (const float*)d_in[3];
    const float* in_b    = (const float*)d_in[4];
    const float* in_lng  = (const float*)d_in[5];
    const float* in_lnb  = (const float*)d_in[6];
    const float* meth    = (const float*)d_in[7];
    const float* histn   = (const float*)d_in[8];
    const float* logd    = (const float*)d_in[9];
    const float* gcn_w   = (const float*)d_in[10];
    const float* gcn_b   = (const float*)d_in[11];
    const float* ln_g    = (const float*)d_in[12];
    const float* ln_b    = (const float*)d_in[13];
    const float* gate_w  = (const float*)d_in[14];
    const float* gate_b  = (const float*)d_in[15];
    const float* rw      = (const float*)d_in[16];
    const float* out_w   = (const float*)d_in[17];
    const float* out_b   = (const float*)d_in[18];
    const float* out_lng = (const float*)d_in[19];
    const float* out_lnb = (const float*)d_in[20];
    float* out = (float*)d_out;

    char* w = (char*)d_ws;
    size_t off = 0;
    float* scal   = (float*)(w + off); off += al(16 * 4);
    int*   hist   = (int*)(w + off);   off += al((size_t)NN * 4);
    int*   rp     = (int*)(w + off);   off += al((size_t)(NN + 1) * 4);
    int*   cursor = (int*)(w + off);   off += al((size_t)(NN + 1) * 4);
    int*   aux    = (int*)(w + off);   off += al(64 * 4);
    int*   st     = (int*)(w + off);   off += al(16 * 4);
    float* dinv   = (float*)(w + off); off += al((size_t)NN * 4);
    unsigned* ew  = (unsigned*)(w + off); off += al((size_t)(EE + 128) * 4);
    float* partial= (float*)(w + off); off += al((size_t)PBLK * 1024 * 4);
    // packed bf16 weights: [in | gcn0 | gcn1 | gcn2 | gate0 | gate1 | out] contiguous
    unsigned short* wpak = (unsigned short*)(w + off); off += al((size_t)(8192 + 6 * 16384) * 2);
    unsigned short* inwp  = wpak;
    unsigned short* gcnwp = wpak + 8192;
    unsigned short* gwp   = wpak + 8192 + 3 * 16384;
    unsigned short* owp   = wpak + 8192 + 5 * 16384;
    // bf16 activations
    size_t B16 = al((size_t)NN * 128 * 2);
    unsigned short* xb  = (unsigned short*)(w + off); off += al((size_t)NN * 64 * 2);
    unsigned short* h0  = (unsigned short*)(w + off); off += B16;
    unsigned short* y   = (unsigned short*)(w + off); off += B16;
    unsigned short* cur = (unsigned short*)(w + off); off += B16;
    unsigned short* t2  = (unsigned short*)(w + off); off += B16;
    // bf16 RK4 slope buffers
    unsigned short* tv1 = (unsigned short*)(w + off); off += B16;
    unsigned short* tv2 = (unsigned short*)(w + off); off += B16;
    unsigned short* tv3 = (unsigned short*)(w + off); off += B16;
    // fp8 gather shadows (pre-scaled by dinv[node])
    size_t B8 = al((size_t)NN * 128);
    unsigned char* h08  = (unsigned char*)(w + off); off += B8;
    unsigned char* y8   = (unsigned char*)(w + off); off += B8;
    unsigned char* cur8 = (unsigned char*)(w + off); off += B8;
    if (off > ws_size) return;

    hipMemsetAsync(hist, 0, (size_t)NN * 4, stream);

    // setup+bounds, merged pack, x conversion (independent)
    k_setup<<<2, 64, 0, stream>>>(meth, histn, logd, scal, batch, st);
    k_packall<<<(8192 + 6 * 16384 + 255) / 256, 256, 0, stream>>>(in_w, gcn_w, gate_w, out_w, wpak);
    k_cvtx<<<3125, 256, 0, stream>>>(x, xb);

    // CSR build (scan_c also initializes cursor — no memcpy)
    k_hist<<<(EE + 255) / 256, 256, 0, stream>>>(ei, hist);
    k_dinv<<<(NN + 255) / 256, 256, 0, stream>>>(hist, dinv);
    k_scan_a<<<49, 256, 0, stream>>>(hist, aux);
    k_scan_b<<<1, 1, 0, stream>>>(aux, 49);
    k_scan_c<<<49, 256, 0, stream>>>(hist, aux, rp, cursor);
    k_scatter<<<SB, 256, 0, stream>>>(ei, cursor, ew);

    const int DG = (NN + 63) / 64;     // 782 blocks (dense/gate)
    const int SG = (NN + 15) / 16;     // 3125 blocks (spgemm)
    k_dense_mfma<2, 1><<<DG, 256, 0, stream>>>(xb, inwp, in_b, in_lng, in_lnb, scal, dinv, h0, h08,
                                               (const int*)0, (float*)0);

    for (int s = 1; s <= 4; ++s) {
        const unsigned short* fin = (s == 1) ? h0 : y;
        const unsigned char*  fin8 = (s == 1) ? h08 : y8;
        // layer 0
        k_spgemm<<<SG, 128, 0, stream>>>(rp, ew, fin8, gcnwp, gcn_b, ln_g, ln_b, dinv, cur, cur8);
        // layer 1 + gate
        k_spgemm<<<SG, 128, 0, stream>>>(rp, ew, cur8,
                                         gcnwp + (size_t)1 * 128 * 128, gcn_b + 128,
                                         ln_g + 128, ln_b + 128, dinv, t2, (unsigned char*)0);
        k_gate_mfma<<<DG, 256, 0, stream>>>(cur, t2, gwp, gate_b, dinv, cur8);
        // layer 2 + gate fused with RK4 stage combine
        k_spgemm<<<SG, 128, 0, stream>>>(rp, ew, cur8,
                                         gcnwp + (size_t)2 * 128 * 128, gcn_b + 256,
                                         ln_g + 256, ln_b + 256, dinv, t2, (unsigned char*)0);
        if (s == 1)      k_gate_fused<1><<<DG, 256, 0, stream>>>(cur, t2, gwp, gate_b, fin, h0, tv1, tv2, tv3, y, y8, scal, rw, dinv);
        else if (s == 2) k_gate_fused<2><<<DG, 256, 0, stream>>>(cur, t2, gwp, gate_b, fin, h0, tv1, tv2, tv3, y, y8, scal, rw, dinv);
        else if (s == 3) k_gate_fused<3><<<DG, 256, 0, stream>>>(cur, t2, gwp, gate_b, fin, h0, tv1, tv2, tv3, y, y8, scal, rw, dinv);
        else             k_gate_fused<4><<<DG, 256, 0, stream>>>(cur, t2, gwp, gate_b, fin, h0, tv1, tv2, tv3, y, y8, scal, rw, dinv);
    }

    // output projection with fused pooling (MODE=2) + final reduce
    k_dense_mfma<4, 2><<<DG, 256, 0, stream>>>(y, owp, out_b, out_lng, out_lnb, scal, dinv,
                                               (unsigned short*)0, (unsigned char*)0, batch, partial);
    k_pool2<<<GG * 4, 256, 0, stream>>>(partial, st, out);
}

// Round 12
// 825.980 us; speedup vs baseline: 1.3016x; 1.0414x over previous
//
#include <hip/hip_runtime.h>
#include <math.h>

#define NN 50000
#define EE 800000
#define HH 128
#define FF 64
#define GG 8
#define PBLK 782    // pooled partials: one per dense-output block ((NN+63)/64)
#define SB 1600     // scatter blocks: 200 per dst-group, 8 groups

using short8 = __attribute__((ext_vector_type(8))) short;
using f32x4  = __attribute__((ext_vector_type(4))) float;
using f32x2  = __attribute__((ext_vector_type(2))) float;

__device__ __forceinline__ float sigm(float x){ return 1.0f/(1.0f+expf(-x)); }
__device__ __forceinline__ unsigned short f2bf(float f){
    union { float f; unsigned u; } v; v.f = f;
    unsigned r = v.u + 0x7fff + ((v.u >> 16) & 1);
    return (unsigned short)(r >> 16);
}
__device__ __forceinline__ float bf2f(unsigned short h){
    union { unsigned u; float f; } v; v.u = ((unsigned)h) << 16;
    return v.f;
}

// ---------- fp8 helpers (HW cvt on gfx950; self-consistent either format) ----------
#if __has_builtin(__builtin_amdgcn_cvt_pk_fp8_f32) && __has_builtin(__builtin_amdgcn_cvt_pk_f32_fp8)
#define FP8_HW 1
#else
#define FP8_HW 0
#endif

__device__ __forceinline__ unsigned fp8enc1_sw(float f){
    union { float fl; unsigned u; } x; x.fl = f;
    unsigned s = (x.u >> 31) << 7;
    float a = fabsf(f);
    if (!(a > 0.f)) return s;
    if (a >= 448.f) return s | 0x7E;
    if (a < 0.015625f) {
        int q = (int)(a * 512.f + 0.5f);
        if (q > 7) return s | (1u << 3);
        return s | (unsigned)q;
    }
    unsigned u = x.u + (1u << 19);          // round at 3-bit mantissa
    int e32 = (int)((u >> 23) & 255) - 127;
    if (e32 < -6) { int q=(int)(a*512.f+0.5f); if(q>7)q=7; return s|(unsigned)q; }
    if (e32 > 8) return s | 0x7E;
    unsigned m = (u >> 20) & 7;
    return s | ((unsigned)(e32 + 7) << 3) | m;
}
__device__ __forceinline__ float fp8dec1_sw(unsigned v){
    unsigned s = v >> 7, e = (v >> 3) & 15, m = v & 7;
    float f;
    if (e == 0) f = (float)m * 0.001953125f;
    else { union { unsigned u; float fl; } x; x.u = ((e + 120u) << 23) | (m << 20); f = x.fl; }
    return s ? -f : f;
}
__device__ __forceinline__ unsigned char e2fp8(float a){
#if FP8_HW
    return (unsigned char)(__builtin_amdgcn_cvt_pk_fp8_f32(a, a, 0, false) & 0xFF);
#else
    return (unsigned char)fp8enc1_sw(a);
#endif
}
__device__ __forceinline__ float2 d2fp8(unsigned short u){
#if FP8_HW
    f32x2 r = __builtin_amdgcn_cvt_pk_f32_fp8((int)(unsigned)u, false);
    return make_float2(r[0], r[1]);
#else
    return make_float2(fp8dec1_sw(u & 0xFF), fp8dec1_sw((u >> 8) & 0xFF));
#endif
}

// ---------- setup (block 0) + graph bounds (block 1) ----------
__global__ void k_setup(const float* __restrict__ meth,
                        const float* __restrict__ histones,
                        const float* __restrict__ logd,
                        float* __restrict__ scal,
                        const int* __restrict__ batch, int* __restrict__ st)
{
    if (blockIdx.x == 1) {
        int g = threadIdx.x;
        if (g > GG) return;
        int lo = 0, hi = NN;
        while (lo < hi) { int mid = (lo + hi) >> 1; if (batch[mid] < g) lo = mid + 1; else hi = mid; }
        st[g] = lo;
        return;
    }
    int l = threadIdx.x;
    float s = sigm(meth[l]) + sigm(meth[l + 64]);
#pragma unroll
    for (int o = 32; o >= 1; o >>= 1) s += __shfl_xor(s, o, 64);
    if (l == 0) {
        float msil = s * (1.0f / 128.0f);
        float h0 = sigm(histones[0]), h1 = sigm(histones[1]);
        float h2 = sigm(histones[2]), h3 = sigm(histones[3]);
        float act = (h0 + h2) * 0.5f, rep = (h1 + h3) * 0.5f;
        float chrom = fminf(fmaxf(act - rep + 0.5f, 0.0f), 1.0f);
        scal[0] = chrom * (1.0f - msil);
        float d = expf(logd[0]);
        scal[1] = fminf(fmaxf(d, 0.1f), 3.0f);   // dt
    }
}

// ---------- single merged weight pack: all 7 matrices -> one contiguous bf16 buffer ----------
__global__ void k_packall(const float* __restrict__ in_w, const float* __restrict__ gcn_w,
                          const float* __restrict__ gate_w, const float* __restrict__ out_w,
                          unsigned short* __restrict__ outp)
{
    int i = blockIdx.x * 256 + threadIdx.x;
    if (i >= 8192 + 6 * 16384) return;
    const float* src; int base, li;
    if (i < 8192) { src = in_w + i; base = 0; li = i; }
    else {
        int j = i - 8192;
        int m = j >> 14, r = j & 16383;
        base = 8192 + (m << 14); li = r;
        if (m < 3)      src = gcn_w  + m * 16384 + r;
        else if (m < 5) src = gate_w + (m - 3) * 16384 + r;
        else            src = out_w + r;
    }
    int k = li >> 7, n = li & 127;
    int c = k >> 5, kl = k & 31, q = kl >> 3, j2 = kl & 7;
    int b = n >> 4, ln = n & 15;
    int lane = q * 16 + ln;
    outp[base + ((c * 8 + b) * 64 + lane) * 8 + j2] = f2bf(*src);
}

// ---------- x fp32 -> bf16 ----------
__global__ void k_cvtx(const float* __restrict__ x, unsigned short* __restrict__ xb)
{
    size_t i = (size_t)blockIdx.x * 256 + threadIdx.x;
    if (i >= (size_t)NN * 16) return;
    float4 v = ((const float4*)x)[i];
    ushort4 o;
    o.x = f2bf(v.x); o.y = f2bf(v.y); o.z = f2bf(v.z); o.w = f2bf(v.w);
    ((ushort4*)xb)[i] = o;
}

// ---------- CSR build ----------
__global__ void k_hist(const int* __restrict__ ei, int* __restrict__ hist)
{
    int e = blockIdx.x * 256 + threadIdx.x;
    if (e < EE) atomicAdd(&hist[ei[EE + e]], 1);
}

__global__ void k_dinv(const int* __restrict__ hist, float* __restrict__ dinv)
{
    int n = blockIdx.x * 256 + threadIdx.x;
    if (n < NN) {
        int d = hist[n];
        dinv[n] = d > 0 ? rsqrtf((float)d) : 0.0f;
    }
}

__global__ void k_scan_a(const int* __restrict__ hist, int* __restrict__ aux)
{
    __shared__ int sh[256];
    int b = blockIdx.x, t = threadIdx.x;
    int base = b * 1024 + t * 4;
    int s = 0;
#pragma unroll
    for (int j = 0; j < 4; ++j) { int i = base + j; if (i < NN) s += hist[i]; }
    sh[t] = s; __syncthreads();
    for (int o = 128; o >= 1; o >>= 1) { if (t < o) sh[t] += sh[t + o]; __syncthreads(); }
    if (t == 0) aux[b] = sh[0];
}

__global__ void k_scan_b(int* __restrict__ aux, int nb)
{
    if (blockIdx.x == 0 && threadIdx.x == 0) {
        int run = 0;
        for (int i = 0; i < nb; ++i) { int v = aux[i]; aux[i] = run; run += v; }
    }
}

// writes BOTH row_ptr and cursor (folds the old cursor memcpy away)
__global__ void k_scan_c(const int* __restrict__ hist, const int* __restrict__ aux,
                         int* __restrict__ row_ptr, int* __restrict__ cursor)
{
    __shared__ int sh[256];
    int b = blockIdx.x, t = threadIdx.x;
    int base = b * 1024 + t * 4;
    int v[4]; int s = 0;
#pragma unroll
    for (int j = 0; j < 4; ++j) { int i = base + j; v[j] = (i < NN) ? hist[i] : 0; s += v[j]; }
    sh[t] = s; __syncthreads();
    for (int o = 1; o < 256; o <<= 1) {
        int x = 0; if (t >= o) x = sh[t - o];
        __syncthreads(); sh[t] += x; __syncthreads();
    }
    int run = aux[b] + sh[t] - s;
#pragma unroll
    for (int j = 0; j < 4; ++j) {
        int i = base + j;
        if (i < NN) { row_ptr[i] = run; cursor[i] = run; }
        run += v[j];
    }
    if (b == 0 && t == 0) { row_ptr[NN] = EE; cursor[NN] = EE; }
}

// ---------- XCD-aligned dst-partitioned scatter, 4-byte records, nt streams ----------
// Verified rounds 5-8: 42 µs (FETCH 25 MB from 8x dst-read replication — L3
// does NOT absorb it; WRITE 31 MB; nt hints don't prevent L2 allocation).
__global__ __launch_bounds__(256) void k_scatter(const int* __restrict__ ei,
                          int* __restrict__ cursor, unsigned* __restrict__ ew)
{
    if (blockIdx.x == 0 && threadIdx.x < 128)    // tail pads for spgemm prefetch
        ew[EE + threadIdx.x] = 0u;
    const int grp = blockIdx.x & 7;
    const int blk = blockIdx.x >> 3;             // 0..SB/8-1
    const int CH  = EE / (SB / 8);               // 4000
    const int e0 = blk * CH, e1 = e0 + CH;
    const int glo = grp * (NN / 8), ghi = glo + (NN / 8);
    for (int e = e0 + threadIdx.x; e < e1; e += 256) {
        int d = __builtin_nontemporal_load(ei + EE + e);
        if (d >= glo && d < ghi) {
            int s = __builtin_nontemporal_load(ei + e);
            int p = atomicAdd(&cursor[d], 1);
            ew[p] = (unsigned)s | ((unsigned)(d & 15) << 16);
        }
    }
}

// ---------- MFMA dense (LDS-staged W) ----------
// MODE=1: relu(LN(A@W+b))*sc -> out + scaled fp8 shadow (input projection).
// MODE=2: LN(A@W+b) pooled per-graph into partial[block][8][128].
//   ROUND-12 FIX: R11's per-element LDS atomicAdd serialized 16-way on the
//   same address (batch is sorted -> whole block usually one graph): MODE=2
//   ran at 49.6 µs with NOTHING busy (VALU 3.6%, HBM 200 GB/s). Now: blocks
//   with a uniform graph (774/782) accumulate in registers, reduce across
//   quads with 2 shfl_xor, one LDS word per wave, plain 4 KB store. Only
//   graph-boundary blocks keep the atomic path.
// NOTE (R10 lesson): keep this kernel's template/signature stable — changing
// it perturbed co-compiled kernels' regalloc (gate_fused 60->64 VGPR, +15 µs
// per dispatch, total 845->914).
template<int KC, int MODE>
__global__ __launch_bounds__(256) void k_dense_mfma(
    const unsigned short* __restrict__ A, const unsigned short* __restrict__ Wp,
    const float* __restrict__ bias, const float* __restrict__ lng,
    const float* __restrict__ lnb, const float* __restrict__ scal,
    const float* __restrict__ dinv,
    unsigned short* __restrict__ out, unsigned char* __restrict__ out8,
    const int* __restrict__ batchp, float* __restrict__ partial)
{
    __shared__ unsigned short Ws[KC * 4096];
    const int t = threadIdx.x;
    {
        const float4* src = (const float4*)Wp;
        float4* dst = (float4*)Ws;
#pragma unroll
        for (int i = 0; i < KC * 2; ++i) dst[t + i * 256] = src[t + i * 256];
    }
    __syncthreads();
    const int wave = t >> 6, lane = t & 63;
    const int quad = lane >> 4, ln = lane & 15;
    const int r0 = blockIdx.x * 64 + wave * 16;
    const int K = KC * 32;
    const int arow = r0 + ln;
    const bool av = arow < NN;

    f32x4 acc[8] = {};
#pragma unroll
    for (int c = 0; c < KC; ++c) {
        short8 a = {};
        if (av) a = *(const short8*)(A + (size_t)arow * K + c * 32 + quad * 8);
#pragma unroll
        for (int b = 0; b < 8; ++b) {
            short8 bb = *(const short8*)&Ws[((c * 8 + b) * 64 + lane) * 8];
            acc[b] = __builtin_amdgcn_mfma_f32_16x16x32_bf16(a, bb, acc[b], 0, 0, 0);
        }
    }

    float* pbuf = (float*)Ws;                 // MODE==2: reuse staging LDS
    bool uni = false; int gfirst = 0;
    if (MODE == 2) {
        gfirst = batchp[blockIdx.x * 64];
        int rlast = blockIdx.x * 64 + 63; if (rlast >= NN) rlast = NN - 1;
        uni = (gfirst == batchp[rlast]);
        __syncthreads();                      // all waves done reading Ws
        if (!uni) {
            for (int i2 = t; i2 < GG * 128; i2 += 256) pbuf[i2] = 0.f;
        }
        __syncthreads();
    }

    float b_s[8], g_s[8], e_s[8];
#pragma unroll
    for (int b = 0; b < 8; ++b) {
        int col = b * 16 + ln;
        b_s[b] = bias[col]; g_s[b] = lng[col]; e_s[b] = lnb[col];
    }
    float sc = (MODE == 1) ? scal[0] : 0.0f;
    float psum[8];
#pragma unroll
    for (int b = 0; b < 8; ++b) psum[b] = 0.f;
#pragma unroll
    for (int i = 0; i < 4; ++i) {
        int row = r0 + quad * 4 + i;
        float v[8]; float s = 0.f, q = 0.f;
#pragma unroll
        for (int b = 0; b < 8; ++b) { float x = acc[b][i] + b_s[b]; v[b] = x; s += x; q += x * x; }
#pragma unroll
        for (int o = 1; o < 16; o <<= 1) { s += __shfl_xor(s, o, 64); q += __shfl_xor(q, o, 64); }
        float m  = s * (1.0f / 128.0f);
        float vr = q * (1.0f / 128.0f) - m * m;
        float rs = rsqrtf(vr + 1e-5f);
        if (row < NN) {
            if (MODE == 2) {
                if (uni) {
#pragma unroll
                    for (int b = 0; b < 8; ++b)
                        psum[b] += (v[b] - m) * rs * g_s[b] + e_s[b];
                } else {
                    int gg = batchp[row];
#pragma unroll
                    for (int b = 0; b < 8; ++b) {
                        float o2 = (v[b] - m) * rs * g_s[b] + e_s[b];
                        atomicAdd(&pbuf[gg * 128 + b * 16 + ln], o2);
                    }
                }
            } else {
                float dv = out8 ? dinv[row] : 0.f;
#pragma unroll
                for (int b = 0; b < 8; ++b) {
                    float o2 = (v[b] - m) * rs * g_s[b] + e_s[b];
                    if (MODE == 1) o2 = fmaxf(o2, 0.f) * sc;
                    out[(size_t)row * 128 + b * 16 + ln] = f2bf(o2);
                    if (out8) out8[(size_t)row * 128 + b * 16 + ln] = e2fp8(o2 * dv);
                }
            }
        }
    }

    if (MODE == 2) {
        if (uni) {
            // sum across the 4 quads (rows) of this wave; all lanes end with it
#pragma unroll
            for (int b = 0; b < 8; ++b) {
                psum[b] += __shfl_xor(psum[b], 16, 64);
                psum[b] += __shfl_xor(psum[b], 32, 64);
            }
            if (quad == 0) {
#pragma unroll
                for (int b = 0; b < 8; ++b) pbuf[wave * 128 + b * 16 + ln] = psum[b];
            }
            __syncthreads();
            // partial[block][8][128]: thread t writes float4 at t*4; only the
            // gfirst slot is nonzero (sum of the 4 per-wave vectors).
            int slot = t >> 5;
            int col  = (t * 4) & 127;
            float4 o = make_float4(0.f, 0.f, 0.f, 0.f);
            if (slot == gfirst) {
                o.x = pbuf[col]     + pbuf[128 + col]     + pbuf[256 + col]     + pbuf[384 + col];
                o.y = pbuf[col + 1] + pbuf[128 + col + 1] + pbuf[256 + col + 1] + pbuf[384 + col + 1];
                o.z = pbuf[col + 2] + pbuf[128 + col + 2] + pbuf[256 + col + 2] + pbuf[384 + col + 2];
                o.w = pbuf[col + 3] + pbuf[128 + col + 3] + pbuf[256 + col + 3] + pbuf[384 + col + 3];
            }
            ((float4*)(partial + (size_t)blockIdx.x * 1024))[t] = o;
        } else {
            __syncthreads();
            ((float4*)(partial + (size_t)blockIdx.x * 1024))[t] = ((const float4*)pbuf)[t];
        }
    }
}

// ---------- fused SpMM + GEMM + LN (fp8 gather; 2 half-wave edge tracks) ----------
// Wave owns 8 CSR-contiguous nodes. Half h = lane>>5 processes edges e+2j+h;
// lane covers 4 fp8 cols. Plain-store flushes into per-half buffers.
// PIPELINE DEPTH IS 1 (R5: 2-deep prefetch regressed ~2 µs/dispatch).
// LESSONS: no LDS atomics in hot loop (R1-2: halves throughput); no min-waves
// launch_bounds (spills); occupancy NOT LDS-capped; do NOT fuse
// register-hungry epilogues in here (R9: gate epilogue -> VGPR 60->88,
// occupancy 30->18%, dur 67->113 µs — the gather phase's occupancy is this
// kernel's most fragile resource).
__global__ __launch_bounds__(128) void k_spgemm(
    const int* __restrict__ rp, const unsigned* __restrict__ ew,
    const unsigned char* __restrict__ X8, const unsigned short* __restrict__ Wp,
    const float* __restrict__ bias, const float* __restrict__ lng,
    const float* __restrict__ lnb, const float* __restrict__ dinv,
    unsigned short* __restrict__ out, unsigned char* __restrict__ out8)
{
    __shared__ float accf[2][16 * 132];       // per-half buffers (16.9 KB)
    const int t = threadIdx.x, wave = t >> 6, lane = t & 63;
    const int quad = lane >> 4, ln = lane & 15;
    const int half = lane >> 5, li = lane & 31;
    const int n0 = blockIdx.x * 16;
    const int nf = n0 + wave * 8;

    // zero own rows in both half-buffers (own-wave rows only)
    {
        float* z0 = &accf[0][wave * 8 * 132];
        float* z1 = &accf[1][wave * 8 * 132];
        for (int i = lane; i < 8 * 132; i += 64) { z0[i] = 0.f; z1[i] = 0.f; }
    }

    if (nf < NN) {
        const int nl = min(nf + 8, NN);
        const int ebeg = __builtin_amdgcn_readfirstlane(rp[nf]);
        const int eend = __builtin_amdgcn_readfirstlane(rp[nl]);
        if (ebeg < eend) {
            float4 racc = make_float4(0.f, 0.f, 0.f, 0.f);
            int curd = (int)((ew[min(ebeg + half, eend - 1)] >> 16) & 15u);
            const unsigned char* Xl = X8 + li * 4;
            unsigned rec[8], recN[8], g[8];
#pragma unroll
            for (int j = 0; j < 8; ++j) rec[j]  = ew[ebeg + 2 * j + half];        // pad-safe
#pragma unroll
            for (int j = 0; j < 8; ++j) recN[j] = ew[ebeg + 16 + 2 * j + half];   // pad-safe
#pragma unroll
            for (int j = 0; j < 8; ++j) {
                int src = (int)(rec[j] & 0xFFFFu);
                g[j] = *(const unsigned*)(Xl + (size_t)src * 128);
            }
            for (int e = ebeg; e < eend; e += 16) {
                // issue next round's gathers + round-after-next records
                unsigned gN[8], recNN[8];
#pragma unroll
                for (int j = 0; j < 8; ++j) {
                    int src = (int)(recN[j] & 0xFFFFu);
                    gN[j] = *(const unsigned*)(Xl + (size_t)src * 128);
                }
#pragma unroll
                for (int j = 0; j < 8; ++j) recNN[j] = ew[e + 32 + 2 * j + half]; // pad-safe
                // consume current round (waits only on g)
                int lim = eend - e;
                int mj = lim > half ? ((lim - half + 1) >> 1) : 0; if (mj > 8) mj = 8;
#pragma unroll
                for (int j = 0; j < 8; ++j) {
                    if (j >= mj) break;                  // half-uniform (tail only)
                    int dl = (int)((rec[j] >> 16) & 15u);
                    if (dl != curd) {                    // half-uniform, 1 store
                        *(float4*)&accf[half][curd * 132 + li * 4] = racc;
                        racc = make_float4(0.f, 0.f, 0.f, 0.f);
                        curd = dl;
                    }
                    float2 p0 = d2fp8((unsigned short)(g[j] & 0xFFFFu));
                    float2 p1 = d2fp8((unsigned short)(g[j] >> 16));
                    racc.x += p0.x;
                    racc.y += p0.y;
                    racc.z += p1.x;
                    racc.w += p1.y;
                }
#pragma unroll
                for (int j = 0; j < 8; ++j) { rec[j] = recN[j]; recN[j] = recNN[j]; g[j] = gN[j]; }
            }
            *(float4*)&accf[half][curd * 132 + li * 4] = racc;   // final flush
        }
    }
    __syncthreads();

    // MFMA phase (redundant across the 2 waves): A = accf[0]+accf[1], B from L2
    f32x4 acc[8] = {};
    const float* ar0 = &accf[0][(size_t)ln * 132];
    const float* ar1 = &accf[1][(size_t)ln * 132];
#pragma unroll
    for (int c = 0; c < 4; ++c) {
        float4 a0 = *(const float4*)(ar0 + c * 32 + quad * 8);
        float4 a1 = *(const float4*)(ar0 + c * 32 + quad * 8 + 4);
        float4 b0 = *(const float4*)(ar1 + c * 32 + quad * 8);
        float4 b1 = *(const float4*)(ar1 + c * 32 + quad * 8 + 4);
        short8 af;
        af[0] = (short)f2bf(a0.x + b0.x); af[1] = (short)f2bf(a0.y + b0.y);
        af[2] = (short)f2bf(a0.z + b0.z); af[3] = (short)f2bf(a0.w + b0.w);
        af[4] = (short)f2bf(a1.x + b1.x); af[5] = (short)f2bf(a1.y + b1.y);
        af[6] = (short)f2bf(a1.z + b1.z); af[7] = (short)f2bf(a1.w + b1.w);
#pragma unroll
        for (int b = 0; b < 8; ++b) {
            short8 bb = *(const short8*)(Wp + ((size_t)(c * 8 + b) * 64 + lane) * 8);
            acc[b] = __builtin_amdgcn_mfma_f32_16x16x32_bf16(af, bb, acc[b], 0, 0, 0);
        }
    }

    float b_s[8], g_s[8], e_s[8];
#pragma unroll
    for (int b = 0; b < 8; ++b) {
        int col = b * 16 + ln;
        b_s[b] = bias[col]; g_s[b] = lng[col]; e_s[b] = lnb[col];
    }
#pragma unroll
    for (int i = 0; i < 4; ++i) {
        int row = n0 + quad * 4 + i;
        float dv = (row < NN) ? dinv[row] : 0.f;   // dinv[dst] factor of enorm
        float v[8]; float s = 0.f, q = 0.f;
#pragma unroll
        for (int b = 0; b < 8; ++b) { float x = acc[b][i] * dv + b_s[b]; v[b] = x; s += x; q += x * x; }
#pragma unroll
        for (int o = 1; o < 16; o <<= 1) { s += __shfl_xor(s, o, 64); q += __shfl_xor(q, o, 64); }
        float m  = s * (1.0f / 128.0f);
        float vr = q * (1.0f / 128.0f) - m * m;
        float rs = rsqrtf(vr + 1e-5f);
        if (((quad >> 1) == wave) && row < NN) {   // each wave stores its half
#pragma unroll
            for (int b = 0; b < 8; ++b) {
                float o2 = (v[b] - m) * rs * g_s[b] + e_s[b];
                out[(size_t)row * 128 + b * 16 + ln] = f2bf(o2);
                if (out8) out8[(size_t)row * 128 + b * 16 + ln] = e2fp8(o2 * dv);
            }
        }
    }
}

// ---------- MFMA gate (LDS-staged W), writes bf16 + scaled fp8 shadow ----------
// ROUND-6 LESSON: keep the LDS staging. Reading W per-MFMA from L2 puts a
// vmcnt wait in front of every MFMA and serializes the accumulator chain on
// ~200-cyc L2 latency 64x/wave: +14.5 µs per gate dispatch (870->961 µs).
__global__ __launch_bounds__(256) void k_gate_mfma(
    unsigned short* __restrict__ cur, const unsigned short* __restrict__ hnew,
    const unsigned short* __restrict__ Wp, const float* __restrict__ gb,
    const float* __restrict__ dinv, unsigned char* __restrict__ cur8)
{
    __shared__ unsigned short Ws[16384];
    const int t = threadIdx.x;
    const int wave = t >> 6, lane = t & 63;
    const int quad = lane >> 4, ln = lane & 15;
    const int r0 = blockIdx.x * 64 + wave * 16;
    const int arow = r0 + ln;
    const bool av = arow < NN;

    f32x4 acc[8] = {};
#pragma unroll
    for (int s = 0; s < 2; ++s) {
        __syncthreads();
        {
            const float4* src = (const float4*)(Wp + (size_t)s * 16384);
            float4* dst = (float4*)Ws;
#pragma unroll
            for (int i = 0; i < 8; ++i) dst[t + i * 256] = src[t + i * 256];
        }
        __syncthreads();
        const unsigned short* A = s ? hnew : cur;
#pragma unroll
        for (int c = 0; c < 4; ++c) {
            short8 a = {};
            if (av) a = *(const short8*)(A + (size_t)arow * 128 + c * 32 + quad * 8);
#pragma unroll
            for (int b = 0; b < 8; ++b) {
                short8 bb = *(const short8*)&Ws[((c * 8 + b) * 64 + lane) * 8];
                acc[b] = __builtin_amdgcn_mfma_f32_16x16x32_bf16(a, bb, acc[b], 0, 0, 0);
            }
        }
    }

    float gb_s[8];
#pragma unroll
    for (int b = 0; b < 8; ++b) gb_s[b] = gb[b * 16 + ln];
#pragma unroll
    for (int i = 0; i < 4; ++i) {
        int row = r0 + quad * 4 + i;
        if (row < NN) {
            float dv = dinv[row];
#pragma unroll
            for (int b = 0; b < 8; ++b) {
                size_t idx = (size_t)row * 128 + b * 16 + ln;
                float g  = sigm(acc[b][i] + gb_s[b]);
                float cu = bf2f(cur[idx]);
                float hn = bf2f(hnew[idx]);
                float r  = g * hn + (1.f - g) * cu;
                cur[idx]  = f2bf(r);
                cur8[idx] = e2fp8(r * dv);
            }
        }
    }
}

// ---------- fused MFMA gate + RK4 stage combine (LDS-staged W) ----------
// bf16 tv_s buffers instead of fp32 acc (R8: traffic-neutral in time but
// keeps the smaller footprint); S=4 skips tv/y8 stores.
template<int S>
__global__ __launch_bounds__(256) void k_gate_fused(
    const unsigned short* __restrict__ cur, const unsigned short* __restrict__ hnew,
    const unsigned short* __restrict__ Wp, const float* __restrict__ gb,
    const unsigned short* __restrict__ fin, const unsigned short* __restrict__ h0,
    unsigned short* __restrict__ tv1, unsigned short* __restrict__ tv2,
    unsigned short* __restrict__ tv3,
    unsigned short* __restrict__ ybuf, unsigned char* __restrict__ y8,
    const float* __restrict__ scal, const float* __restrict__ rwp,
    const float* __restrict__ dinv)
{
    __shared__ unsigned short Ws[16384];
    const int t = threadIdx.x;
    const int wave = t >> 6, lane = t & 63;
    const int quad = lane >> 4, ln = lane & 15;
    const int r0 = blockIdx.x * 64 + wave * 16;
    const int arow = r0 + ln;
    const bool av = arow < NN;

    f32x4 am[8] = {};
#pragma unroll
    for (int s = 0; s < 2; ++s) {
        __syncthreads();
        {
            const float4* src = (const float4*)(Wp + (size_t)s * 16384);
            float4* dst = (float4*)Ws;
#pragma unroll
            for (int i = 0; i < 8; ++i) dst[t + i * 256] = src[t + i * 256];
        }
        __syncthreads();
        const unsigned short* A = s ? hnew : cur;
#pragma unroll
        for (int c = 0; c < 4; ++c) {
            short8 a = {};
            if (av) a = *(const short8*)(A + (size_t)arow * 128 + c * 32 + quad * 8);
#pragma unroll
            for (int b = 0; b < 8; ++b) {
                short8 bb = *(const short8*)&Ws[((c * 8 + b) * 64 + lane) * 8];
                am[b] = __builtin_amdgcn_mfma_f32_16x16x32_bf16(a, bb, am[b], 0, 0, 0);
            }
        }
    }

    float gb_s[8];
#pragma unroll
    for (int b = 0; b < 8; ++b) gb_s[b] = gb[b * 16 + ln];
    const float dt = scal[1], rw = rwp[0];
    const float cn = (S == 3) ? dt : 0.5f * dt;
    const float w16 = dt * (1.f / 6.f), w13 = dt * (1.f / 3.f);
#pragma unroll
    for (int i = 0; i < 4; ++i) {
        int row = r0 + quad * 4 + i;
        if (row < NN) {
            float dv = dinv[row];
#pragma unroll
            for (int b = 0; b < 8; ++b) {
                size_t idx = (size_t)row * 128 + b * 16 + ln;
                float g  = sigm(am[b][i] + gb_s[b]);
                float cu = bf2f(cur[idx]);
                float hn = bf2f(hnew[idx]);
                float r  = g * hn + (1.f - g) * cu;
                float tv = tanhf(r) + rw * bf2f(fin[idx]);
                float yv;
                if (S == 4) {
                    float t1 = bf2f(tv1[idx]);
                    float t2 = bf2f(tv2[idx]);
                    float t3 = bf2f(tv3[idx]);
                    yv = bf2f(h0[idx]) + w16 * (t1 + tv) + w13 * (t2 + t3);
                } else {
                    if (S == 1) tv1[idx] = f2bf(tv);
                    if (S == 2) tv2[idx] = f2bf(tv);
                    if (S == 3) tv3[idx] = f2bf(tv);
                    yv = bf2f(h0[idx]) + cn * tv;
                }
                ybuf[idx] = f2bf(yv);
                if (S != 4) y8[idx] = e2fp8(yv * dv);
            }
        }
    }
}

// ---------- pooling phase 2: sum per-block partials (782), divide by counts ----------
__global__ __launch_bounds__(256) void k_pool2(
    const float* __restrict__ partial, const int* __restrict__ st,
    float* __restrict__ out)
{
    __shared__ float sh[8][32];
    int cb = blockIdx.x & 3, g = blockIdx.x >> 2;
    int cl = threadIdx.x & 31, sl = threadIdx.x >> 5;
    int c = cb * 32 + cl;
    float s = 0.f;
    for (int b = sl; b < PBLK; b += 8) s += partial[(size_t)b * 1024 + g * 128 + c];
    sh[sl][cl] = s; __syncthreads();
    if (sl == 0) {
        float tt = 0.f;
#pragma unroll
        for (int i = 0; i < 8; ++i) tt += sh[i][cl];
        int cnt = st[g + 1] - st[g];
        out[g * 128 + c] = tt / (float)(cnt > 0 ? cnt : 1);
    }
}

// ---------- host ----------
static inline size_t al(size_t x) { return (x + 255) & ~(size_t)255; }

extern "C" void kernel_launch(void* const* d_in, const int* in_sizes, int n_in,
                              void* d_out, int out_size, void* d_ws, size_t ws_size,
                              hipStream_t stream)
{
    const float* x       = (const float*)d_in[0];
    const int*   ei      = (const int*)d_in[1];
    const int*   batch   = (const int*)d_in[2];
    const float* in_w    = (const float*)d_in[3];
    const float* in_b    = (const float*)d_in[4];
    const float* in_lng  = (const float*)d_in[5];
    const float* in_lnb  = (const float*)d_in[6];
    const float* meth    = (const float*)d_in[7];
    const float* histn   = (const float*)d_in[8];
    const float* logd    = (const float*)d_in[9];
    const float* gcn_w   = (const float*)d_in[10];
    const float* gcn_b   = (const float*)d_in[11];
    const float* ln_g    = (const float*)d_in[12];
    const float* ln_b    = (const float*)d_in[13];
    const float* gate_w  = (const float*)d_in[14];
    const float* gate_b  = (const float*)d_in[15];
    const float* rw      = (const float*)d_in[16];
    const float* out_w   = (const float*)d_in[17];
    const float* out_b   = (const float*)d_in[18];
    const float* out_lng = (const float*)d_in[19];
    const float* out_lnb = (const float*)d_in[20];
    float* out = (float*)d_out;

    char* w = (char*)d_ws;
    size_t off = 0;
    float* scal   = (float*)(w + off); off += al(16 * 4);
    int*   hist   = (int*)(w + off);   off += al((size_t)NN * 4);
    int*   rp     = (int*)(w + off);   off += al((size_t)(NN + 1) * 4);
    int*   cursor = (int*)(w + off);   off += al((size_t)(NN + 1) * 4);
    int*   aux    = (int*)(w + off);   off += al(64 * 4);
    int*   st     = (int*)(w + off);   off += al(16 * 4);
    float* dinv   = (float*)(w + off); off += al((size_t)NN * 4);
    unsigned* ew  = (unsigned*)(w + off); off += al((size_t)(EE + 128) * 4);
    float* partial= (float*)(w + off); off += al((size_t)PBLK * 1024 * 4);
    // packed bf16 weights: [in | gcn0 | gcn1 | gcn2 | gate0 | gate1 | out] contiguous
    unsigned short* wpak = (unsigned short*)(w + off); off += al((size_t)(8192 + 6 * 16384) * 2);
    unsigned short* inwp  = wpak;
    unsigned short* gcnwp = wpak + 8192;
    unsigned short* gwp   = wpak + 8192 + 3 * 16384;
    unsigned short* owp   = wpak + 8192 + 5 * 16384;
    // bf16 activations
    size_t B16 = al((size_t)NN * 128 * 2);
    unsigned short* xb  = (unsigned short*)(w + off); off += al((size_t)NN * 64 * 2);
    unsigned short* h0  = (unsigned short*)(w + off); off += B16;
    unsigned short* y   = (unsigned short*)(w + off); off += B16;
    unsigned short* cur = (unsigned short*)(w + off); off += B16;
    unsigned short* t2  = (unsigned short*)(w + off); off += B16;
    // bf16 RK4 slope buffers
    unsigned short* tv1 = (unsigned short*)(w + off); off += B16;
    unsigned short* tv2 = (unsigned short*)(w + off); off += B16;
    unsigned short* tv3 = (unsigned short*)(w + off); off += B16;
    // fp8 gather shadows (pre-scaled by dinv[node])
    size_t B8 = al((size_t)NN * 128);
    unsigned char* h08  = (unsigned char*)(w + off); off += B8;
    unsigned char* y8   = (unsigned char*)(w + off); off += B8;
    unsigned char* cur8 = (unsigned char*)(w + off); off += B8;
    if (off > ws_size) return;

    hipMemsetAsync(hist, 0, (size_t)NN * 4, stream);

    // setup+bounds, merged pack, x conversion (independent)
    k_setup<<<2, 64, 0, stream>>>(meth, histn, logd, scal, batch, st);
    k_packall<<<(8192 + 6 * 16384 + 255) / 256, 256, 0, stream>>>(in_w, gcn_w, gate_w, out_w, wpak);
    k_cvtx<<<3125, 256, 0, stream>>>(x, xb);

    // CSR build (scan_c also initializes cursor — no memcpy)
    k_hist<<<(EE + 255) / 256, 256, 0, stream>>>(ei, hist);
    k_dinv<<<(NN + 255) / 256, 256, 0, stream>>>(hist, dinv);
    k_scan_a<<<49, 256, 0, stream>>>(hist, aux);
    k_scan_b<<<1, 1, 0, stream>>>(aux, 49);
    k_scan_c<<<49, 256, 0, stream>>>(hist, aux, rp, cursor);
    k_scatter<<<SB, 256, 0, stream>>>(ei, cursor, ew);

    const int DG = (NN + 63) / 64;     // 782 blocks (dense/gate)
    const int SG = (NN + 15) / 16;     // 3125 blocks (spgemm)
    k_dense_mfma<2, 1><<<DG, 256, 0, stream>>>(xb, inwp, in_b, in_lng, in_lnb, scal, dinv, h0, h08,
                                               (const int*)0, (float*)0);

    for (int s = 1; s <= 4; ++s) {
        const unsigned short* fin = (s == 1) ? h0 : y;
        const unsigned char*  fin8 = (s == 1) ? h08 : y8;
        // layer 0
        k_spgemm<<<SG, 128, 0, stream>>>(rp, ew, fin8, gcnwp, gcn_b, ln_g, ln_b, dinv, cur, cur8);
        // layer 1 + gate
        k_spgemm<<<SG, 128, 0, stream>>>(rp, ew, cur8,
                                         gcnwp + (size_t)1 * 128 * 128, gcn_b + 128,
                                         ln_g + 128, ln_b + 128, dinv, t2, (unsigned char*)0);
        k_gate_mfma<<<DG, 256, 0, stream>>>(cur, t2, gwp, gate_b, dinv, cur8);
        // layer 2 + gate fused with RK4 stage combine
        k_spgemm<<<SG, 128, 0, stream>>>(rp, ew, cur8,
                                         gcnwp + (size_t)2 * 128 * 128, gcn_b + 256,
                                         ln_g + 256, ln_b + 256, dinv, t2, (unsigned char*)0);
        if (s == 1)      k_gate_fused<1><<<DG, 256, 0, stream>>>(cur, t2, gwp, gate_b, fin, h0, tv1, tv2, tv3, y, y8, scal, rw, dinv);
        else if (s == 2) k_gate_fused<2><<<DG, 256, 0, stream>>>(cur, t2, gwp, gate_b, fin, h0, tv1, tv2, tv3, y, y8, scal, rw, dinv);
        else if (s == 3) k_gate_fused<3><<<DG, 256, 0, stream>>>(cur, t2, gwp, gate_b, fin, h0, tv1, tv2, tv3, y, y8, scal, rw, dinv);
        else             k_gate_fused<4><<<DG, 256, 0, stream>>>(cur, t2, gwp, gate_b, fin, h0, tv1, tv2, tv3, y, y8, scal, rw, dinv);
    }

    // output projection with fused pooling (MODE=2) + final reduce
    k_dense_mfma<4, 2><<<DG, 256, 0, stream>>>(y, owp, out_b, out_lng, out_lnb, scal, dinv,
                                               (unsigned short*)0, (unsigned char*)0, batch, partial);
    k_pool2<<<GG * 4, 256, 0, stream>>>(partial, st, out);
}

// Round 13
// 822.342 us; speedup vs baseline: 1.3073x; 1.0044x over previous
//
#include <hip/hip_runtime.h>
#include <math.h>

#define NN 50000
#define EE 800000
#define HH 128
#define FF 64
#define GG 8
#define PBLK 782    // pooled partials: one per dense-output block ((NN+63)/64)
#define SB 1600     // scatter blocks: 200 per dst-group, 8 groups

using short8 = __attribute__((ext_vector_type(8))) short;
using f32x4  = __attribute__((ext_vector_type(4))) float;
using f32x2  = __attribute__((ext_vector_type(2))) float;

__device__ __forceinline__ float sigm(float x){ return 1.0f/(1.0f+expf(-x)); }
__device__ __forceinline__ unsigned short f2bf(float f){
    union { float f; unsigned u; } v; v.f = f;
    unsigned r = v.u + 0x7fff + ((v.u >> 16) & 1);
    return (unsigned short)(r >> 16);
}
__device__ __forceinline__ float bf2f(unsigned short h){
    union { unsigned u; float f; } v; v.u = ((unsigned)h) << 16;
    return v.f;
}

// ---------- fp8 helpers (HW cvt on gfx950; self-consistent either format) ----------
#if __has_builtin(__builtin_amdgcn_cvt_pk_fp8_f32) && __has_builtin(__builtin_amdgcn_cvt_pk_f32_fp8)
#define FP8_HW 1
#else
#define FP8_HW 0
#endif

__device__ __forceinline__ unsigned fp8enc1_sw(float f){
    union { float fl; unsigned u; } x; x.fl = f;
    unsigned s = (x.u >> 31) << 7;
    float a = fabsf(f);
    if (!(a > 0.f)) return s;
    if (a >= 448.f) return s | 0x7E;
    if (a < 0.015625f) {
        int q = (int)(a * 512.f + 0.5f);
        if (q > 7) return s | (1u << 3);
        return s | (unsigned)q;
    }
    unsigned u = x.u + (1u << 19);          // round at 3-bit mantissa
    int e32 = (int)((u >> 23) & 255) - 127;
    if (e32 < -6) { int q=(int)(a*512.f+0.5f); if(q>7)q=7; return s|(unsigned)q; }
    if (e32 > 8) return s | 0x7E;
    unsigned m = (u >> 20) & 7;
    return s | ((unsigned)(e32 + 7) << 3) | m;
}
__device__ __forceinline__ float fp8dec1_sw(unsigned v){
    unsigned s = v >> 7, e = (v >> 3) & 15, m = v & 7;
    float f;
    if (e == 0) f = (float)m * 0.001953125f;
    else { union { unsigned u; float fl; } x; x.u = ((e + 120u) << 23) | (m << 20); f = x.fl; }
    return s ? -f : f;
}
__device__ __forceinline__ unsigned char e2fp8(float a){
#if FP8_HW
    return (unsigned char)(__builtin_amdgcn_cvt_pk_fp8_f32(a, a, 0, false) & 0xFF);
#else
    return (unsigned char)fp8enc1_sw(a);
#endif
}
__device__ __forceinline__ float2 d2fp8(unsigned short u){
#if FP8_HW
    f32x2 r = __builtin_amdgcn_cvt_pk_f32_fp8((int)(unsigned)u, false);
    return make_float2(r[0], r[1]);
#else
    return make_float2(fp8dec1_sw(u & 0xFF), fp8dec1_sw((u >> 8) & 0xFF));
#endif
}

// ---------- setup (block 0) + graph bounds (block 1) ----------
__global__ void k_setup(const float* __restrict__ meth,
                        const float* __restrict__ histones,
                        const float* __restrict__ logd,
                        float* __restrict__ scal,
                        const int* __restrict__ batch, int* __restrict__ st)
{
    if (blockIdx.x == 1) {
        int g = threadIdx.x;
        if (g > GG) return;
        int lo = 0, hi = NN;
        while (lo < hi) { int mid = (lo + hi) >> 1; if (batch[mid] < g) lo = mid + 1; else hi = mid; }
        st[g] = lo;
        return;
    }
    int l = threadIdx.x;
    float s = sigm(meth[l]) + sigm(meth[l + 64]);
#pragma unroll
    for (int o = 32; o >= 1; o >>= 1) s += __shfl_xor(s, o, 64);
    if (l == 0) {
        float msil = s * (1.0f / 128.0f);
        float h0 = sigm(histones[0]), h1 = sigm(histones[1]);
        float h2 = sigm(histones[2]), h3 = sigm(histones[3]);
        float act = (h0 + h2) * 0.5f, rep = (h1 + h3) * 0.5f;
        float chrom = fminf(fmaxf(act - rep + 0.5f, 0.0f), 1.0f);
        scal[0] = chrom * (1.0f - msil);
        float d = expf(logd[0]);
        scal[1] = fminf(fmaxf(d, 0.1f), 3.0f);   // dt
    }
}

// ---------- single merged weight pack: all 7 matrices -> one contiguous bf16 buffer ----------
__global__ void k_packall(const float* __restrict__ in_w, const float* __restrict__ gcn_w,
                          const float* __restrict__ gate_w, const float* __restrict__ out_w,
                          unsigned short* __restrict__ outp)
{
    int i = blockIdx.x * 256 + threadIdx.x;
    if (i >= 8192 + 6 * 16384) return;
    const float* src; int base, li;
    if (i < 8192) { src = in_w + i; base = 0; li = i; }
    else {
        int j = i - 8192;
        int m = j >> 14, r = j & 16383;
        base = 8192 + (m << 14); li = r;
        if (m < 3)      src = gcn_w  + m * 16384 + r;
        else if (m < 5) src = gate_w + (m - 3) * 16384 + r;
        else            src = out_w + r;
    }
    int k = li >> 7, n = li & 127;
    int c = k >> 5, kl = k & 31, q = kl >> 3, j2 = kl & 7;
    int b = n >> 4, ln = n & 15;
    int lane = q * 16 + ln;
    outp[base + ((c * 8 + b) * 64 + lane) * 8 + j2] = f2bf(*src);
}

// ---------- fused x cvt + dst histogram (round 13: identical 3125x256 geometry) ----------
// NN*16 == EE == 800000 == 3125*256 exactly -> no guards, two independent jobs
// per thread: convert one float4 of x to bf16, and count one edge's dst.
__global__ void k_histcvt(const float* __restrict__ x, unsigned short* __restrict__ xb,
                          const int* __restrict__ ei, int* __restrict__ hist)
{
    int e = blockIdx.x * 256 + threadIdx.x;
    float4 v = ((const float4*)x)[e];
    ushort4 o;
    o.x = f2bf(v.x); o.y = f2bf(v.y); o.z = f2bf(v.z); o.w = f2bf(v.w);
    ((ushort4*)xb)[e] = o;
    atomicAdd(&hist[ei[EE + e]], 1);
}

// ---------- CSR scan (round 13: dinv fused into scan_a; aux prefix into scan_c) ----------
__global__ void k_scan_a(const int* __restrict__ hist, int* __restrict__ aux,
                         float* __restrict__ dinv)
{
    __shared__ int sh[256];
    int b = blockIdx.x, t = threadIdx.x;
    int base = b * 1024 + t * 4;
    int s = 0;
#pragma unroll
    for (int j = 0; j < 4; ++j) {
        int i = base + j;
        if (i < NN) {
            int h = hist[i];
            s += h;
            dinv[i] = h > 0 ? rsqrtf((float)h) : 0.0f;   // fused (was k_dinv)
        }
    }
    sh[t] = s; __syncthreads();
    for (int o = 128; o >= 1; o >>= 1) { if (t < o) sh[t] += sh[t + o]; __syncthreads(); }
    if (t == 0) aux[b] = sh[0];
}

// writes BOTH row_ptr and cursor; aux holds RAW per-block sums — thread 0
// computes the 49-element exclusive prefix locally (was k_scan_b's job).
__global__ void k_scan_c(const int* __restrict__ hist, const int* __restrict__ aux,
                         int* __restrict__ row_ptr, int* __restrict__ cursor)
{
    __shared__ int sh[256];
    __shared__ int sbase;
    int b = blockIdx.x, t = threadIdx.x;
    if (t == 0) {
        int r = 0;
        for (int i = 0; i < b; ++i) r += aux[i];   // independent loads, pipelined
        sbase = r;
    }
    int base = b * 1024 + t * 4;
    int v[4]; int s = 0;
#pragma unroll
    for (int j = 0; j < 4; ++j) { int i = base + j; v[j] = (i < NN) ? hist[i] : 0; s += v[j]; }
    sh[t] = s; __syncthreads();
    for (int o = 1; o < 256; o <<= 1) {
        int x = 0; if (t >= o) x = sh[t - o];
        __syncthreads(); sh[t] += x; __syncthreads();
    }
    int run = sbase + sh[t] - s;
#pragma unroll
    for (int j = 0; j < 4; ++j) {
        int i = base + j;
        if (i < NN) { row_ptr[i] = run; cursor[i] = run; }
        run += v[j];
    }
    if (b == 0 && t == 0) { row_ptr[NN] = EE; cursor[NN] = EE; }
}

// ---------- XCD-aligned dst-partitioned scatter, 4-byte records, nt streams ----------
// Verified rounds 5-12: 42 µs (FETCH 25 MB from 8x dst-read replication — L3
// does NOT absorb it; WRITE 31 MB; nt hints don't prevent L2 allocation).
__global__ __launch_bounds__(256) void k_scatter(const int* __restrict__ ei,
                          int* __restrict__ cursor, unsigned* __restrict__ ew)
{
    if (blockIdx.x == 0 && threadIdx.x < 128)    // tail pads for spgemm prefetch
        ew[EE + threadIdx.x] = 0u;
    const int grp = blockIdx.x & 7;
    const int blk = blockIdx.x >> 3;             // 0..SB/8-1
    const int CH  = EE / (SB / 8);               // 4000
    const int e0 = blk * CH, e1 = e0 + CH;
    const int glo = grp * (NN / 8), ghi = glo + (NN / 8);
    for (int e = e0 + threadIdx.x; e < e1; e += 256) {
        int d = __builtin_nontemporal_load(ei + EE + e);
        if (d >= glo && d < ghi) {
            int s = __builtin_nontemporal_load(ei + e);
            int p = atomicAdd(&cursor[d], 1);
            ew[p] = (unsigned)s | ((unsigned)(d & 15) << 16);
        }
    }
}

// ---------- MFMA dense (LDS-staged W) ----------
// MODE=1: relu(LN(A@W+b))*sc -> out + scaled fp8 shadow (input projection).
// MODE=2: LN(A@W+b) pooled per-graph into partial[block][8][128].
//   R12 fix (verified, 49.6 -> <41 µs): uniform-graph blocks (774/782) use
//   register accumulation + shfl reduce; only boundary blocks use LDS atomics
//   (R11's per-element atomics serialized 16-way on sorted batch).
// NOTE (R10 lesson): keep this kernel's template/signature stable — changing
// it perturbed co-compiled kernels' regalloc (gate_fused 60->64 VGPR, +15 µs
// per dispatch, total 845->914).
template<int KC, int MODE>
__global__ __launch_bounds__(256) void k_dense_mfma(
    const unsigned short* __restrict__ A, const unsigned short* __restrict__ Wp,
    const float* __restrict__ bias, const float* __restrict__ lng,
    const float* __restrict__ lnb, const float* __restrict__ scal,
    const float* __restrict__ dinv,
    unsigned short* __restrict__ out, unsigned char* __restrict__ out8,
    const int* __restrict__ batchp, float* __restrict__ partial)
{
    __shared__ unsigned short Ws[KC * 4096];
    const int t = threadIdx.x;
    {
        const float4* src = (const float4*)Wp;
        float4* dst = (float4*)Ws;
#pragma unroll
        for (int i = 0; i < KC * 2; ++i) dst[t + i * 256] = src[t + i * 256];
    }
    __syncthreads();
    const int wave = t >> 6, lane = t & 63;
    const int quad = lane >> 4, ln = lane & 15;
    const int r0 = blockIdx.x * 64 + wave * 16;
    const int K = KC * 32;
    const int arow = r0 + ln;
    const bool av = arow < NN;

    f32x4 acc[8] = {};
#pragma unroll
    for (int c = 0; c < KC; ++c) {
        short8 a = {};
        if (av) a = *(const short8*)(A + (size_t)arow * K + c * 32 + quad * 8);
#pragma unroll
        for (int b = 0; b < 8; ++b) {
            short8 bb = *(const short8*)&Ws[((c * 8 + b) * 64 + lane) * 8];
            acc[b] = __builtin_amdgcn_mfma_f32_16x16x32_bf16(a, bb, acc[b], 0, 0, 0);
        }
    }

    float* pbuf = (float*)Ws;                 // MODE==2: reuse staging LDS
    bool uni = false; int gfirst = 0;
    if (MODE == 2) {
        gfirst = batchp[blockIdx.x * 64];
        int rlast = blockIdx.x * 64 + 63; if (rlast >= NN) rlast = NN - 1;
        uni = (gfirst == batchp[rlast]);
        __syncthreads();                      // all waves done reading Ws
        if (!uni) {
            for (int i2 = t; i2 < GG * 128; i2 += 256) pbuf[i2] = 0.f;
        }
        __syncthreads();
    }

    float b_s[8], g_s[8], e_s[8];
#pragma unroll
    for (int b = 0; b < 8; ++b) {
        int col = b * 16 + ln;
        b_s[b] = bias[col]; g_s[b] = lng[col]; e_s[b] = lnb[col];
    }
    float sc = (MODE == 1) ? scal[0] : 0.0f;
    float psum[8];
#pragma unroll
    for (int b = 0; b < 8; ++b) psum[b] = 0.f;
#pragma unroll
    for (int i = 0; i < 4; ++i) {
        int row = r0 + quad * 4 + i;
        float v[8]; float s = 0.f, q = 0.f;
#pragma unroll
        for (int b = 0; b < 8; ++b) { float x = acc[b][i] + b_s[b]; v[b] = x; s += x; q += x * x; }
#pragma unroll
        for (int o = 1; o < 16; o <<= 1) { s += __shfl_xor(s, o, 64); q += __shfl_xor(q, o, 64); }
        float m  = s * (1.0f / 128.0f);
        float vr = q * (1.0f / 128.0f) - m * m;
        float rs = rsqrtf(vr + 1e-5f);
        if (row < NN) {
            if (MODE == 2) {
                if (uni) {
#pragma unroll
                    for (int b = 0; b < 8; ++b)
                        psum[b] += (v[b] - m) * rs * g_s[b] + e_s[b];
                } else {
                    int gg = batchp[row];
#pragma unroll
                    for (int b = 0; b < 8; ++b) {
                        float o2 = (v[b] - m) * rs * g_s[b] + e_s[b];
                        atomicAdd(&pbuf[gg * 128 + b * 16 + ln], o2);
                    }
                }
            } else {
                float dv = out8 ? dinv[row] : 0.f;
#pragma unroll
                for (int b = 0; b < 8; ++b) {
                    float o2 = (v[b] - m) * rs * g_s[b] + e_s[b];
                    if (MODE == 1) o2 = fmaxf(o2, 0.f) * sc;
                    out[(size_t)row * 128 + b * 16 + ln] = f2bf(o2);
                    if (out8) out8[(size_t)row * 128 + b * 16 + ln] = e2fp8(o2 * dv);
                }
            }
        }
    }

    if (MODE == 2) {
        if (uni) {
            // sum across the 4 quads (rows) of this wave; all lanes end with it
#pragma unroll
            for (int b = 0; b < 8; ++b) {
                psum[b] += __shfl_xor(psum[b], 16, 64);
                psum[b] += __shfl_xor(psum[b], 32, 64);
            }
            if (quad == 0) {
#pragma unroll
                for (int b = 0; b < 8; ++b) pbuf[wave * 128 + b * 16 + ln] = psum[b];
            }
            __syncthreads();
            // partial[block][8][128]: thread t writes float4 at t*4; only the
            // gfirst slot is nonzero (sum of the 4 per-wave vectors).
            int slot = t >> 5;
            int col  = (t * 4) & 127;
            float4 o = make_float4(0.f, 0.f, 0.f, 0.f);
            if (slot == gfirst) {
                o.x = pbuf[col]     + pbuf[128 + col]     + pbuf[256 + col]     + pbuf[384 + col];
                o.y = pbuf[col + 1] + pbuf[128 + col + 1] + pbuf[256 + col + 1] + pbuf[384 + col + 1];
                o.z = pbuf[col + 2] + pbuf[128 + col + 2] + pbuf[256 + col + 2] + pbuf[384 + col + 2];
                o.w = pbuf[col + 3] + pbuf[128 + col + 3] + pbuf[256 + col + 3] + pbuf[384 + col + 3];
            }
            ((float4*)(partial + (size_t)blockIdx.x * 1024))[t] = o;
        } else {
            __syncthreads();
            ((float4*)(partial + (size_t)blockIdx.x * 1024))[t] = ((const float4*)pbuf)[t];
        }
    }
}

// ---------- fused SpMM + GEMM + LN (fp8 gather; 2 half-wave edge tracks) ----------
// Wave owns 8 CSR-contiguous nodes. Half h = lane>>5 processes edges e+2j+h;
// lane covers 4 fp8 cols. Plain-store flushes into per-half buffers.
// PIPELINE DEPTH IS 1 (R5: 2-deep prefetch regressed ~2 µs/dispatch).
// LESSONS: no LDS atomics in hot loop (R1-2: halves throughput); no min-waves
// launch_bounds (spills); occupancy NOT LDS-capped; do NOT fuse
// register-hungry epilogues in here (R9: gate epilogue -> VGPR 60->88,
// occupancy 30->18%, dur 67->113 µs — the gather phase's occupancy is this
// kernel's most fragile resource).
__global__ __launch_bounds__(128) void k_spgemm(
    const int* __restrict__ rp, const unsigned* __restrict__ ew,
    const unsigned char* __restrict__ X8, const unsigned short* __restrict__ Wp,
    const float* __restrict__ bias, const float* __restrict__ lng,
    const float* __restrict__ lnb, const float* __restrict__ dinv,
    unsigned short* __restrict__ out, unsigned char* __restrict__ out8)
{
    __shared__ float accf[2][16 * 132];       // per-half buffers (16.9 KB)
    const int t = threadIdx.x, wave = t >> 6, lane = t & 63;
    const int quad = lane >> 4, ln = lane & 15;
    const int half = lane >> 5, li = lane & 31;
    const int n0 = blockIdx.x * 16;
    const int nf = n0 + wave * 8;

    // zero own rows in both half-buffers (own-wave rows only)
    {
        float* z0 = &accf[0][wave * 8 * 132];
        float* z1 = &accf[1][wave * 8 * 132];
        for (int i = lane; i < 8 * 132; i += 64) { z0[i] = 0.f; z1[i] = 0.f; }
    }

    if (nf < NN) {
        const int nl = min(nf + 8, NN);
        const int ebeg = __builtin_amdgcn_readfirstlane(rp[nf]);
        const int eend = __builtin_amdgcn_readfirstlane(rp[nl]);
        if (ebeg < eend) {
            float4 racc = make_float4(0.f, 0.f, 0.f, 0.f);
            int curd = (int)((ew[min(ebeg + half, eend - 1)] >> 16) & 15u);
            const unsigned char* Xl = X8 + li * 4;
            unsigned rec[8], recN[8], g[8];
#pragma unroll
            for (int j = 0; j < 8; ++j) rec[j]  = ew[ebeg + 2 * j + half];        // pad-safe
#pragma unroll
            for (int j = 0; j < 8; ++j) recN[j] = ew[ebeg + 16 + 2 * j + half];   // pad-safe
#pragma unroll
            for (int j = 0; j < 8; ++j) {
                int src = (int)(rec[j] & 0xFFFFu);
                g[j] = *(const unsigned*)(Xl + (size_t)src * 128);
            }
            for (int e = ebeg; e < eend; e += 16) {
                // issue next round's gathers + round-after-next records
                unsigned gN[8], recNN[8];
#pragma unroll
                for (int j = 0; j < 8; ++j) {
                    int src = (int)(recN[j] & 0xFFFFu);
                    gN[j] = *(const unsigned*)(Xl + (size_t)src * 128);
                }
#pragma unroll
                for (int j = 0; j < 8; ++j) recNN[j] = ew[e + 32 + 2 * j + half]; // pad-safe
                // consume current round (waits only on g)
                int lim = eend - e;
                int mj = lim > half ? ((lim - half + 1) >> 1) : 0; if (mj > 8) mj = 8;
#pragma unroll
                for (int j = 0; j < 8; ++j) {
                    if (j >= mj) break;                  // half-uniform (tail only)
                    int dl = (int)((rec[j] >> 16) & 15u);
                    if (dl != curd) {                    // half-uniform, 1 store
                        *(float4*)&accf[half][curd * 132 + li * 4] = racc;
                        racc = make_float4(0.f, 0.f, 0.f, 0.f);
                        curd = dl;
                    }
                    float2 p0 = d2fp8((unsigned short)(g[j] & 0xFFFFu));
                    float2 p1 = d2fp8((unsigned short)(g[j] >> 16));
                    racc.x += p0.x;
                    racc.y += p0.y;
                    racc.z += p1.x;
                    racc.w += p1.y;
                }
#pragma unroll
                for (int j = 0; j < 8; ++j) { rec[j] = recN[j]; recN[j] = recNN[j]; g[j] = gN[j]; }
            }
            *(float4*)&accf[half][curd * 132 + li * 4] = racc;   // final flush
        }
    }
    __syncthreads();

    // MFMA phase (redundant across the 2 waves): A = accf[0]+accf[1], B from L2
    f32x4 acc[8] = {};
    const float* ar0 = &accf[0][(size_t)ln * 132];
    const float* ar1 = &accf[1][(size_t)ln * 132];
#pragma unroll
    for (int c = 0; c < 4; ++c) {
        float4 a0 = *(const float4*)(ar0 + c * 32 + quad * 8);
        float4 a1 = *(const float4*)(ar0 + c * 32 + quad * 8 + 4);
        float4 b0 = *(const float4*)(ar1 + c * 32 + quad * 8);
        float4 b1 = *(const float4*)(ar1 + c * 32 + quad * 8 + 4);
        short8 af;
        af[0] = (short)f2bf(a0.x + b0.x); af[1] = (short)f2bf(a0.y + b0.y);
        af[2] = (short)f2bf(a0.z + b0.z); af[3] = (short)f2bf(a0.w + b0.w);
        af[4] = (short)f2bf(a1.x + b1.x); af[5] = (short)f2bf(a1.y + b1.y);
        af[6] = (short)f2bf(a1.z + b1.z); af[7] = (short)f2bf(a1.w + b1.w);
#pragma unroll
        for (int b = 0; b < 8; ++b) {
            short8 bb = *(const short8*)(Wp + ((size_t)(c * 8 + b) * 64 + lane) * 8);
            acc[b] = __builtin_amdgcn_mfma_f32_16x16x32_bf16(af, bb, acc[b], 0, 0, 0);
        }
    }

    float b_s[8], g_s[8], e_s[8];
#pragma unroll
    for (int b = 0; b < 8; ++b) {
        int col = b * 16 + ln;
        b_s[b] = bias[col]; g_s[b] = lng[col]; e_s[b] = lnb[col];
    }
#pragma unroll
    for (int i = 0; i < 4; ++i) {
        int row = n0 + quad * 4 + i;
        float dv = (row < NN) ? dinv[row] : 0.f;   // dinv[dst] factor of enorm
        float v[8]; float s = 0.f, q = 0.f;
#pragma unroll
        for (int b = 0; b < 8; ++b) { float x = acc[b][i] * dv + b_s[b]; v[b] = x; s += x; q += x * x; }
#pragma unroll
        for (int o = 1; o < 16; o <<= 1) { s += __shfl_xor(s, o, 64); q += __shfl_xor(q, o, 64); }
        float m  = s * (1.0f / 128.0f);
        float vr = q * (1.0f / 128.0f) - m * m;
        float rs = rsqrtf(vr + 1e-5f);
        if (((quad >> 1) == wave) && row < NN) {   // each wave stores its half
#pragma unroll
            for (int b = 0; b < 8; ++b) {
                float o2 = (v[b] - m) * rs * g_s[b] + e_s[b];
                out[(size_t)row * 128 + b * 16 + ln] = f2bf(o2);
                if (out8) out8[(size_t)row * 128 + b * 16 + ln] = e2fp8(o2 * dv);
            }
        }
    }
}

// ---------- MFMA gate (LDS-staged W), writes bf16 + scaled fp8 shadow ----------
// ROUND-6 LESSON: keep the LDS staging. Reading W per-MFMA from L2 puts a
// vmcnt wait in front of every MFMA and serializes the accumulator chain on
// ~200-cyc L2 latency 64x/wave: +14.5 µs per gate dispatch (870->961 µs).
__global__ __launch_bounds__(256) void k_gate_mfma(
    unsigned short* __restrict__ cur, const unsigned short* __restrict__ hnew,
    const unsigned short* __restrict__ Wp, const float* __restrict__ gb,
    const float* __restrict__ dinv, unsigned char* __restrict__ cur8)
{
    __shared__ unsigned short Ws[16384];
    const int t = threadIdx.x;
    const int wave = t >> 6, lane = t & 63;
    const int quad = lane >> 4, ln = lane & 15;
    const int r0 = blockIdx.x * 64 + wave * 16;
    const int arow = r0 + ln;
    const bool av = arow < NN;

    f32x4 acc[8] = {};
#pragma unroll
    for (int s = 0; s < 2; ++s) {
        __syncthreads();
        {
            const float4* src = (const float4*)(Wp + (size_t)s * 16384);
            float4* dst = (float4*)Ws;
#pragma unroll
            for (int i = 0; i < 8; ++i) dst[t + i * 256] = src[t + i * 256];
        }
        __syncthreads();
        const unsigned short* A = s ? hnew : cur;
#pragma unroll
        for (int c = 0; c < 4; ++c) {
            short8 a = {};
            if (av) a = *(const short8*)(A + (size_t)arow * 128 + c * 32 + quad * 8);
#pragma unroll
            for (int b = 0; b < 8; ++b) {
                short8 bb = *(const short8*)&Ws[((c * 8 + b) * 64 + lane) * 8];
                acc[b] = __builtin_amdgcn_mfma_f32_16x16x32_bf16(a, bb, acc[b], 0, 0, 0);
            }
        }
    }

    float gb_s[8];
#pragma unroll
    for (int b = 0; b < 8; ++b) gb_s[b] = gb[b * 16 + ln];
#pragma unroll
    for (int i = 0; i < 4; ++i) {
        int row = r0 + quad * 4 + i;
        if (row < NN) {
            float dv = dinv[row];
#pragma unroll
            for (int b = 0; b < 8; ++b) {
                size_t idx = (size_t)row * 128 + b * 16 + ln;
                float g  = sigm(acc[b][i] + gb_s[b]);
                float cu = bf2f(cur[idx]);
                float hn = bf2f(hnew[idx]);
                float r  = g * hn + (1.f - g) * cu;
                cur[idx]  = f2bf(r);
                cur8[idx] = e2fp8(r * dv);
            }
        }
    }
}

// ---------- fused MFMA gate + RK4 stage combine (LDS-staged W) ----------
// bf16 tv_s buffers instead of fp32 acc (R8: traffic-neutral in time but
// keeps the smaller footprint); S=4 skips tv/y8 stores.
template<int S>
__global__ __launch_bounds__(256) void k_gate_fused(
    const unsigned short* __restrict__ cur, const unsigned short* __restrict__ hnew,
    const unsigned short* __restrict__ Wp, const float* __restrict__ gb,
    const unsigned short* __restrict__ fin, const unsigned short* __restrict__ h0,
    unsigned short* __restrict__ tv1, unsigned short* __restrict__ tv2,
    unsigned short* __restrict__ tv3,
    unsigned short* __restrict__ ybuf, unsigned char* __restrict__ y8,
    const float* __restrict__ scal, const float* __restrict__ rwp,
    const float* __restrict__ dinv)
{
    __shared__ unsigned short Ws[16384];
    const int t = threadIdx.x;
    const int wave = t >> 6, lane = t & 63;
    const int quad = lane >> 4, ln = lane & 15;
    const int r0 = blockIdx.x * 64 + wave * 16;
    const int arow = r0 + ln;
    const bool av = arow < NN;

    f32x4 am[8] = {};
#pragma unroll
    for (int s = 0; s < 2; ++s) {
        __syncthreads();
        {
            const float4* src = (const float4*)(Wp + (size_t)s * 16384);
            float4* dst = (float4*)Ws;
#pragma unroll
            for (int i = 0; i < 8; ++i) dst[t + i * 256] = src[t + i * 256];
        }
        __syncthreads();
        const unsigned short* A = s ? hnew : cur;
#pragma unroll
        for (int c = 0; c < 4; ++c) {
            short8 a = {};
            if (av) a = *(const short8*)(A + (size_t)arow * 128 + c * 32 + quad * 8);
#pragma unroll
            for (int b = 0; b < 8; ++b) {
                short8 bb = *(const short8*)&Ws[((c * 8 + b) * 64 + lane) * 8];
                am[b] = __builtin_amdgcn_mfma_f32_16x16x32_bf16(a, bb, am[b], 0, 0, 0);
            }
        }
    }

    float gb_s[8];
#pragma unroll
    for (int b = 0; b < 8; ++b) gb_s[b] = gb[b * 16 + ln];
    const float dt = scal[1], rw = rwp[0];
    const float cn = (S == 3) ? dt : 0.5f * dt;
    const float w16 = dt * (1.f / 6.f), w13 = dt * (1.f / 3.f);
#pragma unroll
    for (int i = 0; i < 4; ++i) {
        int row = r0 + quad * 4 + i;
        if (row < NN) {
            float dv = dinv[row];
#pragma unroll
            for (int b = 0; b < 8; ++b) {
                size_t idx = (size_t)row * 128 + b * 16 + ln;
                float g  = sigm(am[b][i] + gb_s[b]);
                float cu = bf2f(cur[idx]);
                float hn = bf2f(hnew[idx]);
                float r  = g * hn + (1.f - g) * cu;
                float tv = tanhf(r) + rw * bf2f(fin[idx]);
                float yv;
                if (S == 4) {
                    float t1 = bf2f(tv1[idx]);
                    float t2 = bf2f(tv2[idx]);
                    float t3 = bf2f(tv3[idx]);
                    yv = bf2f(h0[idx]) + w16 * (t1 + tv) + w13 * (t2 + t3);
                } else {
                    if (S == 1) tv1[idx] = f2bf(tv);
                    if (S == 2) tv2[idx] = f2bf(tv);
                    if (S == 3) tv3[idx] = f2bf(tv);
                    yv = bf2f(h0[idx]) + cn * tv;
                }
                ybuf[idx] = f2bf(yv);
                if (S != 4) y8[idx] = e2fp8(yv * dv);
            }
        }
    }
}

// ---------- pooling phase 2: sum per-block partials (782), divide by counts ----------
__global__ __launch_bounds__(256) void k_pool2(
    const float* __restrict__ partial, const int* __restrict__ st,
    float* __restrict__ out)
{
    __shared__ float sh[8][32];
    int cb = blockIdx.x & 3, g = blockIdx.x >> 2;
    int cl = threadIdx.x & 31, sl = threadIdx.x >> 5;
    int c = cb * 32 + cl;
    float s = 0.f;
    for (int b = sl; b < PBLK; b += 8) s += partial[(size_t)b * 1024 + g * 128 + c];
    sh[sl][cl] = s; __syncthreads();
    if (sl == 0) {
        float tt = 0.f;
#pragma unroll
        for (int i = 0; i < 8; ++i) tt += sh[i][cl];
        int cnt = st[g + 1] - st[g];
        out[g * 128 + c] = tt / (float)(cnt > 0 ? cnt : 1);
    }
}

// ---------- host ----------
static inline size_t al(size_t x) { return (x + 255) & ~(size_t)255; }

extern "C" void kernel_launch(void* const* d_in, const int* in_sizes, int n_in,
                              void* d_out, int out_size, void* d_ws, size_t ws_size,
                              hipStream_t stream)
{
    const float* x       = (const float*)d_in[0];
    const int*   ei      = (const int*)d_in[1];
    const int*   batch   = (const int*)d_in[2];
    const float* in_w    = (const float*)d_in[3];
    const float* in_b    = (const float*)d_in[4];
    const float* in_lng  = (const float*)d_in[5];
    const float* in_lnb  = (const float*)d_in[6];
    const float* meth    = (const float*)d_in[7];
    const float* histn   = (const float*)d_in[8];
    const float* logd    = (const float*)d_in[9];
    const float* gcn_w   = (const float*)d_in[10];
    const float* gcn_b   = (const float*)d_in[11];
    const float* ln_g    = (const float*)d_in[12];
    const float* ln_b    = (const float*)d_in[13];
    const float* gate_w  = (const float*)d_in[14];
    const float* gate_b  = (const float*)d_in[15];
    const float* rw      = (const float*)d_in[16];
    const float* out_w   = (const float*)d_in[17];
    const float* out_b   = (const float*)d_in[18];
    const float* out_lng = (const float*)d_in[19];
    const float* out_lnb = (const float*)d_in[20];
    float* out = (float*)d_out;

    char* w = (char*)d_ws;
    size_t off = 0;
    float* scal   = (float*)(w + off); off += al(16 * 4);
    int*   hist   = (int*)(w + off);   off += al((size_t)NN * 4);
    int*   rp     = (int*)(w + off);   off += al((size_t)(NN + 1) * 4);
    int*   cursor = (int*)(w + off);   off += al((size_t)(NN + 1) * 4);
    int*   aux    = (int*)(w + off);   off += al(64 * 4);
    int*   st     = (int*)(w + off);   off += al(16 * 4);
    float* dinv   = (float*)(w + off); off += al((size_t)NN * 4);
    unsigned* ew  = (unsigned*)(w + off); off += al((size_t)(EE + 128) * 4);
    float* partial= (float*)(w + off); off += al((size_t)PBLK * 1024 * 4);
    // packed bf16 weights: [in | gcn0 | gcn1 | gcn2 | gate0 | gate1 | out] contiguous
    unsigned short* wpak = (unsigned short*)(w + off); off += al((size_t)(8192 + 6 * 16384) * 2);
    unsigned short* inwp  = wpak;
    unsigned short* gcnwp = wpak + 8192;
    unsigned short* gwp   = wpak + 8192 + 3 * 16384;
    unsigned short* owp   = wpak + 8192 + 5 * 16384;
    // bf16 activations
    size_t B16 = al((size_t)NN * 128 * 2);
    unsigned short* xb  = (unsigned short*)(w + off); off += al((size_t)NN * 64 * 2);
    unsigned short* h0  = (unsigned short*)(w + off); off += B16;
    unsigned short* y   = (unsigned short*)(w + off); off += B16;
    unsigned short* cur = (unsigned short*)(w + off); off += B16;
    unsigned short* t2  = (unsigned short*)(w + off); off += B16;
    // bf16 RK4 slope buffers
    unsigned short* tv1 = (unsigned short*)(w + off); off += B16;
    unsigned short* tv2 = (unsigned short*)(w + off); off += B16;
    unsigned short* tv3 = (unsigned short*)(w + off); off += B16;
    // fp8 gather shadows (pre-scaled by dinv[node])
    size_t B8 = al((size_t)NN * 128);
    unsigned char* h08  = (unsigned char*)(w + off); off += B8;
    unsigned char* y8   = (unsigned char*)(w + off); off += B8;
    unsigned char* cur8 = (unsigned char*)(w + off); off += B8;
    if (off > ws_size) return;

    hipMemsetAsync(hist, 0, (size_t)NN * 4, stream);

    // setup+bounds, merged pack (independent)
    k_setup<<<2, 64, 0, stream>>>(meth, histn, logd, scal, batch, st);
    k_packall<<<(8192 + 6 * 16384 + 255) / 256, 256, 0, stream>>>(in_w, gcn_w, gate_w, out_w, wpak);

    // fused x-convert + dst histogram (identical 3125x256 geometry)
    k_histcvt<<<3125, 256, 0, stream>>>(x, xb, ei, hist);
    // CSR scan: scan_a also computes dinv; scan_c computes aux prefix + cursor
    k_scan_a<<<49, 256, 0, stream>>>(hist, aux, dinv);
    k_scan_c<<<49, 256, 0, stream>>>(hist, aux, rp, cursor);
    k_scatter<<<SB, 256, 0, stream>>>(ei, cursor, ew);

    const int DG = (NN + 63) / 64;     // 782 blocks (dense/gate)
    const int SG = (NN + 15) / 16;     // 3125 blocks (spgemm)
    k_dense_mfma<2, 1><<<DG, 256, 0, stream>>>(xb, inwp, in_b, in_lng, in_lnb, scal, dinv, h0, h08,
                                               (const int*)0, (float*)0);

    for (int s = 1; s <= 4; ++s) {
        const unsigned short* fin = (s == 1) ? h0 : y;
        const unsigned char*  fin8 = (s == 1) ? h08 : y8;
        // layer 0
        k_spgemm<<<SG, 128, 0, stream>>>(rp, ew, fin8, gcnwp, gcn_b, ln_g, ln_b, dinv, cur, cur8);
        // layer 1 + gate
        k_spgemm<<<SG, 128, 0, stream>>>(rp, ew, cur8,
                                         gcnwp + (size_t)1 * 128 * 128, gcn_b + 128,
                                         ln_g + 128, ln_b + 128, dinv, t2, (unsigned char*)0);
        k_gate_mfma<<<DG, 256, 0, stream>>>(cur, t2, gwp, gate_b, dinv, cur8);
        // layer 2 + gate fused with RK4 stage combine
        k_spgemm<<<SG, 128, 0, stream>>>(rp, ew, cur8,
                                         gcnwp + (size_t)2 * 128 * 128, gcn_b + 256,
                                         ln_g + 256, ln_b + 256, dinv, t2, (unsigned char*)0);
        if (s == 1)      k_gate_fused<1><<<DG, 256, 0, stream>>>(cur, t2, gwp, gate_b, fin, h0, tv1, tv2, tv3, y, y8, scal, rw, dinv);
        else if (s == 2) k_gate_fused<2><<<DG, 256, 0, stream>>>(cur, t2, gwp, gate_b, fin, h0, tv1, tv2, tv3, y, y8, scal, rw, dinv);
        else if (s == 3) k_gate_fused<3><<<DG, 256, 0, stream>>>(cur, t2, gwp, gate_b, fin, h0, tv1, tv2, tv3, y, y8, scal, rw, dinv);
        else             k_gate_fused<4><<<DG, 256, 0, stream>>>(cur, t2, gwp, gate_b, fin, h0, tv1, tv2, tv3, y, y8, scal, rw, dinv);
    }

    // output projection with fused pooling (MODE=2) + final reduce
    k_dense_mfma<4, 2><<<DG, 256, 0, stream>>>(y, owp, out_b, out_lng, out_lnb, scal, dinv,
                                               (unsigned short*)0, (unsigned char*)0, batch, partial);
    k_pool2<<<GG * 4, 256, 0, stream>>>(partial, st, out);
}

// Round 14
// 818.633 us; speedup vs baseline: 1.3133x; 1.0045x over previous
//
#include <hip/hip_runtime.h>
#include <math.h>

#define NN 50000
#define EE 800000
#define HH 128
#define FF 64
#define GG 8
#define PBLK 782    // pooled partials: one per dense-output block ((NN+63)/64)
#define SB 1600     // scatter blocks: 200 per dst-group, 8 groups

using short8 = __attribute__((ext_vector_type(8))) short;
using f32x4  = __attribute__((ext_vector_type(4))) float;
using f32x2  = __attribute__((ext_vector_type(2))) float;

__device__ __forceinline__ float sigm(float x){ return 1.0f/(1.0f+expf(-x)); }
__device__ __forceinline__ unsigned short f2bf(float f){
    union { float f; unsigned u; } v; v.f = f;
    unsigned r = v.u + 0x7fff + ((v.u >> 16) & 1);
    return (unsigned short)(r >> 16);
}
__device__ __forceinline__ float bf2f(unsigned short h){
    union { unsigned u; float f; } v; v.u = ((unsigned)h) << 16;
    return v.f;
}

// ---------- fp8 helpers (HW cvt on gfx950; self-consistent either format) ----------
#if __has_builtin(__builtin_amdgcn_cvt_pk_fp8_f32) && __has_builtin(__builtin_amdgcn_cvt_pk_f32_fp8)
#define FP8_HW 1
#else
#define FP8_HW 0
#endif

__device__ __forceinline__ unsigned fp8enc1_sw(float f){
    union { float fl; unsigned u; } x; x.fl = f;
    unsigned s = (x.u >> 31) << 7;
    float a = fabsf(f);
    if (!(a > 0.f)) return s;
    if (a >= 448.f) return s | 0x7E;
    if (a < 0.015625f) {
        int q = (int)(a * 512.f + 0.5f);
        if (q > 7) return s | (1u << 3);
        return s | (unsigned)q;
    }
    unsigned u = x.u + (1u << 19);          // round at 3-bit mantissa
    int e32 = (int)((u >> 23) & 255) - 127;
    if (e32 < -6) { int q=(int)(a*512.f+0.5f); if(q>7)q=7; return s|(unsigned)q; }
    if (e32 > 8) return s | 0x7E;
    unsigned m = (u >> 20) & 7;
    return s | ((unsigned)(e32 + 7) << 3) | m;
}
__device__ __forceinline__ float fp8dec1_sw(unsigned v){
    unsigned s = v >> 7, e = (v >> 3) & 15, m = v & 7;
    float f;
    if (e == 0) f = (float)m * 0.001953125f;
    else { union { unsigned u; float fl; } x; x.u = ((e + 120u) << 23) | (m << 20); f = x.fl; }
    return s ? -f : f;
}
__device__ __forceinline__ unsigned char e2fp8(float a){
#if FP8_HW
    return (unsigned char)(__builtin_amdgcn_cvt_pk_fp8_f32(a, a, 0, false) & 0xFF);
#else
    return (unsigned char)fp8enc1_sw(a);
#endif
}
__device__ __forceinline__ float2 d2fp8(unsigned short u){
#if FP8_HW
    f32x2 r = __builtin_amdgcn_cvt_pk_f32_fp8((int)(unsigned)u, false);
    return make_float2(r[0], r[1]);
#else
    return make_float2(fp8dec1_sw(u & 0xFF), fp8dec1_sw((u >> 8) & 0xFF));
#endif
}

// ---------- setup (block 0) + graph bounds (block 1) ----------
__global__ void k_setup(const float* __restrict__ meth,
                        const float* __restrict__ histones,
                        const float* __restrict__ logd,
                        float* __restrict__ scal,
                        const int* __restrict__ batch, int* __restrict__ st)
{
    if (blockIdx.x == 1) {
        int g = threadIdx.x;
        if (g > GG) return;
        int lo = 0, hi = NN;
        while (lo < hi) { int mid = (lo + hi) >> 1; if (batch[mid] < g) lo = mid + 1; else hi = mid; }
        st[g] = lo;
        return;
    }
    int l = threadIdx.x;
    float s = sigm(meth[l]) + sigm(meth[l + 64]);
#pragma unroll
    for (int o = 32; o >= 1; o >>= 1) s += __shfl_xor(s, o, 64);
    if (l == 0) {
        float msil = s * (1.0f / 128.0f);
        float h0 = sigm(histones[0]), h1 = sigm(histones[1]);
        float h2 = sigm(histones[2]), h3 = sigm(histones[3]);
        float act = (h0 + h2) * 0.5f, rep = (h1 + h3) * 0.5f;
        float chrom = fminf(fmaxf(act - rep + 0.5f, 0.0f), 1.0f);
        scal[0] = chrom * (1.0f - msil);
        float d = expf(logd[0]);
        scal[1] = fminf(fmaxf(d, 0.1f), 3.0f);   // dt
    }
}

// ---------- single merged weight pack: all 7 matrices -> one contiguous bf16 buffer ----------
__global__ void k_packall(const float* __restrict__ in_w, const float* __restrict__ gcn_w,
                          const float* __restrict__ gate_w, const float* __restrict__ out_w,
                          unsigned short* __restrict__ outp)
{
    int i = blockIdx.x * 256 + threadIdx.x;
    if (i >= 8192 + 6 * 16384) return;
    const float* src; int base, li;
    if (i < 8192) { src = in_w + i; base = 0; li = i; }
    else {
        int j = i - 8192;
        int m = j >> 14, r = j & 16383;
        base = 8192 + (m << 14); li = r;
        if (m < 3)      src = gcn_w  + m * 16384 + r;
        else if (m < 5) src = gate_w + (m - 3) * 16384 + r;
        else            src = out_w + r;
    }
    int k = li >> 7, n = li & 127;
    int c = k >> 5, kl = k & 31, q = kl >> 3, j2 = kl & 7;
    int b = n >> 4, ln = n & 15;
    int lane = q * 16 + ln;
    outp[base + ((c * 8 + b) * 64 + lane) * 8 + j2] = f2bf(*src);
}

// ---------- fused x cvt + dst histogram (identical 3125x256 geometry) ----------
// NN*16 == EE == 800000 == 3125*256 exactly -> no guards, two independent jobs
// per thread: convert one float4 of x to bf16, and count one edge's dst.
__global__ void k_histcvt(const float* __restrict__ x, unsigned short* __restrict__ xb,
                          const int* __restrict__ ei, int* __restrict__ hist)
{
    int e = blockIdx.x * 256 + threadIdx.x;
    float4 v = ((const float4*)x)[e];
    ushort4 o;
    o.x = f2bf(v.x); o.y = f2bf(v.y); o.z = f2bf(v.z); o.w = f2bf(v.w);
    ((ushort4*)xb)[e] = o;
    atomicAdd(&hist[ei[EE + e]], 1);
}

// ---------- CSR scan (dinv fused into scan_a; aux prefix into scan_c) ----------
__global__ void k_scan_a(const int* __restrict__ hist, int* __restrict__ aux,
                         float* __restrict__ dinv)
{
    __shared__ int sh[256];
    int b = blockIdx.x, t = threadIdx.x;
    int base = b * 1024 + t * 4;
    int s = 0;
#pragma unroll
    for (int j = 0; j < 4; ++j) {
        int i = base + j;
        if (i < NN) {
            int h = hist[i];
            s += h;
            dinv[i] = h > 0 ? rsqrtf((float)h) : 0.0f;   // fused (was k_dinv)
        }
    }
    sh[t] = s; __syncthreads();
    for (int o = 128; o >= 1; o >>= 1) { if (t < o) sh[t] += sh[t + o]; __syncthreads(); }
    if (t == 0) aux[b] = sh[0];
}

// writes BOTH row_ptr and cursor; aux holds RAW per-block sums — thread 0
// computes the 49-element exclusive prefix locally (was k_scan_b's job).
__global__ void k_scan_c(const int* __restrict__ hist, const int* __restrict__ aux,
                         int* __restrict__ row_ptr, int* __restrict__ cursor)
{
    __shared__ int sh[256];
    __shared__ int sbase;
    int b = blockIdx.x, t = threadIdx.x;
    if (t == 0) {
        int r = 0;
        for (int i = 0; i < b; ++i) r += aux[i];   // independent loads, pipelined
        sbase = r;
    }
    int base = b * 1024 + t * 4;
    int v[4]; int s = 0;
#pragma unroll
    for (int j = 0; j < 4; ++j) { int i = base + j; v[j] = (i < NN) ? hist[i] : 0; s += v[j]; }
    sh[t] = s; __syncthreads();
    for (int o = 1; o < 256; o <<= 1) {
        int x = 0; if (t >= o) x = sh[t - o];
        __syncthreads(); sh[t] += x; __syncthreads();
    }
    int run = sbase + sh[t] - s;
#pragma unroll
    for (int j = 0; j < 4; ++j) {
        int i = base + j;
        if (i < NN) { row_ptr[i] = run; cursor[i] = run; }
        run += v[j];
    }
    if (b == 0 && t == 0) { row_ptr[NN] = EE; cursor[NN] = EE; }
}

// ---------- XCD-aligned dst-partitioned scatter, 4-byte records, nt streams ----------
// Verified rounds 5-13: 42 µs (FETCH 25 MB from 8x dst-read replication — L3
// does NOT absorb it; WRITE 31 MB; nt hints don't prevent L2 allocation).
__global__ __launch_bounds__(256) void k_scatter(const int* __restrict__ ei,
                          int* __restrict__ cursor, unsigned* __restrict__ ew)
{
    if (blockIdx.x == 0 && threadIdx.x < 128)    // tail pads for spgemm prefetch
        ew[EE + threadIdx.x] = 0u;
    const int grp = blockIdx.x & 7;
    const int blk = blockIdx.x >> 3;             // 0..SB/8-1
    const int CH  = EE / (SB / 8);               // 4000
    const int e0 = blk * CH, e1 = e0 + CH;
    const int glo = grp * (NN / 8), ghi = glo + (NN / 8);
    for (int e = e0 + threadIdx.x; e < e1; e += 256) {
        int d = __builtin_nontemporal_load(ei + EE + e);
        if (d >= glo && d < ghi) {
            int s = __builtin_nontemporal_load(ei + e);
            int p = atomicAdd(&cursor[d], 1);
            ew[p] = (unsigned)s | ((unsigned)(d & 15) << 16);
        }
    }
}

// ---------- MFMA dense (LDS-staged W) ----------
// MODE=1: relu(LN(A@W+b))*sc -> out + scaled fp8 shadow (input projection).
// MODE=2: LN(A@W+b) pooled per-graph into partial[block][8][128].
//   R12 fix (verified, 49.6 -> <41 µs): uniform-graph blocks (774/782) use
//   register accumulation + shfl reduce; only boundary blocks use LDS atomics
//   (R11's per-element atomics serialized 16-way on sorted batch).
// NOTE (R10 lesson): keep this kernel's template/signature stable — changing
// it perturbed co-compiled kernels' regalloc (gate_fused 60->64 VGPR, +15 µs
// per dispatch, total 845->914).
template<int KC, int MODE>
__global__ __launch_bounds__(256) void k_dense_mfma(
    const unsigned short* __restrict__ A, const unsigned short* __restrict__ Wp,
    const float* __restrict__ bias, const float* __restrict__ lng,
    const float* __restrict__ lnb, const float* __restrict__ scal,
    const float* __restrict__ dinv,
    unsigned short* __restrict__ out, unsigned char* __restrict__ out8,
    const int* __restrict__ batchp, float* __restrict__ partial)
{
    __shared__ unsigned short Ws[KC * 4096];
    const int t = threadIdx.x;
    {
        const float4* src = (const float4*)Wp;
        float4* dst = (float4*)Ws;
#pragma unroll
        for (int i = 0; i < KC * 2; ++i) dst[t + i * 256] = src[t + i * 256];
    }
    __syncthreads();
    const int wave = t >> 6, lane = t & 63;
    const int quad = lane >> 4, ln = lane & 15;
    const int r0 = blockIdx.x * 64 + wave * 16;
    const int K = KC * 32;
    const int arow = r0 + ln;
    const bool av = arow < NN;

    f32x4 acc[8] = {};
#pragma unroll
    for (int c = 0; c < KC; ++c) {
        short8 a = {};
        if (av) a = *(const short8*)(A + (size_t)arow * K + c * 32 + quad * 8);
#pragma unroll
        for (int b = 0; b < 8; ++b) {
            short8 bb = *(const short8*)&Ws[((c * 8 + b) * 64 + lane) * 8];
            acc[b] = __builtin_amdgcn_mfma_f32_16x16x32_bf16(a, bb, acc[b], 0, 0, 0);
        }
    }

    float* pbuf = (float*)Ws;                 // MODE==2: reuse staging LDS
    bool uni = false; int gfirst = 0;
    if (MODE == 2) {
        gfirst = batchp[blockIdx.x * 64];
        int rlast = blockIdx.x * 64 + 63; if (rlast >= NN) rlast = NN - 1;
        uni = (gfirst == batchp[rlast]);
        __syncthreads();                      // all waves done reading Ws
        if (!uni) {
            for (int i2 = t; i2 < GG * 128; i2 += 256) pbuf[i2] = 0.f;
        }
        __syncthreads();
    }

    float b_s[8], g_s[8], e_s[8];
#pragma unroll
    for (int b = 0; b < 8; ++b) {
        int col = b * 16 + ln;
        b_s[b] = bias[col]; g_s[b] = lng[col]; e_s[b] = lnb[col];
    }
    float sc = (MODE == 1) ? scal[0] : 0.0f;
    float psum[8];
#pragma unroll
    for (int b = 0; b < 8; ++b) psum[b] = 0.f;
#pragma unroll
    for (int i = 0; i < 4; ++i) {
        int row = r0 + quad * 4 + i;
        float v[8]; float s = 0.f, q = 0.f;
#pragma unroll
        for (int b = 0; b < 8; ++b) { float x = acc[b][i] + b_s[b]; v[b] = x; s += x; q += x * x; }
#pragma unroll
        for (int o = 1; o < 16; o <<= 1) { s += __shfl_xor(s, o, 64); q += __shfl_xor(q, o, 64); }
        float m  = s * (1.0f / 128.0f);
        float vr = q * (1.0f / 128.0f) - m * m;
        float rs = rsqrtf(vr + 1e-5f);
        if (row < NN) {
            if (MODE == 2) {
                if (uni) {
#pragma unroll
                    for (int b = 0; b < 8; ++b)
                        psum[b] += (v[b] - m) * rs * g_s[b] + e_s[b];
                } else {
                    int gg = batchp[row];
#pragma unroll
                    for (int b = 0; b < 8; ++b) {
                        float o2 = (v[b] - m) * rs * g_s[b] + e_s[b];
                        atomicAdd(&pbuf[gg * 128 + b * 16 + ln], o2);
                    }
                }
            } else {
                float dv = out8 ? dinv[row] : 0.f;
#pragma unroll
                for (int b = 0; b < 8; ++b) {
                    float o2 = (v[b] - m) * rs * g_s[b] + e_s[b];
                    if (MODE == 1) o2 = fmaxf(o2, 0.f) * sc;
                    out[(size_t)row * 128 + b * 16 + ln] = f2bf(o2);
                    if (out8) out8[(size_t)row * 128 + b * 16 + ln] = e2fp8(o2 * dv);
                }
            }
        }
    }

    if (MODE == 2) {
        if (uni) {
            // sum across the 4 quads (rows) of this wave; all lanes end with it
#pragma unroll
            for (int b = 0; b < 8; ++b) {
                psum[b] += __shfl_xor(psum[b], 16, 64);
                psum[b] += __shfl_xor(psum[b], 32, 64);
            }
            if (quad == 0) {
#pragma unroll
                for (int b = 0; b < 8; ++b) pbuf[wave * 128 + b * 16 + ln] = psum[b];
            }
            __syncthreads();
            // partial[block][8][128]: thread t writes float4 at t*4; only the
            // gfirst slot is nonzero (sum of the 4 per-wave vectors).
            int slot = t >> 5;
            int col  = (t * 4) & 127;
            float4 o = make_float4(0.f, 0.f, 0.f, 0.f);
            if (slot == gfirst) {
                o.x = pbuf[col]     + pbuf[128 + col]     + pbuf[256 + col]     + pbuf[384 + col];
                o.y = pbuf[col + 1] + pbuf[128 + col + 1] + pbuf[256 + col + 1] + pbuf[384 + col + 1];
                o.z = pbuf[col + 2] + pbuf[128 + col + 2] + pbuf[256 + col + 2] + pbuf[384 + col + 2];
                o.w = pbuf[col + 3] + pbuf[128 + col + 3] + pbuf[256 + col + 3] + pbuf[384 + col + 3];
            }
            ((float4*)(partial + (size_t)blockIdx.x * 1024))[t] = o;
        } else {
            __syncthreads();
            ((float4*)(partial + (size_t)blockIdx.x * 1024))[t] = ((const float4*)pbuf)[t];
        }
    }
}

// ---------- fused SpMM + GEMM + LN (fp8 gather; 2 half-wave edge tracks) ----------
// Wave owns 8 CSR-contiguous nodes. Half h = lane>>5 processes edges e+2j+h;
// lane covers 4 fp8 cols. Plain-store flushes into per-half buffers.
// ROUND-14: consume loop restructured for ILP — dual accumulators alternating
// by j parity (halves the 16-deep per-component fma chain) and a straight-line
// full-round path (mj==8; the guarded path runs only in the <=1 tail round).
// Memory/prefetch structure byte-identical.
// PIPELINE DEPTH IS 1 (R5: 2-deep prefetch regressed ~2 µs/dispatch).
// LESSONS: no LDS atomics in hot loop (R1-2: halves throughput); no min-waves
// launch_bounds (spills); occupancy NOT LDS-capped; do NOT fuse
// register-hungry epilogues in here (R9: VGPR 60->88, occupancy 30->18%).
__global__ __launch_bounds__(128) void k_spgemm(
    const int* __restrict__ rp, const unsigned* __restrict__ ew,
    const unsigned char* __restrict__ X8, const unsigned short* __restrict__ Wp,
    const float* __restrict__ bias, const float* __restrict__ lng,
    const float* __restrict__ lnb, const float* __restrict__ dinv,
    unsigned short* __restrict__ out, unsigned char* __restrict__ out8)
{
    __shared__ float accf[2][16 * 132];       // per-half buffers (16.9 KB)
    const int t = threadIdx.x, wave = t >> 6, lane = t & 63;
    const int quad = lane >> 4, ln = lane & 15;
    const int half = lane >> 5, li = lane & 31;
    const int n0 = blockIdx.x * 16;
    const int nf = n0 + wave * 8;

    // zero own rows in both half-buffers (own-wave rows only)
    {
        float* z0 = &accf[0][wave * 8 * 132];
        float* z1 = &accf[1][wave * 8 * 132];
        for (int i = lane; i < 8 * 132; i += 64) { z0[i] = 0.f; z1[i] = 0.f; }
    }

    if (nf < NN) {
        const int nl = min(nf + 8, NN);
        const int ebeg = __builtin_amdgcn_readfirstlane(rp[nf]);
        const int eend = __builtin_amdgcn_readfirstlane(rp[nl]);
        if (ebeg < eend) {
            float4 racc0 = make_float4(0.f, 0.f, 0.f, 0.f);
            float4 racc1 = make_float4(0.f, 0.f, 0.f, 0.f);
            int curd = (int)((ew[min(ebeg + half, eend - 1)] >> 16) & 15u);
            const unsigned char* Xl = X8 + li * 4;
            unsigned rec[8], recN[8], g[8];
#pragma unroll
            for (int j = 0; j < 8; ++j) rec[j]  = ew[ebeg + 2 * j + half];        // pad-safe
#pragma unroll
            for (int j = 0; j < 8; ++j) recN[j] = ew[ebeg + 16 + 2 * j + half];   // pad-safe
#pragma unroll
            for (int j = 0; j < 8; ++j) {
                int src = (int)(rec[j] & 0xFFFFu);
                g[j] = *(const unsigned*)(Xl + (size_t)src * 128);
            }
            for (int e = ebeg; e < eend; e += 16) {
                // issue next round's gathers + round-after-next records
                unsigned gN[8], recNN[8];
#pragma unroll
                for (int j = 0; j < 8; ++j) {
                    int src = (int)(recN[j] & 0xFFFFu);
                    gN[j] = *(const unsigned*)(Xl + (size_t)src * 128);
                }
#pragma unroll
                for (int j = 0; j < 8; ++j) recNN[j] = ew[e + 32 + 2 * j + half]; // pad-safe
                // consume current round (waits only on g)
                int lim = eend - e;
                int mj = lim > half ? ((lim - half + 1) >> 1) : 0; if (mj > 8) mj = 8;
                if (mj == 8) {
                    // full round: straight-line, dual accumulators (j parity)
#pragma unroll
                    for (int j = 0; j < 8; ++j) {
                        int dl = (int)((rec[j] >> 16) & 15u);
                        if (dl != curd) {                // half-uniform, rare
                            float4 sum = make_float4(racc0.x + racc1.x, racc0.y + racc1.y,
                                                     racc0.z + racc1.z, racc0.w + racc1.w);
                            *(float4*)&accf[half][curd * 132 + li * 4] = sum;
                            racc0 = make_float4(0.f, 0.f, 0.f, 0.f);
                            racc1 = make_float4(0.f, 0.f, 0.f, 0.f);
                            curd = dl;
                        }
                        float2 p0 = d2fp8((unsigned short)(g[j] & 0xFFFFu));
                        float2 p1 = d2fp8((unsigned short)(g[j] >> 16));
                        if (j & 1) {
                            racc1.x += p0.x; racc1.y += p0.y;
                            racc1.z += p1.x; racc1.w += p1.y;
                        } else {
                            racc0.x += p0.x; racc0.y += p0.y;
                            racc0.z += p1.x; racc0.w += p1.y;
                        }
                    }
                } else {
                    // tail round (<=1 per wave): guarded path
#pragma unroll
                    for (int j = 0; j < 8; ++j) {
                        if (j >= mj) break;              // half-uniform (tail only)
                        int dl = (int)((rec[j] >> 16) & 15u);
                        if (dl != curd) {
                            float4 sum = make_float4(racc0.x + racc1.x, racc0.y + racc1.y,
                                                     racc0.z + racc1.z, racc0.w + racc1.w);
                            *(float4*)&accf[half][curd * 132 + li * 4] = sum;
                            racc0 = make_float4(0.f, 0.f, 0.f, 0.f);
                            racc1 = make_float4(0.f, 0.f, 0.f, 0.f);
                            curd = dl;
                        }
                        float2 p0 = d2fp8((unsigned short)(g[j] & 0xFFFFu));
                        float2 p1 = d2fp8((unsigned short)(g[j] >> 16));
                        racc0.x += p0.x; racc0.y += p0.y;
                        racc0.z += p1.x; racc0.w += p1.y;
                    }
                }
#pragma unroll
                for (int j = 0; j < 8; ++j) { rec[j] = recN[j]; recN[j] = recNN[j]; g[j] = gN[j]; }
            }
            {   // final flush
                float4 sum = make_float4(racc0.x + racc1.x, racc0.y + racc1.y,
                                         racc0.z + racc1.z, racc0.w + racc1.w);
                *(float4*)&accf[half][curd * 132 + li * 4] = sum;
            }
        }
    }
    __syncthreads();

    // MFMA phase (redundant across the 2 waves): A = accf[0]+accf[1], B from L2
    f32x4 acc[8] = {};
    const float* ar0 = &accf[0][(size_t)ln * 132];
    const float* ar1 = &accf[1][(size_t)ln * 132];
#pragma unroll
    for (int c = 0; c < 4; ++c) {
        float4 a0 = *(const float4*)(ar0 + c * 32 + quad * 8);
        float4 a1 = *(const float4*)(ar0 + c * 32 + quad * 8 + 4);
        float4 b0 = *(const float4*)(ar1 + c * 32 + quad * 8);
        float4 b1 = *(const float4*)(ar1 + c * 32 + quad * 8 + 4);
        short8 af;
        af[0] = (short)f2bf(a0.x + b0.x); af[1] = (short)f2bf(a0.y + b0.y);
        af[2] = (short)f2bf(a0.z + b0.z); af[3] = (short)f2bf(a0.w + b0.w);
        af[4] = (short)f2bf(a1.x + b1.x); af[5] = (short)f2bf(a1.y + b1.y);
        af[6] = (short)f2bf(a1.z + b1.z); af[7] = (short)f2bf(a1.w + b1.w);
#pragma unroll
        for (int b = 0; b < 8; ++b) {
            short8 bb = *(const short8*)(Wp + ((size_t)(c * 8 + b) * 64 + lane) * 8);
            acc[b] = __builtin_amdgcn_mfma_f32_16x16x32_bf16(af, bb, acc[b], 0, 0, 0);
        }
    }

    float b_s[8], g_s[8], e_s[8];
#pragma unroll
    for (int b = 0; b < 8; ++b) {
        int col = b * 16 + ln;
        b_s[b] = bias[col]; g_s[b] = lng[col]; e_s[b] = lnb[col];
    }
#pragma unroll
    for (int i = 0; i < 4; ++i) {
        int row = n0 + quad * 4 + i;
        float dv = (row < NN) ? dinv[row] : 0.f;   // dinv[dst] factor of enorm
        float v[8]; float s = 0.f, q = 0.f;
#pragma unroll
        for (int b = 0; b < 8; ++b) { float x = acc[b][i] * dv + b_s[b]; v[b] = x; s += x; q += x * x; }
#pragma unroll
        for (int o = 1; o < 16; o <<= 1) { s += __shfl_xor(s, o, 64); q += __shfl_xor(q, o, 64); }
        float m  = s * (1.0f / 128.0f);
        float vr = q * (1.0f / 128.0f) - m * m;
        float rs = rsqrtf(vr + 1e-5f);
        if (((quad >> 1) == wave) && row < NN) {   // each wave stores its half
#pragma unroll
            for (int b = 0; b < 8; ++b) {
                float o2 = (v[b] - m) * rs * g_s[b] + e_s[b];
                out[(size_t)row * 128 + b * 16 + ln] = f2bf(o2);
                if (out8) out8[(size_t)row * 128 + b * 16 + ln] = e2fp8(o2 * dv);
            }
        }
    }
}

// ---------- MFMA gate (LDS-staged W), writes bf16 + scaled fp8 shadow ----------
// ROUND-6 LESSON: keep the LDS staging. Reading W per-MFMA from L2 puts a
// vmcnt wait in front of every MFMA and serializes the accumulator chain on
// ~200-cyc L2 latency 64x/wave: +14.5 µs per gate dispatch (870->961 µs).
__global__ __launch_bounds__(256) void k_gate_mfma(
    unsigned short* __restrict__ cur, const unsigned short* __restrict__ hnew,
    const unsigned short* __restrict__ Wp, const float* __restrict__ gb,
    const float* __restrict__ dinv, unsigned char* __restrict__ cur8)
{
    __shared__ unsigned short Ws[16384];
    const int t = threadIdx.x;
    const int wave = t >> 6, lane = t & 63;
    const int quad = lane >> 4, ln = lane & 15;
    const int r0 = blockIdx.x * 64 + wave * 16;
    const int arow = r0 + ln;
    const bool av = arow < NN;

    f32x4 acc[8] = {};
#pragma unroll
    for (int s = 0; s < 2; ++s) {
        __syncthreads();
        {
            const float4* src = (const float4*)(Wp + (size_t)s * 16384);
            float4* dst = (float4*)Ws;
#pragma unroll
            for (int i = 0; i < 8; ++i) dst[t + i * 256] = src[t + i * 256];
        }
        __syncthreads();
        const unsigned short* A = s ? hnew : cur;
#pragma unroll
        for (int c = 0; c < 4; ++c) {
            short8 a = {};
            if (av) a = *(const short8*)(A + (size_t)arow * 128 + c * 32 + quad * 8);
#pragma unroll
            for (int b = 0; b < 8; ++b) {
                short8 bb = *(const short8*)&Ws[((c * 8 + b) * 64 + lane) * 8];
                acc[b] = __builtin_amdgcn_mfma_f32_16x16x32_bf16(a, bb, acc[b], 0, 0, 0);
            }
        }
    }

    float gb_s[8];
#pragma unroll
    for (int b = 0; b < 8; ++b) gb_s[b] = gb[b * 16 + ln];
#pragma unroll
    for (int i = 0; i < 4; ++i) {
        int row = r0 + quad * 4 + i;
        if (row < NN) {
            float dv = dinv[row];
#pragma unroll
            for (int b = 0; b < 8; ++b) {
                size_t idx = (size_t)row * 128 + b * 16 + ln;
                float g  = sigm(acc[b][i] + gb_s[b]);
                float cu = bf2f(cur[idx]);
                float hn = bf2f(hnew[idx]);
                float r  = g * hn + (1.f - g) * cu;
                cur[idx]  = f2bf(r);
                cur8[idx] = e2fp8(r * dv);
            }
        }
    }
}

// ---------- fused MFMA gate + RK4 stage combine (LDS-staged W) ----------
// bf16 tv_s buffers instead of fp32 acc (R8: traffic-neutral in time but
// keeps the smaller footprint); S=4 skips tv/y8 stores.
template<int S>
__global__ __launch_bounds__(256) void k_gate_fused(
    const unsigned short* __restrict__ cur, const unsigned short* __restrict__ hnew,
    const unsigned short* __restrict__ Wp, const float* __restrict__ gb,
    const unsigned short* __restrict__ fin, const unsigned short* __restrict__ h0,
    unsigned short* __restrict__ tv1, unsigned short* __restrict__ tv2,
    unsigned short* __restrict__ tv3,
    unsigned short* __restrict__ ybuf, unsigned char* __restrict__ y8,
    const float* __restrict__ scal, const float* __restrict__ rwp,
    const float* __restrict__ dinv)
{
    __shared__ unsigned short Ws[16384];
    const int t = threadIdx.x;
    const int wave = t >> 6, lane = t & 63;
    const int quad = lane >> 4, ln = lane & 15;
    const int r0 = blockIdx.x * 64 + wave * 16;
    const int arow = r0 + ln;
    const bool av = arow < NN;

    f32x4 am[8] = {};
#pragma unroll
    for (int s = 0; s < 2; ++s) {
        __syncthreads();
        {
            const float4* src = (const float4*)(Wp + (size_t)s * 16384);
            float4* dst = (float4*)Ws;
#pragma unroll
            for (int i = 0; i < 8; ++i) dst[t + i * 256] = src[t + i * 256];
        }
        __syncthreads();
        const unsigned short* A = s ? hnew : cur;
#pragma unroll
        for (int c = 0; c < 4; ++c) {
            short8 a = {};
            if (av) a = *(const short8*)(A + (size_t)arow * 128 + c * 32 + quad * 8);
#pragma unroll
            for (int b = 0; b < 8; ++b) {
                short8 bb = *(const short8*)&Ws[((c * 8 + b) * 64 + lane) * 8];
                am[b] = __builtin_amdgcn_mfma_f32_16x16x32_bf16(a, bb, am[b], 0, 0, 0);
            }
        }
    }

    float gb_s[8];
#pragma unroll
    for (int b = 0; b < 8; ++b) gb_s[b] = gb[b * 16 + ln];
    const float dt = scal[1], rw = rwp[0];
    const float cn = (S == 3) ? dt : 0.5f * dt;
    const float w16 = dt * (1.f / 6.f), w13 = dt * (1.f / 3.f);
#pragma unroll
    for (int i = 0; i < 4; ++i) {
        int row = r0 + quad * 4 + i;
        if (row < NN) {
            float dv = dinv[row];
#pragma unroll
            for (int b = 0; b < 8; ++b) {
                size_t idx = (size_t)row * 128 + b * 16 + ln;
                float g  = sigm(am[b][i] + gb_s[b]);
                float cu = bf2f(cur[idx]);
                float hn = bf2f(hnew[idx]);
                float r  = g * hn + (1.f - g) * cu;
                float tv = tanhf(r) + rw * bf2f(fin[idx]);
                float yv;
                if (S == 4) {
                    float t1 = bf2f(tv1[idx]);
                    float t2 = bf2f(tv2[idx]);
                    float t3 = bf2f(tv3[idx]);
                    yv = bf2f(h0[idx]) + w16 * (t1 + tv) + w13 * (t2 + t3);
                } else {
                    if (S == 1) tv1[idx] = f2bf(tv);
                    if (S == 2) tv2[idx] = f2bf(tv);
                    if (S == 3) tv3[idx] = f2bf(tv);
                    yv = bf2f(h0[idx]) + cn * tv;
                }
                ybuf[idx] = f2bf(yv);
                if (S != 4) y8[idx] = e2fp8(yv * dv);
            }
        }
    }
}

// ---------- pooling phase 2: sum per-block partials (782), divide by counts ----------
__global__ __launch_bounds__(256) void k_pool2(
    const float* __restrict__ partial, const int* __restrict__ st,
    float* __restrict__ out)
{
    __shared__ float sh[8][32];
    int cb = blockIdx.x & 3, g = blockIdx.x >> 2;
    int cl = threadIdx.x & 31, sl = threadIdx.x >> 5;
    int c = cb * 32 + cl;
    float s = 0.f;
    for (int b = sl; b < PBLK; b += 8) s += partial[(size_t)b * 1024 + g * 128 + c];
    sh[sl][cl] = s; __syncthreads();
    if (sl == 0) {
        float tt = 0.f;
#pragma unroll
        for (int i = 0; i < 8; ++i) tt += sh[i][cl];
        int cnt = st[g + 1] - st[g];
        out[g * 128 + c] = tt / (float)(cnt > 0 ? cnt : 1);
    }
}

// ---------- host ----------
static inline size_t al(size_t x) { return (x + 255) & ~(size_t)255; }

extern "C" void kernel_launch(void* const* d_in, const int* in_sizes, int n_in,
                              void* d_out, int out_size, void* d_ws, size_t ws_size,
                              hipStream_t stream)
{
    const float* x       = (const float*)d_in[0];
    const int*   ei      = (const int*)d_in[1];
    const int*   batch   = (const int*)d_in[2];
    const float* in_w    = (const float*)d_in[3];
    const float* in_b    = (const float*)d_in[4];
    const float* in_lng  = (const float*)d_in[5];
    const float* in_lnb  = (const float*)d_in[6];
    const float* meth    = (const float*)d_in[7];
    const float* histn   = (const float*)d_in[8];
    const float* logd    = (const float*)d_in[9];
    const float* gcn_w   = (const float*)d_in[10];
    const float* gcn_b   = (const float*)d_in[11];
    const float* ln_g    = (const float*)d_in[12];
    const float* ln_b    = (const float*)d_in[13];
    const float* gate_w  = (const float*)d_in[14];
    const float* gate_b  = (const float*)d_in[15];
    const float* rw      = (const float*)d_in[16];
    const float* out_w   = (const float*)d_in[17];
    const float* out_b   = (const float*)d_in[18];
    const float* out_lng = (const float*)d_in[19];
    const float* out_lnb = (const float*)d_in[20];
    float* out = (float*)d_out;

    char* w = (char*)d_ws;
    size_t off = 0;
    float* scal   = (float*)(w + off); off += al(16 * 4);
    int*   hist   = (int*)(w + off);   off += al((size_t)NN * 4);
    int*   rp     = (int*)(w + off);   off += al((size_t)(NN + 1) * 4);
    int*   cursor = (int*)(w + off);   off += al((size_t)(NN + 1) * 4);
    int*   aux    = (int*)(w + off);   off += al(64 * 4);
    int*   st     = (int*)(w + off);   off += al(16 * 4);
    float* dinv   = (float*)(w + off); off += al((size_t)NN * 4);
    unsigned* ew  = (unsigned*)(w + off); off += al((size_t)(EE + 128) * 4);
    float* partial= (float*)(w + off); off += al((size_t)PBLK * 1024 * 4);
    // packed bf16 weights: [in | gcn0 | gcn1 | gcn2 | gate0 | gate1 | out] contiguous
    unsigned short* wpak = (unsigned short*)(w + off); off += al((size_t)(8192 + 6 * 16384) * 2);
    unsigned short* inwp  = wpak;
    unsigned short* gcnwp = wpak + 8192;
    unsigned short* gwp   = wpak + 8192 + 3 * 16384;
    unsigned short* owp   = wpak + 8192 + 5 * 16384;
    // bf16 activations
    size_t B16 = al((size_t)NN * 128 * 2);
    unsigned short* xb  = (unsigned short*)(w + off); off += al((size_t)NN * 64 * 2);
    unsigned short* h0  = (unsigned short*)(w + off); off += B16;
    unsigned short* y   = (unsigned short*)(w + off); off += B16;
    unsigned short* cur = (unsigned short*)(w + off); off += B16;
    unsigned short* t2  = (unsigned short*)(w + off); off += B16;
    // bf16 RK4 slope buffers
    unsigned short* tv1 = (unsigned short*)(w + off); off += B16;
    unsigned short* tv2 = (unsigned short*)(w + off); off += B16;
    unsigned short* tv3 = (unsigned short*)(w + off); off += B16;
    // fp8 gather shadows (pre-scaled by dinv[node])
    size_t B8 = al((size_t)NN * 128);
    unsigned char* h08  = (unsigned char*)(w + off); off += B8;
    unsigned char* y8   = (unsigned char*)(w + off); off += B8;
    unsigned char* cur8 = (unsigned char*)(w + off); off += B8;
    if (off > ws_size) return;

    hipMemsetAsync(hist, 0, (size_t)NN * 4, stream);

    // setup+bounds, merged pack (independent)
    k_setup<<<2, 64, 0, stream>>>(meth, histn, logd, scal, batch, st);
    k_packall<<<(8192 + 6 * 16384 + 255) / 256, 256, 0, stream>>>(in_w, gcn_w, gate_w, out_w, wpak);

    // fused x-convert + dst histogram (identical 3125x256 geometry)
    k_histcvt<<<3125, 256, 0, stream>>>(x, xb, ei, hist);
    // CSR scan: scan_a also computes dinv; scan_c computes aux prefix + cursor
    k_scan_a<<<49, 256, 0, stream>>>(hist, aux, dinv);
    k_scan_c<<<49, 256, 0, stream>>>(hist, aux, rp, cursor);
    k_scatter<<<SB, 256, 0, stream>>>(ei, cursor, ew);

    const int DG = (NN + 63) / 64;     // 782 blocks (dense/gate)
    const int SG = (NN + 15) / 16;     // 3125 blocks (spgemm)
    k_dense_mfma<2, 1><<<DG, 256, 0, stream>>>(xb, inwp, in_b, in_lng, in_lnb, scal, dinv, h0, h08,
                                               (const int*)0, (float*)0);

    for (int s = 1; s <= 4; ++s) {
        const unsigned short* fin = (s == 1) ? h0 : y;
        const unsigned char*  fin8 = (s == 1) ? h08 : y8;
        // layer 0
        k_spgemm<<<SG, 128, 0, stream>>>(rp, ew, fin8, gcnwp, gcn_b, ln_g, ln_b, dinv, cur, cur8);
        // layer 1 + gate
        k_spgemm<<<SG, 128, 0, stream>>>(rp, ew, cur8,
                                         gcnwp + (size_t)1 * 128 * 128, gcn_b + 128,
                                         ln_g + 128, ln_b + 128, dinv, t2, (unsigned char*)0);
        k_gate_mfma<<<DG, 256, 0, stream>>>(cur, t2, gwp, gate_b, dinv, cur8);
        // layer 2 + gate fused with RK4 stage combine
        k_spgemm<<<SG, 128, 0, stream>>>(rp, ew, cur8,
                                         gcnwp + (size_t)2 * 128 * 128, gcn_b + 256,
                                         ln_g + 256, ln_b + 256, dinv, t2, (unsigned char*)0);
        if (s == 1)      k_gate_fused<1><<<DG, 256, 0, stream>>>(cur, t2, gwp, gate_b, fin, h0, tv1, tv2, tv3, y, y8, scal, rw, dinv);
        else if (s == 2) k_gate_fused<2><<<DG, 256, 0, stream>>>(cur, t2, gwp, gate_b, fin, h0, tv1, tv2, tv3, y, y8, scal, rw, dinv);
        else if (s == 3) k_gate_fused<3><<<DG, 256, 0, stream>>>(cur, t2, gwp, gate_b, fin, h0, tv1, tv2, tv3, y, y8, scal, rw, dinv);
        else             k_gate_fused<4><<<DG, 256, 0, stream>>>(cur, t2, gwp, gate_b, fin, h0, tv1, tv2, tv3, y, y8, scal, rw, dinv);
    }

    // output projection with fused pooling (MODE=2) + final reduce
    k_dense_mfma<4, 2><<<DG, 256, 0, stream>>>(y, owp, out_b, out_lng, out_lnb, scal, dinv,
                                               (unsigned short*)0, (unsigned char*)0, batch, partial);
    k_pool2<<<GG * 4, 256, 0, stream>>>(partial, st, out);
}